// Round 7
// baseline (2175.867 us; speedup 1.0000x reference)
//
#include <hip/hip_runtime.h>

#define EPS_BN 1e-5f

// ---------------- workspace layout (float-unit offsets) ----------------
#define O_SRCD   0u
#define O_DSTD   17024u
#define O_COUNTS 34048u
#define O_OFFS   35072u
#define O_CURS   36096u
#define O_EIDX   37120u                    // esrc (src node id, CSR-ordered)
#define O_PW1    54144u                    // [32][640]  (Wl1T|Wr1T|WpT)
#define O_PW2    74624u                    // [256][256] (Wl2T|Wr2T)
#define O_LW     140160u                   // PLW: [2][16w][8q][4dk][64lane][4gate]
#define O_BCOMB  402304u                   // [2][128j][4]
#define O_ABF    403328u                   // A1(256)|B1(256)|A2(128)|B2(128)
#define O_HWT    404352u                   // Ws1T(832)|Ws2T(2048)|Wh1T(10240)
#define O_BIG0   417536u                   // XL1  | later XL2,XR2
#define O_BIG1   (O_BIG0 + 16384000u)      // XR1  | later LO
#define O_BIG2   (O_BIG1 + 16384000u)      // H1
#define O_BIG3   (O_BIG2 + 16384000u)      // XP
#define O_BIG4   (O_BIG3 + 8192000u)       // Hres

__device__ __forceinline__ float rsum32(float p) {
  p += __shfl_xor(p, 1);  p += __shfl_xor(p, 2);  p += __shfl_xor(p, 4);
  p += __shfl_xor(p, 8);  p += __shfl_xor(p, 16); return p;
}
__device__ __forceinline__ float rsum64(float p) {
  p = rsum32(p); p += __shfl_xor(p, 32); return p;
}
__device__ __forceinline__ float lrelu(float x) { return x > 0.f ? x : 0.2f * x; }
__device__ __forceinline__ float eluf(float x)  { return x > 0.f ? x : expm1f(x); }
__device__ __forceinline__ float geluf(float x) { return 0.5f * x * (1.f + erff(x * 0.70710678118654752f)); }

// ---------------- prep kernels ----------------
__global__ void prep_edges(const int* __restrict__ ei, int* __restrict__ srcD,
                           int* __restrict__ dstD, int* __restrict__ counts) {
  int i = blockIdx.x * 256 + threadIdx.x;
  if (i < 1024) counts[i] = 0;
  if (i < 17000) {
    int s = (i < 16000) ? ei[i] : (i - 16000);
    int d = (i < 16000) ? ei[16000 + i] : (i - 16000);
    srcD[i] = s; dstD[i] = d;
  }
}
__global__ void hist_kernel(const int* __restrict__ dstD, int* __restrict__ counts) {
  int i = blockIdx.x * 256 + threadIdx.x;
  if (i < 17000) atomicAdd(&counts[dstD[i]], 1);
}
__global__ void scan_kernel(const int* __restrict__ counts, int* __restrict__ offs,
                            int* __restrict__ curs) {
  __shared__ int sh[1024];
  int i = threadIdx.x;
  int v = (i < 1000) ? counts[i] : 0;
  sh[i] = v;
  __syncthreads();
  for (int d = 1; d < 1024; d <<= 1) {
    int t = (i >= d) ? sh[i - d] : 0;
    __syncthreads();
    sh[i] += t;
    __syncthreads();
  }
  if (i < 1000) { offs[i + 1] = sh[i]; curs[i] = sh[i] - v; }
  if (i == 0) offs[0] = 0;
}
__global__ void fill_kernel(const int* __restrict__ srcD, const int* __restrict__ dstD,
                            int* __restrict__ curs, int* __restrict__ esrc) {
  int i = blockIdx.x * 256 + threadIdx.x;
  if (i < 17000) { int p = atomicAdd(&curs[dstD[i]], 1); esrc[p] = srcD[i]; }
}

__global__ void pack_kernel(
    const float* __restrict__ Wl1, const float* __restrict__ Wr1, const float* __restrict__ Wp,
    const float* __restrict__ Wl2, const float* __restrict__ Wr2,
    const float* __restrict__ Wih0, const float* __restrict__ Whh0,
    const float* __restrict__ bih0, const float* __restrict__ bhh0,
    const float* __restrict__ Wih1, const float* __restrict__ Whh1,
    const float* __restrict__ bih1, const float* __restrict__ bhh1,
    const float* __restrict__ g1, const float* __restrict__ be1, const float* __restrict__ m1,
    const float* __restrict__ v1, const float* __restrict__ bg1,
    const float* __restrict__ g2, const float* __restrict__ be2, const float* __restrict__ m2,
    const float* __restrict__ v2, const float* __restrict__ bg2,
    const float* __restrict__ Ws1, const float* __restrict__ Ws2, const float* __restrict__ Wh1,
    float* __restrict__ PW1, float* __restrict__ PW2, float* __restrict__ PLW,
    float* __restrict__ BC, float* __restrict__ ABF, float* __restrict__ HWT)
{
  int i = blockIdx.x * 256 + threadIdx.x;
  if (i < 262144) {  // LSTM packed weights: [L][w16][q8][dk4][lane64][gate4]
    int gate = i & 3, lane = (i >> 2) & 63, dk = (i >> 8) & 3,
        q = (i >> 10) & 7, w = (i >> 13) & 15, L = (i >> 17) & 1;
    int jlo = lane & 7, pp = lane >> 3;
    int mat = pp >> 2, kq = pp & 3;
    int jj = (w << 3) + jlo;
    int kk = (kq << 5) + (q << 2) + dk;
    const float* Wih = L ? Wih1 : Wih0;
    const float* Whh = L ? Whh1 : Whh0;
    PLW[i] = mat ? Whh[(gate * 128 + jj) * 128 + kk]
                 : Wih[(gate * 128 + jj) * 128 + kk];
  }
  if (i < 65536) { int c = i & 255, k = i >> 8;
    PW2[i] = (c < 128) ? Wl2[c * 256 + k] : Wr2[(c - 128) * 256 + k]; }
  if (i < 20480) { int g = i % 640, k = i / 640;
    PW1[i] = (g < 256) ? Wl1[g * 32 + k] : (g < 512) ? Wr1[(g - 256) * 32 + k]
                                                     : Wp[(g - 512) * 32 + k]; }
  if (i < 1024) { int u = i & 3, jj = (i >> 2) & 127, L = i >> 9;
    BC[i] = (L ? bih1 : bih0)[u * 128 + jj] + (L ? bhh1 : bhh0)[u * 128 + jj]; }
  if (i < 768) {
    if (i < 256) ABF[i] = g1[i] * rsqrtf(v1[i] + EPS_BN);
    else if (i < 512) { int c = i - 256; float a = g1[c] * rsqrtf(v1[c] + EPS_BN);
      ABF[i] = (bg1[c] - m1[c]) * a + be1[c]; }
    else if (i < 640) { int c = i - 512; ABF[i] = g2[c] * rsqrtf(v2[c] + EPS_BN); }
    else { int c = i - 640; float a = g2[c] * rsqrtf(v2[c] + EPS_BN);
      ABF[i] = (bg2[c] - m2[c]) * a + be2[c]; }
  }
  if (i < 13120) {
    if (i < 832) { int l = i & 63, c = i >> 6; HWT[i] = Ws1[l * 13 + c]; }
    else if (i < 2880) { int k = i - 832; int l = k & 31, jj = k >> 5; HWT[i] = Ws2[l * 64 + jj]; }
    else { int k = i - 2880; int l = k & 63, r = k >> 6; HWT[i] = Wh1[l * 160 + r]; }
  }
}

// ---------------- projection 1: x -> xl1(256) | xr1(256) | xp(128) ----------------
__global__ __launch_bounds__(320)
void proj1_kernel(const float* __restrict__ X, const float* __restrict__ PW1,
                  const float* __restrict__ bp,
                  float* __restrict__ XL1, float* __restrict__ XR1, float* __restrict__ XP)
{
  __shared__ __align__(16) float xs[32][16];
  const int tid = threadIdx.x;
  const int r0 = blockIdx.x * 16;
  for (int el = tid; el < 512; el += 320) {
    int r = el >> 5, k = el & 31;
    xs[k][r] = X[(size_t)(r0 + r) * 32 + k];
  }
  __syncthreads();
  const int gA = tid, gB = tid + 320;
  float accA[16], accB[16];
  const float iB = (gB >= 512) ? bp[gB - 512] : 0.f;
  #pragma unroll
  for (int r = 0; r < 16; ++r) { accA[r] = 0.f; accB[r] = iB; }
  for (int k = 0; k < 32; ++k) {
    float wA = PW1[k * 640 + gA], wB = PW1[k * 640 + gB];
    float xv[16];
    #pragma unroll
    for (int q = 0; q < 4; ++q)
      *reinterpret_cast<float4*>(&xv[q * 4]) = *reinterpret_cast<const float4*>(&xs[k][q * 4]);
    #pragma unroll
    for (int r = 0; r < 16; ++r) {
      accA[r] = fmaf(wA, xv[r], accA[r]);
      accB[r] = fmaf(wB, xv[r], accB[r]);
    }
  }
  for (int r = 0; r < 16; ++r) {
    size_t row = r0 + r;
    if (gA < 256) XL1[row * 256 + gA] = accA[r];
    else          XR1[row * 256 + (gA - 256)] = accA[r];
    if (gB < 512) XR1[row * 256 + (gB - 256)] = accB[r];
    else          XP[row * 128 + (gB - 512)] = accB[r];
  }
}

// ---------------- GAT layer 1 fused (2 heads, d=128) ----------------
__global__ __launch_bounds__(256)
void gat1_kernel(const float* __restrict__ XL, const float* __restrict__ XR,
                 const int* __restrict__ esrc,
                 const int* __restrict__ offs, const float* __restrict__ a1,
                 const float* __restrict__ ABF, float* __restrict__ H1)
{
  const int lane = threadIdx.x & 63;
  const int wv = threadIdx.x >> 6;
  const int n = blockIdx.x * 4 + wv;
  const int b = blockIdx.y;
  const int half = lane >> 5;
  __shared__ float lsh[4][128];
  const int beg = offs[n];
  const int deg = offs[n + 1] - beg;
  const float4 a4 = reinterpret_cast<const float4*>(a1)[lane];
  const float4* XLb = reinterpret_cast<const float4*>(XL) + (size_t)b * 64000;
  const float4 xr4 = reinterpret_cast<const float4*>(XR + (size_t)(b * 1000 + n) * 256)[lane];
  float m = -INFINITY, ssum = 0.f;
  {
    int sC = esrc[beg];
    float4 xc = XLb[(size_t)sC * 64 + lane];
    for (int i = 0; i < deg; ++i) {
      int nx = (i + 1 < deg) ? (i + 1) : i;
      int sN = esrc[beg + nx];
      float4 xn = XLb[(size_t)sN * 64 + lane];
      float p = lrelu(xc.x + xr4.x) * a4.x + lrelu(xc.y + xr4.y) * a4.y
              + lrelu(xc.z + xr4.z) * a4.z + lrelu(xc.w + xr4.w) * a4.w;
      p = rsum32(p);
      if (i < 64 && (lane & 31) == 0) lsh[wv][2 * i + half] = p;
      float mn = fmaxf(m, p);
      ssum = ssum * __expf(m - mn) + __expf(p - mn);
      m = mn;
      xc = xn;
    }
  }
  const float inv = 1.f / ssum;
  __builtin_amdgcn_wave_barrier();
  float4 acc = make_float4(0.f, 0.f, 0.f, 0.f);
  {
    int sC = esrc[beg];
    float4 xc = XLb[(size_t)sC * 64 + lane];
    for (int i = 0; i < deg; ++i) {
      int nx = (i + 1 < deg) ? (i + 1) : i;
      int sN = esrc[beg + nx];
      float4 xn = XLb[(size_t)sN * 64 + lane];
      float lg;
      if (i < 64) lg = lsh[wv][2 * i + half];
      else {
        float p = lrelu(xc.x + xr4.x) * a4.x + lrelu(xc.y + xr4.y) * a4.y
                + lrelu(xc.z + xr4.z) * a4.z + lrelu(xc.w + xr4.w) * a4.w;
        lg = rsum32(p);
      }
      const float al = __expf(lg - m) * inv;
      acc.x = fmaf(al, xc.x, acc.x);
      acc.y = fmaf(al, xc.y, acc.y);
      acc.z = fmaf(al, xc.z, acc.z);
      acc.w = fmaf(al, xc.w, acc.w);
      xc = xn;
    }
  }
  const float4 A4 = reinterpret_cast<const float4*>(ABF)[lane];
  const float4 B4 = reinterpret_cast<const float4*>(ABF + 256)[lane];
  float4 o;
  o.x = eluf(fmaf(acc.x, A4.x, B4.x));
  o.y = eluf(fmaf(acc.y, A4.y, B4.y));
  o.z = eluf(fmaf(acc.z, A4.z, B4.z));
  o.w = eluf(fmaf(acc.w, A4.w, B4.w));
  reinterpret_cast<float4*>(H1 + (size_t)(b * 1000 + n) * 256)[lane] = o;
}

// ---------------- projection 2: h1(256) -> xl2(128)|xr2(128) ----------------
__global__ __launch_bounds__(256)
void proj2_kernel(const float* __restrict__ H1, const float* __restrict__ PW2,
                  float* __restrict__ XL2, float* __restrict__ XR2)
{
  __shared__ __align__(16) float xs[256][20];
  const int tid = threadIdx.x;
  const int r0 = blockIdx.x * 16;
  for (int el = tid; el < 4096; el += 256) {
    int k = el & 255, r = el >> 8;
    xs[k][r] = H1[(size_t)(r0 + r) * 256 + k];
  }
  __syncthreads();
  float acc[16];
  #pragma unroll
  for (int r = 0; r < 16; ++r) acc[r] = 0.f;
  for (int k = 0; k < 256; ++k) {
    float wgt = PW2[k * 256 + tid];
    float xv[16];
    #pragma unroll
    for (int q = 0; q < 4; ++q)
      *reinterpret_cast<float4*>(&xv[q * 4]) = *reinterpret_cast<const float4*>(&xs[k][q * 4]);
    #pragma unroll
    for (int r = 0; r < 16; ++r) acc[r] = fmaf(wgt, xv[r], acc[r]);
  }
  float* dst = (tid < 128) ? XL2 : XR2;
  const int col = tid & 127;
  for (int r = 0; r < 16; ++r)
    dst[(size_t)(r0 + r) * 128 + col] = acc[r];
}

// ---------------- GAT layer 2 fused (1 head) + BN/ELU + residual ----------------
__global__ __launch_bounds__(256)
void gat2_kernel(const float* __restrict__ XL, const float* __restrict__ XR,
                 const int* __restrict__ esrc,
                 const int* __restrict__ offs, const float* __restrict__ a2,
                 const float* __restrict__ ABF, const float* __restrict__ XP,
                 float* __restrict__ Hout)
{
  const int lane = threadIdx.x & 63;
  const int wv = threadIdx.x >> 6;
  const int n = blockIdx.x * 4 + wv;
  const int b = blockIdx.y;
  __shared__ float lsh[4][96];
  const int beg = offs[n];
  const int deg = offs[n + 1] - beg;
  const float2 av = reinterpret_cast<const float2*>(a2)[lane];
  const float2* XLb = reinterpret_cast<const float2*>(XL) + (size_t)b * 64000;
  const float2 xr2 = reinterpret_cast<const float2*>(XR + (size_t)(b * 1000 + n) * 128)[lane];
  float m = -INFINITY, ssum = 0.f;
  {
    int sC = esrc[beg];
    float2 xc = XLb[(size_t)sC * 64 + lane];
    for (int i = 0; i < deg; ++i) {
      int nx = (i + 1 < deg) ? (i + 1) : i;
      int sN = esrc[beg + nx];
      float2 xn = XLb[(size_t)sN * 64 + lane];
      float p = lrelu(xc.x + xr2.x) * av.x + lrelu(xc.y + xr2.y) * av.y;
      p = rsum64(p);
      if (i < 96 && lane == 0) lsh[wv][i] = p;
      float mn = fmaxf(m, p);
      ssum = ssum * __expf(m - mn) + __expf(p - mn);
      m = mn;
      xc = xn;
    }
  }
  const float inv = 1.f / ssum;
  __builtin_amdgcn_wave_barrier();
  float2 acc = make_float2(0.f, 0.f);
  {
    int sC = esrc[beg];
    float2 xc = XLb[(size_t)sC * 64 + lane];
    for (int i = 0; i < deg; ++i) {
      int nx = (i + 1 < deg) ? (i + 1) : i;
      int sN = esrc[beg + nx];
      float2 xn = XLb[(size_t)sN * 64 + lane];
      float lg;
      if (i < 96) lg = lsh[wv][i];
      else {
        float p = lrelu(xc.x + xr2.x) * av.x + lrelu(xc.y + xr2.y) * av.y;
        lg = rsum64(p);
      }
      const float al = __expf(lg - m) * inv;
      acc.x = fmaf(al, xc.x, acc.x);
      acc.y = fmaf(al, xc.y, acc.y);
      xc = xn;
    }
  }
  const float2 A2 = reinterpret_cast<const float2*>(ABF + 512)[lane];
  const float2 B2 = reinterpret_cast<const float2*>(ABF + 640)[lane];
  const float2 xp = reinterpret_cast<const float2*>(XP + (size_t)(b * 1000 + n) * 128)[lane];
  float2 o;
  o.x = eluf(fmaf(acc.x, A2.x, B2.x)) + xp.x;
  o.y = eluf(fmaf(acc.y, A2.y, B2.y)) + xp.y;
  reinterpret_cast<float2*>(Hout + (size_t)(b * 1000 + n) * 128)[lane] = o;
}

// ---------------- fused 2-layer LSTM (8-way k-split, 2 units/thread, 8 seq/block) ----
#define FMA4(A, W, S) { (A).x = fmaf((W).x, (S), (A).x); (A).y = fmaf((W).y, (S), (A).y); \
                        (A).z = fmaf((W).z, (S), (A).z); (A).w = fmaf((W).w, (S), (A).w); }
#define AD4(a, b) { (a).x += (b).x; (a).y += (b).y; (a).z += (b).z; (a).w += (b).w; }
#define LROW 140

__device__ __forceinline__ float4 shflx4(float4 v, int msk) {
  float4 r;
  r.x = __shfl_xor(v.x, msk); r.y = __shfl_xor(v.y, msk);
  r.z = __shfl_xor(v.z, msk); r.w = __shfl_xor(v.w, msk);
  return r;
}

// Two j-units per thread, 8 sequences per block. Accumulators gA[8]+gB[8] = 64
// VGPRs; whole working set ~120 regs fits the 128-total budget at 4 waves/EU.
__device__ __forceinline__ void gates8x2(const float4* __restrict__ wbA,
                                         const float4* __restrict__ wbB,
                                         const float* XS, int xoff,
                                         float4 (&gA)[8], float4 (&gB)[8])
{
  #pragma unroll 2
  for (int q = 0; q < 8; ++q) {
    const float4* wqA = wbA + q * 256;
    const float4* wqB = wbB + q * 256;
    float4 a0 = wqA[0], a1 = wqA[64], a2 = wqA[128], a3 = wqA[192];
    float4 b0 = wqB[0], b1 = wqB[64], b2 = wqB[128], b3 = wqB[192];
    const float* xp = XS + xoff + (q << 2);
    #pragma unroll
    for (int s = 0; s < 8; ++s) {
      float4 xv = *reinterpret_cast<const float4*>(xp + s * LROW);
      FMA4(gA[s], a0, xv.x); FMA4(gA[s], a1, xv.y);
      FMA4(gA[s], a2, xv.z); FMA4(gA[s], a3, xv.w);
      FMA4(gB[s], b0, xv.x); FMA4(gB[s], b1, xv.y);
      FMA4(gB[s], b2, xv.z); FMA4(gB[s], b3, xv.w);
    }
  }
}

// narrowing 3-round butterfly over p = lane>>3; result: seq p (one per slice)
__device__ __forceinline__ void reduce8to1(float4 (&g)[8], int lane, float4& ga)
{
  const bool b4 = (lane & 32) != 0, b2 = (lane & 16) != 0, b1 = (lane & 8) != 0;
  float4 t[4];
  #pragma unroll
  for (int i = 0; i < 4; ++i) {
    float4 keep = b4 ? g[4 + i] : g[i];
    float4 send = b4 ? g[i] : g[4 + i];
    float4 r = shflx4(send, 32);
    AD4(keep, r); t[i] = keep;
  }
  float4 u[2];
  #pragma unroll
  for (int i = 0; i < 2; ++i) {
    float4 keep = b2 ? t[2 + i] : t[i];
    float4 send = b2 ? t[i] : t[2 + i];
    float4 r = shflx4(send, 16);
    AD4(keep, r); u[i] = keep;
  }
  {
    float4 keep = b1 ? u[1] : u[0];
    float4 send = b1 ? u[0] : u[1];
    float4 r = shflx4(send, 8);
    AD4(keep, r); ga = keep;
  }
}

__device__ __forceinline__ float cellf(float4 g, float& c) {
  const float ig = 1.f / (1.f + __expf(-g.x));
  const float fg = 1.f / (1.f + __expf(-g.y));
  const float gg = tanhf(g.z);
  const float og = 1.f / (1.f + __expf(-g.w));
  c = fmaf(fg, c, ig * gg);
  return og * tanhf(c);
}

// 512 threads = 8 waves, 8 seqs/block, 500 blocks.
// waves_per_eu(4,4): total-reg budget 512/4 = 128/thread. Round 6 used (2,2),
// which licensed 256 regs -> RA banked 128 AGPRs per wave (accvgpr moves) and
// occupancy stuck at 2 waves/EU. With (4,4) the ~120-reg working set fits all-
// architectural, and LDS 22.5 KB x 2 blocks/CU gives 4 waves/EU.
__global__ __launch_bounds__(512)
__attribute__((amdgpu_waves_per_eu(4, 4)))
void lstm_kernel(const float* __restrict__ Hin, const float* __restrict__ PLW,
                 const float* __restrict__ BC, float* __restrict__ LO)
{
  __shared__ __align__(16) float xb[2][8][LROW];
  __shared__ __align__(16) float h1s[8][LROW];
  __shared__ __align__(16) float h2b[2][8][LROW];
  const int tid = threadIdx.x;
  const int lane = tid & 63;
  const int w = tid >> 6;                  // 0..7
  const int jlo = lane & 7;
  const int p = lane >> 3;                 // 0..7: (k,mat) slice; mat = p>>2
  const int jA = (w << 3) + jlo;           // unit 0..63
  const int jB = jA + 64;                  // unit 64..127
  const int xoff = 36 * (p & 3);
  const bool hi = p >= 4;                  // hh side
  const int joA = jA + ((jA >> 5) << 2);
  const int joB = jB + ((jB >> 5) << 2);
  const int q0 = blockIdx.x << 3;          // 8 seqs per block
  for (int i = tid; i < 8 * LROW; i += 512) {
    (&h1s[0][0])[i] = 0.f;
  }
  for (int i = tid; i < 2 * 8 * LROW; i += 512) {
    (&h2b[0][0][0])[i] = 0.f;
  }
  {
    int el = tid;                           // 1024 elements, 512 threads, 2 each
    #pragma unroll
    for (int c = 0; c < 2; ++c) {
      int s = el >> 7, k = el & 127;
      xb[0][s][k + ((k >> 5) << 2)] = Hin[((size_t)(((q0 + s) << 4))) * 128 + k];
      el += 512;
    }
  }
  const float4 b1A = *reinterpret_cast<const float4*>(BC + (jA << 2));
  const float4 b1B = *reinterpret_cast<const float4*>(BC + (jB << 2));
  const float4 b2A = *reinterpret_cast<const float4*>(BC + 512 + (jA << 2));
  const float4 b2B = *reinterpret_cast<const float4*>(BC + 512 + (jB << 2));
  const float4* PLW4 = reinterpret_cast<const float4*>(PLW);
  const float4* wbA1 = PLW4 + (w << 11) + lane;
  const float4* wbB1 = PLW4 + ((w + 8) << 11) + lane;
  const float4* wbA2 = wbA1 + 32768;
  const float4* wbB2 = wbB1 + 32768;
  float c1A = 0.f, c1B = 0.f, c2A = 0.f, c2B = 0.f;
  __syncthreads();
  int cur = 0;
  for (int t = 0; t < 16; ++t) {
    if (t < 15) {
      int el = tid;
      #pragma unroll
      for (int c = 0; c < 2; ++c) {
        int s = el >> 7, k = el & 127;
        xb[cur ^ 1][s][k + ((k >> 5) << 2)] =
            Hin[((size_t)(((q0 + s) << 4) + (t + 1))) * 128 + k];
        el += 512;
      }
    }
    float4 gA[8], gB[8];
    #pragma unroll
    for (int s = 0; s < 8; ++s) {
      gA[s] = make_float4(0.f, 0.f, 0.f, 0.f);
      gB[s] = make_float4(0.f, 0.f, 0.f, 0.f);
    }
    gates8x2(wbA1, wbB1, hi ? &h1s[0][0] : &xb[cur][0][0], xoff, gA, gB);
    float4 gaA, gaB;
    reduce8to1(gA, lane, gaA);
    reduce8to1(gB, lane, gaB);
    AD4(gaA, b1A); AD4(gaB, b1B);
    float h1A = cellf(gaA, c1A);
    float h1B = cellf(gaB, c1B);
    __syncthreads();                       // (A) all gates-1 reads done
    h1s[p][joA] = h1A;
    h1s[p][joB] = h1B;
    __syncthreads();                       // (B) h1 visible
    #pragma unroll
    for (int s = 0; s < 8; ++s) {
      gA[s] = make_float4(0.f, 0.f, 0.f, 0.f);
      gB[s] = make_float4(0.f, 0.f, 0.f, 0.f);
    }
    gates8x2(wbA2, wbB2, hi ? &h2b[cur][0][0] : &h1s[0][0], xoff, gA, gB);
    reduce8to1(gA, lane, gaA);
    reduce8to1(gB, lane, gaB);
    AD4(gaA, b2A); AD4(gaB, b2B);
    float h2A = cellf(gaA, c2A);
    float h2B = cellf(gaB, c2B);
    h2b[cur ^ 1][p][joA] = h2A;
    h2b[cur ^ 1][p][joB] = h2B;
    LO[((size_t)(((q0 + p) << 4) + t)) * 128 + jA] = h2A;
    LO[((size_t)(((q0 + p) << 4) + t)) * 128 + jB] = h2B;
    cur ^= 1;
  }
}

// ---------------- attention pool + skip MLP + head ----------------
__global__ __launch_bounds__(64)
void attn_kernel(const float* __restrict__ LO, const float* __restrict__ X,
                 const float* __restrict__ Wa, const float* __restrict__ ba,
                 const float* __restrict__ bs1, const float* __restrict__ bs2,
                 const float* __restrict__ bh1, const float* __restrict__ bh2,
                 const float* __restrict__ Wh2, const float* __restrict__ HWT,
                 float* __restrict__ out)
{
  const int q = blockIdx.x, l = threadIdx.x;
  const float* lob = LO + (size_t)q * 2048;
  float loa[16], lobv[16];
  #pragma unroll
  for (int t = 0; t < 16; ++t) {
    loa[t]  = lob[t * 128 + l];
    lobv[t] = lob[t * 128 + 64 + l];
  }
  const float wa = Wa[l], wb = Wa[64 + l];
  float sc[16];
  #pragma unroll
  for (int t = 0; t < 16; ++t) sc[t] = rsum64(loa[t] * wa + lobv[t] * wb) + ba[0];
  float mx = sc[0];
  #pragma unroll
  for (int t = 1; t < 16; ++t) mx = fmaxf(mx, sc[t]);
  float den = 0.f;
  #pragma unroll
  for (int t = 0; t < 16; ++t) { sc[t] = __expf(sc[t] - mx); den += sc[t]; }
  const float inv = 1.f / den;
  float ca = 0.f, cb = 0.f;
  #pragma unroll
  for (int t = 0; t < 16; ++t) {
    float wgt = sc[t] * inv;
    ca = fmaf(wgt, loa[t], ca);
    cb = fmaf(wgt, lobv[t], cb);
  }
  __shared__ float zsh[160];
  __shared__ float hsk[64];
  __shared__ float skin[16];
  zsh[l] = ca; zsh[64 + l] = cb;
  const int bb = q / 1000, nn = q - bb * 1000;
  if (l < 13) skin[l] = X[(size_t)((bb * 16 + 15) * 1000 + nn) * 32 + l];
  __syncthreads();
  float h1 = bs1[l];
  for (int c = 0; c < 13; ++c) h1 = fmaf(skin[c], HWT[c * 64 + l], h1);
  h1 = geluf(h1);
  hsk[l] = h1;
  __syncthreads();
  if (l < 32) {
    float a = bs2[l];
    for (int jj = 0; jj < 64; ++jj) a = fmaf(hsk[jj], HWT[832 + jj * 32 + l], a);
    zsh[128 + l] = a;
  }
  __syncthreads();
  float hh = bh1[l];
  for (int r = 0; r < 160; ++r) hh = fmaf(zsh[r], HWT[2880 + r * 64 + l], hh);
  hh = geluf(hh);
  float s = rsum64(hh * Wh2[l]);
  if (l == 0) out[q] = s + bh2[0];
}

// ---------------- launch ----------------
extern "C" void kernel_launch(void* const* d_in, const int* in_sizes, int n_in,
                              void* d_out, int out_size, void* d_ws, size_t ws_size,
                              hipStream_t stream)
{
  const float* x    = (const float*)d_in[0];
  const int*   ei   = (const int*)d_in[1];
  const float* Wp   = (const float*)d_in[2];
  const float* bp   = (const float*)d_in[3];
  const float* Wl1  = (const float*)d_in[4];
  const float* Wr1  = (const float*)d_in[5];
  const float* a1   = (const float*)d_in[6];
  const float* bg1  = (const float*)d_in[7];
  const float* g1   = (const float*)d_in[8];
  const float* be1  = (const float*)d_in[9];
  const float* m1   = (const float*)d_in[10];
  const float* v1   = (const float*)d_in[11];
  const float* Wl2  = (const float*)d_in[12];
  const float* Wr2  = (const float*)d_in[13];
  const float* a2   = (const float*)d_in[14];
  const float* bg2  = (const float*)d_in[15];
  const float* g2   = (const float*)d_in[16];
  const float* be2  = (const float*)d_in[17];
  const float* m2   = (const float*)d_in[18];
  const float* v2   = (const float*)d_in[19];
  const float* Wih0 = (const float*)d_in[20];
  const float* Whh0 = (const float*)d_in[21];
  const float* bih0 = (const float*)d_in[22];
  const float* bhh0 = (const float*)d_in[23];
  const float* Wih1 = (const float*)d_in[24];
  const float* Whh1 = (const float*)d_in[25];
  const float* bih1 = (const float*)d_in[26];
  const float* bhh1 = (const float*)d_in[27];
  const float* Wa   = (const float*)d_in[28];
  const float* ba   = (const float*)d_in[29];
  const float* Ws1  = (const float*)d_in[30];
  const float* bs1  = (const float*)d_in[31];
  const float* Ws2  = (const float*)d_in[32];
  const float* bs2  = (const float*)d_in[33];
  const float* Wh1  = (const float*)d_in[34];
  const float* bh1  = (const float*)d_in[35];
  const float* Wh2  = (const float*)d_in[36];
  const float* bh2  = (const float*)d_in[37];

  float* ws = (float*)d_ws;
  int* srcD   = (int*)(ws + O_SRCD);
  int* dstD   = (int*)(ws + O_DSTD);
  int* counts = (int*)(ws + O_COUNTS);
  int* offs   = (int*)(ws + O_OFFS);
  int* curs   = (int*)(ws + O_CURS);
  int* esrc   = (int*)(ws + O_EIDX);
  float* PW1  = ws + O_PW1;
  float* PW2  = ws + O_PW2;
  float* PLW  = ws + O_LW;
  float* BC   = ws + O_BCOMB;
  float* ABF  = ws + O_ABF;
  float* HWT  = ws + O_HWT;
  float* XL1  = ws + O_BIG0;
  float* XR1  = ws + O_BIG1;
  float* H1   = ws + O_BIG2;
  float* XP   = ws + O_BIG3;
  float* Hres = ws + O_BIG4;
  float* XL2  = ws + O_BIG0;             // reuse (XL1 dead)
  float* XR2  = ws + O_BIG0 + 8192000u;
  float* LOp  = ws + O_BIG1;             // reuse (XR1 dead)
  float* outp = (float*)d_out;

  prep_edges<<<67, 256, 0, stream>>>(ei, srcD, dstD, counts);
  hist_kernel<<<67, 256, 0, stream>>>(dstD, counts);
  scan_kernel<<<1, 1024, 0, stream>>>(counts, offs, curs);
  fill_kernel<<<67, 256, 0, stream>>>(srcD, dstD, curs, esrc);
  pack_kernel<<<1024, 256, 0, stream>>>(Wl1, Wr1, Wp, Wl2, Wr2,
      Wih0, Whh0, bih0, bhh0, Wih1, Whh1, bih1, bhh1,
      g1, be1, m1, v1, bg1, g2, be2, m2, v2, bg2,
      Ws1, Ws2, Wh1, PW1, PW2, PLW, BC, ABF, HWT);
  proj1_kernel<<<4000, 320, 0, stream>>>(x, PW1, bp, XL1, XR1, XP);
  gat1_kernel<<<dim3(250, 64), 256, 0, stream>>>(XL1, XR1, esrc, offs, a1, ABF, H1);
  proj2_kernel<<<4000, 256, 0, stream>>>(H1, PW2, XL2, XR2);
  gat2_kernel<<<dim3(250, 64), 256, 0, stream>>>(XL2, XR2, esrc, offs, a2, ABF, XP, Hres);
  lstm_kernel<<<500, 512, 0, stream>>>(Hres, PLW, BC, LOp);
  attn_kernel<<<4000, 64, 0, stream>>>(LOp, x, Wa, ba, bs1, bs2, bh1, bh2, Wh2, HWT, outp);
}

// Round 8
// 1186.965 us; speedup vs baseline: 1.8331x; 1.8331x over previous
//
#include <hip/hip_runtime.h>

#define EPS_BN 1e-5f

// ---------------- workspace layout (float-unit offsets) ----------------
#define O_SRCD   0u
#define O_DSTD   17024u
#define O_COUNTS 34048u
#define O_OFFS   35072u
#define O_CURS   36096u
#define O_EIDX   37120u                    // esrc (src node id, CSR-ordered)
#define O_PW1    54144u                    // [32][640]  (Wl1T|Wr1T|WpT)
#define O_PW2    74624u                    // [256][256] (Wl2T|Wr2T)
#define O_LW     140160u                   // PLW: [2][16w][8q][4dk][64lane][4gate]
#define O_BCOMB  402304u                   // [2][128j][4]
#define O_ABF    403328u                   // A1(256)|B1(256)|A2(128)|B2(128)
#define O_HWT    404352u                   // Ws1T(832)|Ws2T(2048)|Wh1T(10240)
#define O_BIG0   417536u                   // XL1  | later XL2,XR2
#define O_BIG1   (O_BIG0 + 16384000u)      // XR1  | later LO
#define O_BIG2   (O_BIG1 + 16384000u)      // H1
#define O_BIG3   (O_BIG2 + 16384000u)      // XP
#define O_BIG4   (O_BIG3 + 8192000u)       // Hres

__device__ __forceinline__ float rsum32(float p) {
  p += __shfl_xor(p, 1);  p += __shfl_xor(p, 2);  p += __shfl_xor(p, 4);
  p += __shfl_xor(p, 8);  p += __shfl_xor(p, 16); return p;
}
__device__ __forceinline__ float rsum64(float p) {
  p = rsum32(p); p += __shfl_xor(p, 32); return p;
}
__device__ __forceinline__ float lrelu(float x) { return x > 0.f ? x : 0.2f * x; }
__device__ __forceinline__ float eluf(float x)  { return x > 0.f ? x : expm1f(x); }
__device__ __forceinline__ float geluf(float x) { return 0.5f * x * (1.f + erff(x * 0.70710678118654752f)); }

// ---------------- prep kernels ----------------
__global__ void prep_edges(const int* __restrict__ ei, int* __restrict__ srcD,
                           int* __restrict__ dstD, int* __restrict__ counts) {
  int i = blockIdx.x * 256 + threadIdx.x;
  if (i < 1024) counts[i] = 0;
  if (i < 17000) {
    int s = (i < 16000) ? ei[i] : (i - 16000);
    int d = (i < 16000) ? ei[16000 + i] : (i - 16000);
    srcD[i] = s; dstD[i] = d;
  }
}
__global__ void hist_kernel(const int* __restrict__ dstD, int* __restrict__ counts) {
  int i = blockIdx.x * 256 + threadIdx.x;
  if (i < 17000) atomicAdd(&counts[dstD[i]], 1);
}
__global__ void scan_kernel(const int* __restrict__ counts, int* __restrict__ offs,
                            int* __restrict__ curs) {
  __shared__ int sh[1024];
  int i = threadIdx.x;
  int v = (i < 1000) ? counts[i] : 0;
  sh[i] = v;
  __syncthreads();
  for (int d = 1; d < 1024; d <<= 1) {
    int t = (i >= d) ? sh[i - d] : 0;
    __syncthreads();
    sh[i] += t;
    __syncthreads();
  }
  if (i < 1000) { offs[i + 1] = sh[i]; curs[i] = sh[i] - v; }
  if (i == 0) offs[0] = 0;
}
__global__ void fill_kernel(const int* __restrict__ srcD, const int* __restrict__ dstD,
                            int* __restrict__ curs, int* __restrict__ esrc) {
  int i = blockIdx.x * 256 + threadIdx.x;
  if (i < 17000) { int p = atomicAdd(&curs[dstD[i]], 1); esrc[p] = srcD[i]; }
}

__global__ void pack_kernel(
    const float* __restrict__ Wl1, const float* __restrict__ Wr1, const float* __restrict__ Wp,
    const float* __restrict__ Wl2, const float* __restrict__ Wr2,
    const float* __restrict__ Wih0, const float* __restrict__ Whh0,
    const float* __restrict__ bih0, const float* __restrict__ bhh0,
    const float* __restrict__ Wih1, const float* __restrict__ Whh1,
    const float* __restrict__ bih1, const float* __restrict__ bhh1,
    const float* __restrict__ g1, const float* __restrict__ be1, const float* __restrict__ m1,
    const float* __restrict__ v1, const float* __restrict__ bg1,
    const float* __restrict__ g2, const float* __restrict__ be2, const float* __restrict__ m2,
    const float* __restrict__ v2, const float* __restrict__ bg2,
    const float* __restrict__ Ws1, const float* __restrict__ Ws2, const float* __restrict__ Wh1,
    float* __restrict__ PW1, float* __restrict__ PW2, float* __restrict__ PLW,
    float* __restrict__ BC, float* __restrict__ ABF, float* __restrict__ HWT)
{
  int i = blockIdx.x * 256 + threadIdx.x;
  if (i < 262144) {  // LSTM packed weights: [L][w16][q8][dk4][lane64][gate4]
    int gate = i & 3, lane = (i >> 2) & 63, dk = (i >> 8) & 3,
        q = (i >> 10) & 7, w = (i >> 13) & 15, L = (i >> 17) & 1;
    int jlo = lane & 7, pp = lane >> 3;
    int mat = pp >> 2, kq = pp & 3;
    int jj = (w << 3) + jlo;
    int kk = (kq << 5) + (q << 2) + dk;
    const float* Wih = L ? Wih1 : Wih0;
    const float* Whh = L ? Whh1 : Whh0;
    PLW[i] = mat ? Whh[(gate * 128 + jj) * 128 + kk]
                 : Wih[(gate * 128 + jj) * 128 + kk];
  }
  if (i < 65536) { int c = i & 255, k = i >> 8;
    PW2[i] = (c < 128) ? Wl2[c * 256 + k] : Wr2[(c - 128) * 256 + k]; }
  if (i < 20480) { int g = i % 640, k = i / 640;
    PW1[i] = (g < 256) ? Wl1[g * 32 + k] : (g < 512) ? Wr1[(g - 256) * 32 + k]
                                                     : Wp[(g - 512) * 32 + k]; }
  if (i < 1024) { int u = i & 3, jj = (i >> 2) & 127, L = i >> 9;
    BC[i] = (L ? bih1 : bih0)[u * 128 + jj] + (L ? bhh1 : bhh0)[u * 128 + jj]; }
  if (i < 768) {
    if (i < 256) ABF[i] = g1[i] * rsqrtf(v1[i] + EPS_BN);
    else if (i < 512) { int c = i - 256; float a = g1[c] * rsqrtf(v1[c] + EPS_BN);
      ABF[i] = (bg1[c] - m1[c]) * a + be1[c]; }
    else if (i < 640) { int c = i - 512; ABF[i] = g2[c] * rsqrtf(v2[c] + EPS_BN); }
    else { int c = i - 640; float a = g2[c] * rsqrtf(v2[c] + EPS_BN);
      ABF[i] = (bg2[c] - m2[c]) * a + be2[c]; }
  }
  if (i < 13120) {
    if (i < 832) { int l = i & 63, c = i >> 6; HWT[i] = Ws1[l * 13 + c]; }
    else if (i < 2880) { int k = i - 832; int l = k & 31, jj = k >> 5; HWT[i] = Ws2[l * 64 + jj]; }
    else { int k = i - 2880; int l = k & 63, r = k >> 6; HWT[i] = Wh1[l * 160 + r]; }
  }
}

// ---------------- projection 1: x -> xl1(256) | xr1(256) | xp(128) ----------------
__global__ __launch_bounds__(320)
void proj1_kernel(const float* __restrict__ X, const float* __restrict__ PW1,
                  const float* __restrict__ bp,
                  float* __restrict__ XL1, float* __restrict__ XR1, float* __restrict__ XP)
{
  __shared__ __align__(16) float xs[32][16];
  const int tid = threadIdx.x;
  const int r0 = blockIdx.x * 16;
  for (int el = tid; el < 512; el += 320) {
    int r = el >> 5, k = el & 31;
    xs[k][r] = X[(size_t)(r0 + r) * 32 + k];
  }
  __syncthreads();
  const int gA = tid, gB = tid + 320;
  float accA[16], accB[16];
  const float iB = (gB >= 512) ? bp[gB - 512] : 0.f;
  #pragma unroll
  for (int r = 0; r < 16; ++r) { accA[r] = 0.f; accB[r] = iB; }
  for (int k = 0; k < 32; ++k) {
    float wA = PW1[k * 640 + gA], wB = PW1[k * 640 + gB];
    float xv[16];
    #pragma unroll
    for (int q = 0; q < 4; ++q)
      *reinterpret_cast<float4*>(&xv[q * 4]) = *reinterpret_cast<const float4*>(&xs[k][q * 4]);
    #pragma unroll
    for (int r = 0; r < 16; ++r) {
      accA[r] = fmaf(wA, xv[r], accA[r]);
      accB[r] = fmaf(wB, xv[r], accB[r]);
    }
  }
  for (int r = 0; r < 16; ++r) {
    size_t row = r0 + r;
    if (gA < 256) XL1[row * 256 + gA] = accA[r];
    else          XR1[row * 256 + (gA - 256)] = accA[r];
    if (gB < 512) XR1[row * 256 + (gB - 256)] = accB[r];
    else          XP[row * 128 + (gB - 512)] = accB[r];
  }
}

// ---------------- GAT layer 1 fused (2 heads, d=128) ----------------
__global__ __launch_bounds__(256)
void gat1_kernel(const float* __restrict__ XL, const float* __restrict__ XR,
                 const int* __restrict__ esrc,
                 const int* __restrict__ offs, const float* __restrict__ a1,
                 const float* __restrict__ ABF, float* __restrict__ H1)
{
  const int lane = threadIdx.x & 63;
  const int wv = threadIdx.x >> 6;
  const int n = blockIdx.x * 4 + wv;
  const int b = blockIdx.y;
  const int half = lane >> 5;
  __shared__ float lsh[4][128];
  const int beg = offs[n];
  const int deg = offs[n + 1] - beg;
  const float4 a4 = reinterpret_cast<const float4*>(a1)[lane];
  const float4* XLb = reinterpret_cast<const float4*>(XL) + (size_t)b * 64000;
  const float4 xr4 = reinterpret_cast<const float4*>(XR + (size_t)(b * 1000 + n) * 256)[lane];
  float m = -INFINITY, ssum = 0.f;
  {
    int sC = esrc[beg];
    float4 xc = XLb[(size_t)sC * 64 + lane];
    for (int i = 0; i < deg; ++i) {
      int nx = (i + 1 < deg) ? (i + 1) : i;
      int sN = esrc[beg + nx];
      float4 xn = XLb[(size_t)sN * 64 + lane];
      float p = lrelu(xc.x + xr4.x) * a4.x + lrelu(xc.y + xr4.y) * a4.y
              + lrelu(xc.z + xr4.z) * a4.z + lrelu(xc.w + xr4.w) * a4.w;
      p = rsum32(p);
      if (i < 64 && (lane & 31) == 0) lsh[wv][2 * i + half] = p;
      float mn = fmaxf(m, p);
      ssum = ssum * __expf(m - mn) + __expf(p - mn);
      m = mn;
      xc = xn;
    }
  }
  const float inv = 1.f / ssum;
  __builtin_amdgcn_wave_barrier();
  float4 acc = make_float4(0.f, 0.f, 0.f, 0.f);
  {
    int sC = esrc[beg];
    float4 xc = XLb[(size_t)sC * 64 + lane];
    for (int i = 0; i < deg; ++i) {
      int nx = (i + 1 < deg) ? (i + 1) : i;
      int sN = esrc[beg + nx];
      float4 xn = XLb[(size_t)sN * 64 + lane];
      float lg;
      if (i < 64) lg = lsh[wv][2 * i + half];
      else {
        float p = lrelu(xc.x + xr4.x) * a4.x + lrelu(xc.y + xr4.y) * a4.y
                + lrelu(xc.z + xr4.z) * a4.z + lrelu(xc.w + xr4.w) * a4.w;
        lg = rsum32(p);
      }
      const float al = __expf(lg - m) * inv;
      acc.x = fmaf(al, xc.x, acc.x);
      acc.y = fmaf(al, xc.y, acc.y);
      acc.z = fmaf(al, xc.z, acc.z);
      acc.w = fmaf(al, xc.w, acc.w);
      xc = xn;
    }
  }
  const float4 A4 = reinterpret_cast<const float4*>(ABF)[lane];
  const float4 B4 = reinterpret_cast<const float4*>(ABF + 256)[lane];
  float4 o;
  o.x = eluf(fmaf(acc.x, A4.x, B4.x));
  o.y = eluf(fmaf(acc.y, A4.y, B4.y));
  o.z = eluf(fmaf(acc.z, A4.z, B4.z));
  o.w = eluf(fmaf(acc.w, A4.w, B4.w));
  reinterpret_cast<float4*>(H1 + (size_t)(b * 1000 + n) * 256)[lane] = o;
}

// ---------------- projection 2: h1(256) -> xl2(128)|xr2(128) ----------------
__global__ __launch_bounds__(256)
void proj2_kernel(const float* __restrict__ H1, const float* __restrict__ PW2,
                  float* __restrict__ XL2, float* __restrict__ XR2)
{
  __shared__ __align__(16) float xs[256][20];
  const int tid = threadIdx.x;
  const int r0 = blockIdx.x * 16;
  for (int el = tid; el < 4096; el += 256) {
    int k = el & 255, r = el >> 8;
    xs[k][r] = H1[(size_t)(r0 + r) * 256 + k];
  }
  __syncthreads();
  float acc[16];
  #pragma unroll
  for (int r = 0; r < 16; ++r) acc[r] = 0.f;
  for (int k = 0; k < 256; ++k) {
    float wgt = PW2[k * 256 + tid];
    float xv[16];
    #pragma unroll
    for (int q = 0; q < 4; ++q)
      *reinterpret_cast<float4*>(&xv[q * 4]) = *reinterpret_cast<const float4*>(&xs[k][q * 4]);
    #pragma unroll
    for (int r = 0; r < 16; ++r) acc[r] = fmaf(wgt, xv[r], acc[r]);
  }
  float* dst = (tid < 128) ? XL2 : XR2;
  const int col = tid & 127;
  for (int r = 0; r < 16; ++r)
    dst[(size_t)(r0 + r) * 128 + col] = acc[r];
}

// ---------------- GAT layer 2 fused (1 head) + BN/ELU + residual ----------------
__global__ __launch_bounds__(256)
void gat2_kernel(const float* __restrict__ XL, const float* __restrict__ XR,
                 const int* __restrict__ esrc,
                 const int* __restrict__ offs, const float* __restrict__ a2,
                 const float* __restrict__ ABF, const float* __restrict__ XP,
                 float* __restrict__ Hout)
{
  const int lane = threadIdx.x & 63;
  const int wv = threadIdx.x >> 6;
  const int n = blockIdx.x * 4 + wv;
  const int b = blockIdx.y;
  __shared__ float lsh[4][96];
  const int beg = offs[n];
  const int deg = offs[n + 1] - beg;
  const float2 av = reinterpret_cast<const float2*>(a2)[lane];
  const float2* XLb = reinterpret_cast<const float2*>(XL) + (size_t)b * 64000;
  const float2 xr2 = reinterpret_cast<const float2*>(XR + (size_t)(b * 1000 + n) * 128)[lane];
  float m = -INFINITY, ssum = 0.f;
  {
    int sC = esrc[beg];
    float2 xc = XLb[(size_t)sC * 64 + lane];
    for (int i = 0; i < deg; ++i) {
      int nx = (i + 1 < deg) ? (i + 1) : i;
      int sN = esrc[beg + nx];
      float2 xn = XLb[(size_t)sN * 64 + lane];
      float p = lrelu(xc.x + xr2.x) * av.x + lrelu(xc.y + xr2.y) * av.y;
      p = rsum64(p);
      if (i < 96 && lane == 0) lsh[wv][i] = p;
      float mn = fmaxf(m, p);
      ssum = ssum * __expf(m - mn) + __expf(p - mn);
      m = mn;
      xc = xn;
    }
  }
  const float inv = 1.f / ssum;
  __builtin_amdgcn_wave_barrier();
  float2 acc = make_float2(0.f, 0.f);
  {
    int sC = esrc[beg];
    float2 xc = XLb[(size_t)sC * 64 + lane];
    for (int i = 0; i < deg; ++i) {
      int nx = (i + 1 < deg) ? (i + 1) : i;
      int sN = esrc[beg + nx];
      float2 xn = XLb[(size_t)sN * 64 + lane];
      float lg;
      if (i < 96) lg = lsh[wv][i];
      else {
        float p = lrelu(xc.x + xr2.x) * av.x + lrelu(xc.y + xr2.y) * av.y;
        lg = rsum64(p);
      }
      const float al = __expf(lg - m) * inv;
      acc.x = fmaf(al, xc.x, acc.x);
      acc.y = fmaf(al, xc.y, acc.y);
      xc = xn;
    }
  }
  const float2 A2 = reinterpret_cast<const float2*>(ABF + 512)[lane];
  const float2 B2 = reinterpret_cast<const float2*>(ABF + 640)[lane];
  const float2 xp = reinterpret_cast<const float2*>(XP + (size_t)(b * 1000 + n) * 128)[lane];
  float2 o;
  o.x = eluf(fmaf(acc.x, A2.x, B2.x)) + xp.x;
  o.y = eluf(fmaf(acc.y, A2.y, B2.y)) + xp.y;
  reinterpret_cast<float2*>(Hout + (size_t)(b * 1000 + n) * 128)[lane] = o;
}

// ---------------- fused 2-layer LSTM (8-way k-split, 1 unit/thread, 8 seq/block) ----
#define FMA4(A, W, S) { (A).x = fmaf((W).x, (S), (A).x); (A).y = fmaf((W).y, (S), (A).y); \
                        (A).z = fmaf((W).z, (S), (A).z); (A).w = fmaf((W).w, (S), (A).w); }
#define AD4(a, b) { (a).x += (b).x; (a).y += (b).y; (a).z += (b).z; (a).w += (b).w; }
#define LROW 140

__device__ __forceinline__ float4 shflx4(float4 v, int msk) {
  float4 r;
  r.x = __shfl_xor(v.x, msk); r.y = __shfl_xor(v.y, msk);
  r.z = __shfl_xor(v.z, msk); r.w = __shfl_xor(v.w, msk);
  return r;
}

// One j-unit per thread: acc g[8] = 32 VGPRs, 4 weight float4 live = 16; whole
// working set ~62 regs -> fits the 64-arch-VGPR allocation this toolchain
// produces at a 4-waves/EU target (R3/R4/R7 evidence: 4/EU => 64 arch VGPRs,
// regardless of requested budget; R5/R6: (2,2) gave ~128 arch but self-capped
// occupancy at 2 waves/EU).
__device__ __forceinline__ void gates8x1(const float4* __restrict__ wb,
                                         const float* XS, int xoff,
                                         float4 (&g)[8])
{
  #pragma unroll 2
  for (int q = 0; q < 8; ++q) {
    const float4* wq = wb + q * 256;
    float4 w0 = wq[0], w1 = wq[64], w2 = wq[128], w3 = wq[192];
    const float* xp = XS + xoff + (q << 2);
    #pragma unroll
    for (int s = 0; s < 8; ++s) {
      float4 xv = *reinterpret_cast<const float4*>(xp + s * LROW);
      FMA4(g[s], w0, xv.x); FMA4(g[s], w1, xv.y);
      FMA4(g[s], w2, xv.z); FMA4(g[s], w3, xv.w);
    }
  }
}

// narrowing 3-round butterfly over p = lane>>3; result: seq p (one per slice)
__device__ __forceinline__ void reduce8to1(float4 (&g)[8], int lane, float4& ga)
{
  const bool b4 = (lane & 32) != 0, b2 = (lane & 16) != 0, b1 = (lane & 8) != 0;
  float4 t[4];
  #pragma unroll
  for (int i = 0; i < 4; ++i) {
    float4 keep = b4 ? g[4 + i] : g[i];
    float4 send = b4 ? g[i] : g[4 + i];
    float4 r = shflx4(send, 32);
    AD4(keep, r); t[i] = keep;
  }
  float4 u[2];
  #pragma unroll
  for (int i = 0; i < 2; ++i) {
    float4 keep = b2 ? t[2 + i] : t[i];
    float4 send = b2 ? t[i] : t[2 + i];
    float4 r = shflx4(send, 16);
    AD4(keep, r); u[i] = keep;
  }
  {
    float4 keep = b1 ? u[1] : u[0];
    float4 send = b1 ? u[0] : u[1];
    float4 r = shflx4(send, 8);
    AD4(keep, r); ga = keep;
  }
}

__device__ __forceinline__ float cellf(float4 g, float& c) {
  const float ig = 1.f / (1.f + __expf(-g.x));
  const float fg = 1.f / (1.f + __expf(-g.y));
  const float gg = tanhf(g.z);
  const float og = 1.f / (1.f + __expf(-g.w));
  c = fmaf(fg, c, ig * gg);
  return og * tanhf(c);
}

// 1024 threads = 16 waves, 8 seqs/block, 500 blocks -> 1 block/CU, 4 waves/EU.
__global__ __launch_bounds__(1024)
__attribute__((amdgpu_waves_per_eu(4, 4)))
void lstm_kernel(const float* __restrict__ Hin, const float* __restrict__ PLW,
                 const float* __restrict__ BC, float* __restrict__ LO)
{
  __shared__ __align__(16) float xb[2][8][LROW];
  __shared__ __align__(16) float h1s[8][LROW];
  __shared__ __align__(16) float h2b[2][8][LROW];
  const int tid = threadIdx.x;
  const int lane = tid & 63;
  const int w = tid >> 6;                  // 0..15 (unit block)
  const int jlo = lane & 7;
  const int p = lane >> 3;                 // 0..7: (k,mat) slice; mat = p>>2
  const int j = (w << 3) + jlo;            // unit 0..127
  const int xoff = 36 * (p & 3);
  const bool hi = p >= 4;                  // hh side
  const int jo = j + ((j >> 5) << 2);      // skewed LDS column
  const int q0 = blockIdx.x << 3;          // 8 seqs per block
  for (int i = tid; i < 8 * LROW; i += 1024) {
    (&h1s[0][0])[i] = 0.f;
  }
  for (int i = tid; i < 2 * 8 * LROW; i += 1024) {
    (&h2b[0][0][0])[i] = 0.f;
  }
  {
    int s = tid >> 7, k = tid & 127;        // 1024 elems, one per thread
    xb[0][s][k + ((k >> 5) << 2)] = Hin[((size_t)(((q0 + s) << 4))) * 128 + k];
  }
  const float4 b1 = *reinterpret_cast<const float4*>(BC + (j << 2));
  const float4 b2 = *reinterpret_cast<const float4*>(BC + 512 + (j << 2));
  const float4* PLW4 = reinterpret_cast<const float4*>(PLW);
  const float4* wb1 = PLW4 + (w << 11) + lane;
  const float4* wb2 = wb1 + 32768;
  float c1 = 0.f, c2 = 0.f;
  __syncthreads();
  int cur = 0;
  for (int t = 0; t < 16; ++t) {
    if (t < 15) {
      int s = tid >> 7, k = tid & 127;
      xb[cur ^ 1][s][k + ((k >> 5) << 2)] =
          Hin[((size_t)(((q0 + s) << 4) + (t + 1))) * 128 + k];
    }
    float4 g[8];
    #pragma unroll
    for (int s = 0; s < 8; ++s) g[s] = make_float4(0.f, 0.f, 0.f, 0.f);
    gates8x1(wb1, hi ? &h1s[0][0] : &xb[cur][0][0], xoff, g);
    float4 ga;
    reduce8to1(g, lane, ga);
    AD4(ga, b1);
    float h1 = cellf(ga, c1);
    __syncthreads();                       // (A) all gates-1 reads done
    h1s[p][jo] = h1;
    __syncthreads();                       // (B) h1 visible
    #pragma unroll
    for (int s = 0; s < 8; ++s) g[s] = make_float4(0.f, 0.f, 0.f, 0.f);
    gates8x1(wb2, hi ? &h2b[cur][0][0] : &h1s[0][0], xoff, g);
    reduce8to1(g, lane, ga);
    AD4(ga, b2);
    float h2 = cellf(ga, c2);
    h2b[cur ^ 1][p][jo] = h2;
    LO[((size_t)(((q0 + p) << 4) + t)) * 128 + j] = h2;
    cur ^= 1;
  }
}

// ---------------- attention pool + skip MLP + head ----------------
__global__ __launch_bounds__(64)
void attn_kernel(const float* __restrict__ LO, const float* __restrict__ X,
                 const float* __restrict__ Wa, const float* __restrict__ ba,
                 const float* __restrict__ bs1, const float* __restrict__ bs2,
                 const float* __restrict__ bh1, const float* __restrict__ bh2,
                 const float* __restrict__ Wh2, const float* __restrict__ HWT,
                 float* __restrict__ out)
{
  const int q = blockIdx.x, l = threadIdx.x;
  const float* lob = LO + (size_t)q * 2048;
  float loa[16], lobv[16];
  #pragma unroll
  for (int t = 0; t < 16; ++t) {
    loa[t]  = lob[t * 128 + l];
    lobv[t] = lob[t * 128 + 64 + l];
  }
  const float wa = Wa[l], wb = Wa[64 + l];
  float sc[16];
  #pragma unroll
  for (int t = 0; t < 16; ++t) sc[t] = rsum64(loa[t] * wa + lobv[t] * wb) + ba[0];
  float mx = sc[0];
  #pragma unroll
  for (int t = 1; t < 16; ++t) mx = fmaxf(mx, sc[t]);
  float den = 0.f;
  #pragma unroll
  for (int t = 0; t < 16; ++t) { sc[t] = __expf(sc[t] - mx); den += sc[t]; }
  const float inv = 1.f / den;
  float ca = 0.f, cb = 0.f;
  #pragma unroll
  for (int t = 0; t < 16; ++t) {
    float wgt = sc[t] * inv;
    ca = fmaf(wgt, loa[t], ca);
    cb = fmaf(wgt, lobv[t], cb);
  }
  __shared__ float zsh[160];
  __shared__ float hsk[64];
  __shared__ float skin[16];
  zsh[l] = ca; zsh[64 + l] = cb;
  const int bb = q / 1000, nn = q - bb * 1000;
  if (l < 13) skin[l] = X[(size_t)((bb * 16 + 15) * 1000 + nn) * 32 + l];
  __syncthreads();
  float h1 = bs1[l];
  for (int c = 0; c < 13; ++c) h1 = fmaf(skin[c], HWT[c * 64 + l], h1);
  h1 = geluf(h1);
  hsk[l] = h1;
  __syncthreads();
  if (l < 32) {
    float a = bs2[l];
    for (int jj = 0; jj < 64; ++jj) a = fmaf(hsk[jj], HWT[832 + jj * 32 + l], a);
    zsh[128 + l] = a;
  }
  __syncthreads();
  float hh = bh1[l];
  for (int r = 0; r < 160; ++r) hh = fmaf(zsh[r], HWT[2880 + r * 64 + l], hh);
  hh = geluf(hh);
  float s = rsum64(hh * Wh2[l]);
  if (l == 0) out[q] = s + bh2[0];
}

// ---------------- launch ----------------
extern "C" void kernel_launch(void* const* d_in, const int* in_sizes, int n_in,
                              void* d_out, int out_size, void* d_ws, size_t ws_size,
                              hipStream_t stream)
{
  const float* x    = (const float*)d_in[0];
  const int*   ei   = (const int*)d_in[1];
  const float* Wp   = (const float*)d_in[2];
  const float* bp   = (const float*)d_in[3];
  const float* Wl1  = (const float*)d_in[4];
  const float* Wr1  = (const float*)d_in[5];
  const float* a1   = (const float*)d_in[6];
  const float* bg1  = (const float*)d_in[7];
  const float* g1   = (const float*)d_in[8];
  const float* be1  = (const float*)d_in[9];
  const float* m1   = (const float*)d_in[10];
  const float* v1   = (const float*)d_in[11];
  const float* Wl2  = (const float*)d_in[12];
  const float* Wr2  = (const float*)d_in[13];
  const float* a2   = (const float*)d_in[14];
  const float* bg2  = (const float*)d_in[15];
  const float* g2   = (const float*)d_in[16];
  const float* be2  = (const float*)d_in[17];
  const float* m2   = (const float*)d_in[18];
  const float* v2   = (const float*)d_in[19];
  const float* Wih0 = (const float*)d_in[20];
  const float* Whh0 = (const float*)d_in[21];
  const float* bih0 = (const float*)d_in[22];
  const float* bhh0 = (const float*)d_in[23];
  const float* Wih1 = (const float*)d_in[24];
  const float* Whh1 = (const float*)d_in[25];
  const float* bih1 = (const float*)d_in[26];
  const float* bhh1 = (const float*)d_in[27];
  const float* Wa   = (const float*)d_in[28];
  const float* ba   = (const float*)d_in[29];
  const float* Ws1  = (const float*)d_in[30];
  const float* bs1  = (const float*)d_in[31];
  const float* Ws2  = (const float*)d_in[32];
  const float* bs2  = (const float*)d_in[33];
  const float* Wh1  = (const float*)d_in[34];
  const float* bh1  = (const float*)d_in[35];
  const float* Wh2  = (const float*)d_in[36];
  const float* bh2  = (const float*)d_in[37];

  float* ws = (float*)d_ws;
  int* srcD   = (int*)(ws + O_SRCD);
  int* dstD   = (int*)(ws + O_DSTD);
  int* counts = (int*)(ws + O_COUNTS);
  int* offs   = (int*)(ws + O_OFFS);
  int* curs   = (int*)(ws + O_CURS);
  int* esrc   = (int*)(ws + O_EIDX);
  float* PW1  = ws + O_PW1;
  float* PW2  = ws + O_PW2;
  float* PLW  = ws + O_LW;
  float* BC   = ws + O_BCOMB;
  float* ABF  = ws + O_ABF;
  float* HWT  = ws + O_HWT;
  float* XL1  = ws + O_BIG0;
  float* XR1  = ws + O_BIG1;
  float* H1   = ws + O_BIG2;
  float* XP   = ws + O_BIG3;
  float* Hres = ws + O_BIG4;
  float* XL2  = ws + O_BIG0;             // reuse (XL1 dead)
  float* XR2  = ws + O_BIG0 + 8192000u;
  float* LOp  = ws + O_BIG1;             // reuse (XR1 dead)
  float* outp = (float*)d_out;

  prep_edges<<<67, 256, 0, stream>>>(ei, srcD, dstD, counts);
  hist_kernel<<<67, 256, 0, stream>>>(dstD, counts);
  scan_kernel<<<1, 1024, 0, stream>>>(counts, offs, curs);
  fill_kernel<<<67, 256, 0, stream>>>(srcD, dstD, curs, esrc);
  pack_kernel<<<1024, 256, 0, stream>>>(Wl1, Wr1, Wp, Wl2, Wr2,
      Wih0, Whh0, bih0, bhh0, Wih1, Whh1, bih1, bhh1,
      g1, be1, m1, v1, bg1, g2, be2, m2, v2, bg2,
      Ws1, Ws2, Wh1, PW1, PW2, PLW, BC, ABF, HWT);
  proj1_kernel<<<4000, 320, 0, stream>>>(x, PW1, bp, XL1, XR1, XP);
  gat1_kernel<<<dim3(250, 64), 256, 0, stream>>>(XL1, XR1, esrc, offs, a1, ABF, H1);
  proj2_kernel<<<4000, 256, 0, stream>>>(H1, PW2, XL2, XR2);
  gat2_kernel<<<dim3(250, 64), 256, 0, stream>>>(XL2, XR2, esrc, offs, a2, ABF, XP, Hres);
  lstm_kernel<<<500, 1024, 0, stream>>>(Hres, PLW, BC, LOp);
  attn_kernel<<<4000, 64, 0, stream>>>(LOp, x, Wa, ba, bs1, bs2, bh1, bh2, Wh2, HWT, outp);
}

// Round 9
// 1040.577 us; speedup vs baseline: 2.0910x; 1.1407x over previous
//
#include <hip/hip_runtime.h>

#define EPS_BN 1e-5f

typedef __attribute__((ext_vector_type(8))) short bf16x8;
typedef __attribute__((ext_vector_type(4))) float f32x4;

// ---------------- workspace layout (float-unit offsets) ----------------
#define O_SRCD   0u
#define O_DSTD   17024u
#define O_COUNTS 34048u
#define O_OFFS   35072u
#define O_CURS   36096u
#define O_EIDX   37120u                    // esrc (src node id, CSR-ordered)
#define O_PW1    54144u                    // [32][640]  (Wl1T|Wr1T|WpT)
#define O_PW2    74624u                    // [256][256] (Wl2T|Wr2T)
#define O_LW     140160u                   // PHH (131072 f) + PWB (262144 bf16 = 131072 f-slots)
#define O_BCOMB  402304u                   // [2][128j][4]  (gp order)
#define O_ABF    403328u                   // A1(256)|B1(256)|A2(128)|B2(128)
#define O_HWT    404352u                   // Ws1T(832)|Ws2T(2048)|Wh1T(10240)
#define O_BIG0   417536u                   // XL1 | XL2,XR2 | pre (spans BIG0+BIG1)
#define O_BIG1   (O_BIG0 + 16384000u)      // XR1 | pre upper half
#define O_BIG2   (O_BIG1 + 16384000u)      // H1  | h1seq
#define O_BIG3   (O_BIG2 + 16384000u)      // XP  | LO
#define O_BIG4   (O_BIG3 + 8192000u)       // Hres

__device__ __forceinline__ float rsum32(float p) {
  p += __shfl_xor(p, 1);  p += __shfl_xor(p, 2);  p += __shfl_xor(p, 4);
  p += __shfl_xor(p, 8);  p += __shfl_xor(p, 16); return p;
}
__device__ __forceinline__ float rsum64(float p) {
  p = rsum32(p); p += __shfl_xor(p, 32); return p;
}
__device__ __forceinline__ float lrelu(float x) { return x > 0.f ? x : 0.2f * x; }
__device__ __forceinline__ float eluf(float x)  { return x > 0.f ? x : expm1f(x); }
__device__ __forceinline__ float geluf(float x) { return 0.5f * x * (1.f + erff(x * 0.70710678118654752f)); }
__device__ __forceinline__ unsigned short f2bf(float f) {
  unsigned int u = __float_as_uint(f);
  u += 0x7FFFu + ((u >> 16) & 1u);
  return (unsigned short)(u >> 16);
}
__device__ __forceinline__ float bf2f(unsigned short h) {
  return __uint_as_float(((unsigned int)h) << 16);
}

// ---------------- prep kernels ----------------
__global__ void prep_edges(const int* __restrict__ ei, int* __restrict__ srcD,
                           int* __restrict__ dstD, int* __restrict__ counts) {
  int i = blockIdx.x * 256 + threadIdx.x;
  if (i < 1024) counts[i] = 0;
  if (i < 17000) {
    int s = (i < 16000) ? ei[i] : (i - 16000);
    int d = (i < 16000) ? ei[16000 + i] : (i - 16000);
    srcD[i] = s; dstD[i] = d;
  }
}
__global__ void hist_kernel(const int* __restrict__ dstD, int* __restrict__ counts) {
  int i = blockIdx.x * 256 + threadIdx.x;
  if (i < 17000) atomicAdd(&counts[dstD[i]], 1);
}
__global__ void scan_kernel(const int* __restrict__ counts, int* __restrict__ offs,
                            int* __restrict__ curs) {
  __shared__ int sh[1024];
  int i = threadIdx.x;
  int v = (i < 1000) ? counts[i] : 0;
  sh[i] = v;
  __syncthreads();
  for (int d = 1; d < 1024; d <<= 1) {
    int t = (i >= d) ? sh[i - d] : 0;
    __syncthreads();
    sh[i] += t;
    __syncthreads();
  }
  if (i < 1000) { offs[i + 1] = sh[i]; curs[i] = sh[i] - v; }
  if (i == 0) offs[0] = 0;
}
__global__ void fill_kernel(const int* __restrict__ srcD, const int* __restrict__ dstD,
                            int* __restrict__ curs, int* __restrict__ esrc) {
  int i = blockIdx.x * 256 + threadIdx.x;
  if (i < 17000) { int p = atomicAdd(&curs[dstD[i]], 1); esrc[p] = srcD[i]; }
}

// PHH: hh weights [L][w16][q4][dk4][lane64][gate4], k = p*16 + q*4 + dk (p = lane>>3)
// PWB: ih weights split-bf16 MFMA B-frags [L][split][kc4][gt32][lane64][e8]
//      gp = gt*16 + (lane&15), k = kc*32 + (lane>>4)*8 + e, gp = j*4+gate
__global__ void pack_kernel(
    const float* __restrict__ Wl1, const float* __restrict__ Wr1, const float* __restrict__ Wp,
    const float* __restrict__ Wl2, const float* __restrict__ Wr2,
    const float* __restrict__ Wih0, const float* __restrict__ Whh0,
    const float* __restrict__ bih0, const float* __restrict__ bhh0,
    const float* __restrict__ Wih1, const float* __restrict__ Whh1,
    const float* __restrict__ bih1, const float* __restrict__ bhh1,
    const float* __restrict__ g1, const float* __restrict__ be1, const float* __restrict__ m1,
    const float* __restrict__ v1, const float* __restrict__ bg1,
    const float* __restrict__ g2, const float* __restrict__ be2, const float* __restrict__ m2,
    const float* __restrict__ v2, const float* __restrict__ bg2,
    const float* __restrict__ Ws1, const float* __restrict__ Ws2, const float* __restrict__ Wh1,
    float* __restrict__ PW1, float* __restrict__ PW2, float* __restrict__ PHH,
    unsigned short* __restrict__ PWBu,
    float* __restrict__ BC, float* __restrict__ ABF, float* __restrict__ HWT)
{
  int i = blockIdx.x * 256 + threadIdx.x;
  if (i < 131072) {  // PHH
    int gate = i & 3, lane = (i >> 2) & 63, dk = (i >> 8) & 3,
        q = (i >> 10) & 3, w = (i >> 12) & 15, L = (i >> 16) & 1;
    int jlo = lane & 7, p = lane >> 3;
    int jj = (w << 3) + jlo;
    int kk = (p << 4) + (q << 2) + dk;
    const float* Whh = L ? Whh1 : Whh0;
    PHH[i] = Whh[(gate * 128 + jj) * 128 + kk];
  }
  if (i < 262144) {  // PWB split-bf16
    int e = i & 7, lane = (i >> 3) & 63, gt = (i >> 9) & 31,
        kc = (i >> 14) & 3, sp = (i >> 16) & 1, L = (i >> 17) & 1;
    int gp = (gt << 4) + (lane & 15);
    int jj = gp >> 2, gate = gp & 3;
    int kk = (kc << 5) + ((lane >> 4) << 3) + e;
    const float* Wih = L ? Wih1 : Wih0;
    float wv = Wih[(gate * 128 + jj) * 128 + kk];
    unsigned short hi = f2bf(wv);
    PWBu[i] = (sp == 0) ? hi : f2bf(wv - bf2f(hi));
  }
  if (i < 65536) { int c = i & 255, k = i >> 8;
    PW2[i] = (c < 128) ? Wl2[c * 256 + k] : Wr2[(c - 128) * 256 + k]; }
  if (i < 20480) { int g = i % 640, k = i / 640;
    PW1[i] = (g < 256) ? Wl1[g * 32 + k] : (g < 512) ? Wr1[(g - 256) * 32 + k]
                                                     : Wp[(g - 512) * 32 + k]; }
  if (i < 1024) { int u = i & 3, jj = (i >> 2) & 127, L = i >> 9;
    BC[i] = (L ? bih1 : bih0)[u * 128 + jj] + (L ? bhh1 : bhh0)[u * 128 + jj]; }
  if (i < 768) {
    if (i < 256) ABF[i] = g1[i] * rsqrtf(v1[i] + EPS_BN);
    else if (i < 512) { int c = i - 256; float a = g1[c] * rsqrtf(v1[c] + EPS_BN);
      ABF[i] = (bg1[c] - m1[c]) * a + be1[c]; }
    else if (i < 640) { int c = i - 512; ABF[i] = g2[c] * rsqrtf(v2[c] + EPS_BN); }
    else { int c = i - 640; float a = g2[c] * rsqrtf(v2[c] + EPS_BN);
      ABF[i] = (bg2[c] - m2[c]) * a + be2[c]; }
  }
  if (i < 13120) {
    if (i < 832) { int l = i & 63, c = i >> 6; HWT[i] = Ws1[l * 13 + c]; }
    else if (i < 2880) { int k = i - 832; int l = k & 31, jj = k >> 5; HWT[i] = Ws2[l * 64 + jj]; }
    else { int k = i - 2880; int l = k & 63, r = k >> 6; HWT[i] = Wh1[l * 160 + r]; }
  }
}

// ---------------- projection 1: x -> xl1(256) | xr1(256) | xp(128) ----------------
__global__ __launch_bounds__(320)
void proj1_kernel(const float* __restrict__ X, const float* __restrict__ PW1,
                  const float* __restrict__ bp,
                  float* __restrict__ XL1, float* __restrict__ XR1, float* __restrict__ XP)
{
  __shared__ __align__(16) float xs[32][16];
  const int tid = threadIdx.x;
  const int r0 = blockIdx.x * 16;
  for (int el = tid; el < 512; el += 320) {
    int r = el >> 5, k = el & 31;
    xs[k][r] = X[(size_t)(r0 + r) * 32 + k];
  }
  __syncthreads();
  const int gA = tid, gB = tid + 320;
  float accA[16], accB[16];
  const float iB = (gB >= 512) ? bp[gB - 512] : 0.f;
  #pragma unroll
  for (int r = 0; r < 16; ++r) { accA[r] = 0.f; accB[r] = iB; }
  for (int k = 0; k < 32; ++k) {
    float wA = PW1[k * 640 + gA], wB = PW1[k * 640 + gB];
    float xv[16];
    #pragma unroll
    for (int q = 0; q < 4; ++q)
      *reinterpret_cast<float4*>(&xv[q * 4]) = *reinterpret_cast<const float4*>(&xs[k][q * 4]);
    #pragma unroll
    for (int r = 0; r < 16; ++r) {
      accA[r] = fmaf(wA, xv[r], accA[r]);
      accB[r] = fmaf(wB, xv[r], accB[r]);
    }
  }
  for (int r = 0; r < 16; ++r) {
    size_t row = r0 + r;
    if (gA < 256) XL1[row * 256 + gA] = accA[r];
    else          XR1[row * 256 + (gA - 256)] = accA[r];
    if (gB < 512) XR1[row * 256 + (gB - 256)] = accB[r];
    else          XP[row * 128 + (gB - 512)] = accB[r];
  }
}

// ---------------- GAT layer 1 fused (2 heads, d=128) ----------------
__global__ __launch_bounds__(256)
void gat1_kernel(const float* __restrict__ XL, const float* __restrict__ XR,
                 const int* __restrict__ esrc,
                 const int* __restrict__ offs, const float* __restrict__ a1,
                 const float* __restrict__ ABF, float* __restrict__ H1)
{
  const int lane = threadIdx.x & 63;
  const int wv = threadIdx.x >> 6;
  const int n = blockIdx.x * 4 + wv;
  const int b = blockIdx.y;
  const int half = lane >> 5;
  __shared__ float lsh[4][128];
  const int beg = offs[n];
  const int deg = offs[n + 1] - beg;
  const float4 a4 = reinterpret_cast<const float4*>(a1)[lane];
  const float4* XLb = reinterpret_cast<const float4*>(XL) + (size_t)b * 64000;
  const float4 xr4 = reinterpret_cast<const float4*>(XR + (size_t)(b * 1000 + n) * 256)[lane];
  float m = -INFINITY, ssum = 0.f;
  {
    int sC = esrc[beg];
    float4 xc = XLb[(size_t)sC * 64 + lane];
    for (int i = 0; i < deg; ++i) {
      int nx = (i + 1 < deg) ? (i + 1) : i;
      int sN = esrc[beg + nx];
      float4 xn = XLb[(size_t)sN * 64 + lane];
      float p = lrelu(xc.x + xr4.x) * a4.x + lrelu(xc.y + xr4.y) * a4.y
              + lrelu(xc.z + xr4.z) * a4.z + lrelu(xc.w + xr4.w) * a4.w;
      p = rsum32(p);
      if (i < 64 && (lane & 31) == 0) lsh[wv][2 * i + half] = p;
      float mn = fmaxf(m, p);
      ssum = ssum * __expf(m - mn) + __expf(p - mn);
      m = mn;
      xc = xn;
    }
  }
  const float inv = 1.f / ssum;
  __builtin_amdgcn_wave_barrier();
  float4 acc = make_float4(0.f, 0.f, 0.f, 0.f);
  {
    int sC = esrc[beg];
    float4 xc = XLb[(size_t)sC * 64 + lane];
    for (int i = 0; i < deg; ++i) {
      int nx = (i + 1 < deg) ? (i + 1) : i;
      int sN = esrc[beg + nx];
      float4 xn = XLb[(size_t)sN * 64 + lane];
      float lg;
      if (i < 64) lg = lsh[wv][2 * i + half];
      else {
        float p = lrelu(xc.x + xr4.x) * a4.x + lrelu(xc.y + xr4.y) * a4.y
                + lrelu(xc.z + xr4.z) * a4.z + lrelu(xc.w + xr4.w) * a4.w;
        lg = rsum32(p);
      }
      const float al = __expf(lg - m) * inv;
      acc.x = fmaf(al, xc.x, acc.x);
      acc.y = fmaf(al, xc.y, acc.y);
      acc.z = fmaf(al, xc.z, acc.z);
      acc.w = fmaf(al, xc.w, acc.w);
      xc = xn;
    }
  }
  const float4 A4 = reinterpret_cast<const float4*>(ABF)[lane];
  const float4 B4 = reinterpret_cast<const float4*>(ABF + 256)[lane];
  float4 o;
  o.x = eluf(fmaf(acc.x, A4.x, B4.x));
  o.y = eluf(fmaf(acc.y, A4.y, B4.y));
  o.z = eluf(fmaf(acc.z, A4.z, B4.z));
  o.w = eluf(fmaf(acc.w, A4.w, B4.w));
  reinterpret_cast<float4*>(H1 + (size_t)(b * 1000 + n) * 256)[lane] = o;
}

// ---------------- projection 2: h1(256) -> xl2(128)|xr2(128) ----------------
__global__ __launch_bounds__(256)
void proj2_kernel(const float* __restrict__ H1, const float* __restrict__ PW2,
                  float* __restrict__ XL2, float* __restrict__ XR2)
{
  __shared__ __align__(16) float xs[256][20];
  const int tid = threadIdx.x;
  const int r0 = blockIdx.x * 16;
  for (int el = tid; el < 4096; el += 256) {
    int k = el & 255, r = el >> 8;
    xs[k][r] = H1[(size_t)(r0 + r) * 256 + k];
  }
  __syncthreads();
  float acc[16];
  #pragma unroll
  for (int r = 0; r < 16; ++r) acc[r] = 0.f;
  for (int k = 0; k < 256; ++k) {
    float wgt = PW2[k * 256 + tid];
    float xv[16];
    #pragma unroll
    for (int q = 0; q < 4; ++q)
      *reinterpret_cast<float4*>(&xv[q * 4]) = *reinterpret_cast<const float4*>(&xs[k][q * 4]);
    #pragma unroll
    for (int r = 0; r < 16; ++r) acc[r] = fmaf(wgt, xv[r], acc[r]);
  }
  float* dst = (tid < 128) ? XL2 : XR2;
  const int col = tid & 127;
  for (int r = 0; r < 16; ++r)
    dst[(size_t)(r0 + r) * 128 + col] = acc[r];
}

// ---------------- GAT layer 2 fused (1 head) + BN/ELU + residual ----------------
__global__ __launch_bounds__(256)
void gat2_kernel(const float* __restrict__ XL, const float* __restrict__ XR,
                 const int* __restrict__ esrc,
                 const int* __restrict__ offs, const float* __restrict__ a2,
                 const float* __restrict__ ABF, const float* __restrict__ XP,
                 float* __restrict__ Hout)
{
  const int lane = threadIdx.x & 63;
  const int wv = threadIdx.x >> 6;
  const int n = blockIdx.x * 4 + wv;
  const int b = blockIdx.y;
  __shared__ float lsh[4][96];
  const int beg = offs[n];
  const int deg = offs[n + 1] - beg;
  const float2 av = reinterpret_cast<const float2*>(a2)[lane];
  const float2* XLb = reinterpret_cast<const float2*>(XL) + (size_t)b * 64000;
  const float2 xr2 = reinterpret_cast<const float2*>(XR + (size_t)(b * 1000 + n) * 128)[lane];
  float m = -INFINITY, ssum = 0.f;
  {
    int sC = esrc[beg];
    float2 xc = XLb[(size_t)sC * 64 + lane];
    for (int i = 0; i < deg; ++i) {
      int nx = (i + 1 < deg) ? (i + 1) : i;
      int sN = esrc[beg + nx];
      float2 xn = XLb[(size_t)sN * 64 + lane];
      float p = lrelu(xc.x + xr2.x) * av.x + lrelu(xc.y + xr2.y) * av.y;
      p = rsum64(p);
      if (i < 96 && lane == 0) lsh[wv][i] = p;
      float mn = fmaxf(m, p);
      ssum = ssum * __expf(m - mn) + __expf(p - mn);
      m = mn;
      xc = xn;
    }
  }
  const float inv = 1.f / ssum;
  __builtin_amdgcn_wave_barrier();
  float2 acc = make_float2(0.f, 0.f);
  {
    int sC = esrc[beg];
    float2 xc = XLb[(size_t)sC * 64 + lane];
    for (int i = 0; i < deg; ++i) {
      int nx = (i + 1 < deg) ? (i + 1) : i;
      int sN = esrc[beg + nx];
      float2 xn = XLb[(size_t)sN * 64 + lane];
      float lg;
      if (i < 96) lg = lsh[wv][i];
      else {
        float p = lrelu(xc.x + xr2.x) * av.x + lrelu(xc.y + xr2.y) * av.y;
        lg = rsum64(p);
      }
      const float al = __expf(lg - m) * inv;
      acc.x = fmaf(al, xc.x, acc.x);
      acc.y = fmaf(al, xc.y, acc.y);
      xc = xn;
    }
  }
  const float2 A2 = reinterpret_cast<const float2*>(ABF + 512)[lane];
  const float2 B2 = reinterpret_cast<const float2*>(ABF + 640)[lane];
  const float2 xp = reinterpret_cast<const float2*>(XP + (size_t)(b * 1000 + n) * 128)[lane];
  float2 o;
  o.x = eluf(fmaf(acc.x, A2.x, B2.x)) + xp.x;
  o.y = eluf(fmaf(acc.y, A2.y, B2.y)) + xp.y;
  reinterpret_cast<float2*>(Hout + (size_t)(b * 1000 + n) * 128)[lane] = o;
}

// ---------------- MFMA pre-GEMM: PRE[r][gp] = X[r][:] @ WihT[:, gp] + BC[gp] ----------
// split-bf16 (hi/lo), 3 MFMA per product tile; D layout row=(l>>4)*4+reg, col=l&15 (m89);
// A/B operands: lane l holds Mat[l&15 (M/N-dim)][(l>>4)*8+e (k-dim)].
__global__ __launch_bounds__(512)
void gemm_pre_kernel(const float* __restrict__ X, const unsigned short* __restrict__ PWB,
                     const float* __restrict__ BCL, float* __restrict__ PRE)
{
  const int tid = threadIdx.x;
  const int lane = tid & 63;
  const int wv = tid >> 6;            // 0..7, covers gp [wv*64, wv*64+64)
  const int l15 = lane & 15;
  const int kg = lane >> 4;           // 0..3
  const int r0 = blockIdx.x * 32;
  f32x4 acc[2][4];
  #pragma unroll
  for (int rt = 0; rt < 2; ++rt)
    #pragma unroll
    for (int gt = 0; gt < 4; ++gt)
      #pragma unroll
      for (int e = 0; e < 4; ++e) acc[rt][gt][e] = 0.f;
  for (int kc = 0; kc < 4; ++kc) {
    bf16x8 xh[2], xl[2];
    #pragma unroll
    for (int rt = 0; rt < 2; ++rt) {
      const float* xp = X + (size_t)(r0 + rt * 16 + l15) * 128 + (kc << 5) + (kg << 3);
      float4 va = *reinterpret_cast<const float4*>(xp);
      float4 vb = *reinterpret_cast<const float4*>(xp + 4);
      float xs[8] = {va.x, va.y, va.z, va.w, vb.x, vb.y, vb.z, vb.w};
      #pragma unroll
      for (int e = 0; e < 8; ++e) {
        unsigned short h = f2bf(xs[e]);
        xh[rt][e] = (short)h;
        xl[rt][e] = (short)f2bf(xs[e] - bf2f(h));
      }
    }
    #pragma unroll
    for (int gt = 0; gt < 4; ++gt) {
      const int gtg = (wv << 2) + gt;
      const unsigned short* wp = PWB + ((size_t)(kc * 32 + gtg)) * 512 + lane * 8;
      bf16x8 whi = *reinterpret_cast<const bf16x8*>(wp);
      bf16x8 wlo = *reinterpret_cast<const bf16x8*>(wp + 65536);  // split stride 4*32*512
      #pragma unroll
      for (int rt = 0; rt < 2; ++rt) {
        acc[rt][gt] = __builtin_amdgcn_mfma_f32_16x16x32_bf16(xh[rt], whi, acc[rt][gt], 0, 0, 0);
        acc[rt][gt] = __builtin_amdgcn_mfma_f32_16x16x32_bf16(xh[rt], wlo, acc[rt][gt], 0, 0, 0);
        acc[rt][gt] = __builtin_amdgcn_mfma_f32_16x16x32_bf16(xl[rt], whi, acc[rt][gt], 0, 0, 0);
      }
    }
  }
  #pragma unroll
  for (int gt = 0; gt < 4; ++gt) {
    const int col = (wv << 6) + (gt << 4) + l15;
    const float bias = BCL[col];
    #pragma unroll
    for (int rt = 0; rt < 2; ++rt) {
      #pragma unroll
      for (int reg = 0; reg < 4; ++reg) {
        const int row = r0 + rt * 16 + (kg << 2) + reg;
        PRE[(size_t)row * 512 + col] = acc[rt][gt][reg] + bias;
      }
    }
  }
}

// ---------------- recurrent hh-only LSTM layer ----------------
#define FMA4(A, W, S) { (A).x = fmaf((W).x, (S), (A).x); (A).y = fmaf((W).y, (S), (A).y); \
                        (A).z = fmaf((W).z, (S), (A).z); (A).w = fmaf((W).w, (S), (A).w); }
#define AD4(a, b) { (a).x += (b).x; (a).y += (b).y; (a).z += (b).z; (a).w += (b).w; }
#define LROW 140

__device__ __forceinline__ float4 shflx4(float4 v, int msk) {
  float4 r;
  r.x = __shfl_xor(v.x, msk); r.y = __shfl_xor(v.y, msk);
  r.z = __shfl_xor(v.z, msk); r.w = __shfl_xor(v.w, msk);
  return r;
}
// narrowing 3-round butterfly over p = lane>>3; result: seq p (one per slice)
__device__ __forceinline__ void reduce8to1(float4 (&g)[8], int lane, float4& ga)
{
  const bool b4 = (lane & 32) != 0, b2 = (lane & 16) != 0, b1 = (lane & 8) != 0;
  float4 t[4];
  #pragma unroll
  for (int i = 0; i < 4; ++i) {
    float4 keep = b4 ? g[4 + i] : g[i];
    float4 send = b4 ? g[i] : g[4 + i];
    float4 r = shflx4(send, 32);
    AD4(keep, r); t[i] = keep;
  }
  float4 u[2];
  #pragma unroll
  for (int i = 0; i < 2; ++i) {
    float4 keep = b2 ? t[2 + i] : t[i];
    float4 send = b2 ? t[i] : t[2 + i];
    float4 r = shflx4(send, 16);
    AD4(keep, r); u[i] = keep;
  }
  {
    float4 keep = b1 ? u[1] : u[0];
    float4 send = b1 ? u[0] : u[1];
    float4 r = shflx4(send, 8);
    AD4(keep, r); ga = keep;
  }
}
__device__ __forceinline__ float cellf(float4 g, float& c) {
  const float ig = 1.f / (1.f + __expf(-g.x));
  const float fg = 1.f / (1.f + __expf(-g.y));
  const float gg = tanhf(g.z);
  const float og = 1.f / (1.f + __expf(-g.w));
  c = fmaf(fg, c, ig * gg);
  return og * tanhf(c);
}

// 1024 thr = 16 waves, 8 seqs/block, 500 blocks. hh-only: k-split 8-way (16 k each),
// acc g[8]=32 VGPR, ~55 total -> fits 64-VGPR full-occupancy allocation. LDS 4.5 KB.
__global__ __launch_bounds__(1024)
void rec_kernel(const float* __restrict__ PRE, const float* __restrict__ PHHL,
                float* __restrict__ HOUT)
{
  __shared__ __align__(16) float hs[8][LROW];
  const int tid = threadIdx.x;
  const int lane = tid & 63;
  const int w = tid >> 6;
  const int jlo = lane & 7;
  const int p = lane >> 3;
  const int j = (w << 3) + jlo;
  const int jo = j + ((j >> 5) << 2);
  const int q0 = blockIdx.x << 3;
  for (int i = tid; i < 8 * LROW; i += 1024) (&hs[0][0])[i] = 0.f;
  const float4* W4 = reinterpret_cast<const float4*>(PHHL);
  float cst = 0.f;
  __syncthreads();
  for (int t = 0; t < 16; ++t) {
    float4 g[8];
    #pragma unroll
    for (int s = 0; s < 8; ++s) g[s] = make_float4(0.f, 0.f, 0.f, 0.f);
    #pragma unroll
    for (int q = 0; q < 4; ++q) {
      const float4* wq = W4 + (((w << 2) + q) << 8) + lane;
      float4 w0 = wq[0], w1 = wq[64], w2 = wq[128], w3 = wq[192];
      const int col = (p << 4) + (q << 2);
      const int co = col + ((col >> 5) << 2);
      #pragma unroll
      for (int s = 0; s < 8; ++s) {
        float4 xv = *reinterpret_cast<const float4*>(&hs[s][co]);
        FMA4(g[s], w0, xv.x); FMA4(g[s], w1, xv.y);
        FMA4(g[s], w2, xv.z); FMA4(g[s], w3, xv.w);
      }
    }
    float4 ga;
    reduce8to1(g, lane, ga);
    const int row = ((q0 + p) << 4) + t;
    const float4 pf = *reinterpret_cast<const float4*>(PRE + (size_t)row * 512 + (j << 2));
    AD4(ga, pf);
    float h = cellf(ga, cst);
    __syncthreads();                       // all hs reads of t done
    hs[p][jo] = h;
    HOUT[(size_t)row * 128 + j] = h;
    __syncthreads();                       // h visible for t+1
  }
}

// ---------------- attention pool + skip MLP + head ----------------
__global__ __launch_bounds__(64)
void attn_kernel(const float* __restrict__ LO, const float* __restrict__ X,
                 const float* __restrict__ Wa, const float* __restrict__ ba,
                 const float* __restrict__ bs1, const float* __restrict__ bs2,
                 const float* __restrict__ bh1, const float* __restrict__ bh2,
                 const float* __restrict__ Wh2, const float* __restrict__ HWT,
                 float* __restrict__ out)
{
  const int q = blockIdx.x, l = threadIdx.x;
  const float* lob = LO + (size_t)q * 2048;
  float loa[16], lobv[16];
  #pragma unroll
  for (int t = 0; t < 16; ++t) {
    loa[t]  = lob[t * 128 + l];
    lobv[t] = lob[t * 128 + 64 + l];
  }
  const float wa = Wa[l], wb = Wa[64 + l];
  float sc[16];
  #pragma unroll
  for (int t = 0; t < 16; ++t) sc[t] = rsum64(loa[t] * wa + lobv[t] * wb) + ba[0];
  float mx = sc[0];
  #pragma unroll
  for (int t = 1; t < 16; ++t) mx = fmaxf(mx, sc[t]);
  float den = 0.f;
  #pragma unroll
  for (int t = 0; t < 16; ++t) { sc[t] = __expf(sc[t] - mx); den += sc[t]; }
  const float inv = 1.f / den;
  float ca = 0.f, cb = 0.f;
  #pragma unroll
  for (int t = 0; t < 16; ++t) {
    float wgt = sc[t] * inv;
    ca = fmaf(wgt, loa[t], ca);
    cb = fmaf(wgt, lobv[t], cb);
  }
  __shared__ float zsh[160];
  __shared__ float hsk[64];
  __shared__ float skin[16];
  zsh[l] = ca; zsh[64 + l] = cb;
  const int bb = q / 1000, nn = q - bb * 1000;
  if (l < 13) skin[l] = X[(size_t)((bb * 16 + 15) * 1000 + nn) * 32 + l];
  __syncthreads();
  float h1 = bs1[l];
  for (int c = 0; c < 13; ++c) h1 = fmaf(skin[c], HWT[c * 64 + l], h1);
  h1 = geluf(h1);
  hsk[l] = h1;
  __syncthreads();
  if (l < 32) {
    float a = bs2[l];
    for (int jj = 0; jj < 64; ++jj) a = fmaf(hsk[jj], HWT[832 + jj * 32 + l], a);
    zsh[128 + l] = a;
  }
  __syncthreads();
  float hh = bh1[l];
  for (int r = 0; r < 160; ++r) hh = fmaf(zsh[r], HWT[2880 + r * 64 + l], hh);
  hh = geluf(hh);
  float s = rsum64(hh * Wh2[l]);
  if (l == 0) out[q] = s + bh2[0];
}

// ---------------- launch ----------------
extern "C" void kernel_launch(void* const* d_in, const int* in_sizes, int n_in,
                              void* d_out, int out_size, void* d_ws, size_t ws_size,
                              hipStream_t stream)
{
  const float* x    = (const float*)d_in[0];
  const int*   ei   = (const int*)d_in[1];
  const float* Wp   = (const float*)d_in[2];
  const float* bp   = (const float*)d_in[3];
  const float* Wl1  = (const float*)d_in[4];
  const float* Wr1  = (const float*)d_in[5];
  const float* a1   = (const float*)d_in[6];
  const float* bg1  = (const float*)d_in[7];
  const float* g1   = (const float*)d_in[8];
  const float* be1  = (const float*)d_in[9];
  const float* m1   = (const float*)d_in[10];
  const float* v1   = (const float*)d_in[11];
  const float* Wl2  = (const float*)d_in[12];
  const float* Wr2  = (const float*)d_in[13];
  const float* a2   = (const float*)d_in[14];
  const float* bg2  = (const float*)d_in[15];
  const float* g2   = (const float*)d_in[16];
  const float* be2  = (const float*)d_in[17];
  const float* m2   = (const float*)d_in[18];
  const float* v2   = (const float*)d_in[19];
  const float* Wih0 = (const float*)d_in[20];
  const float* Whh0 = (const float*)d_in[21];
  const float* bih0 = (const float*)d_in[22];
  const float* bhh0 = (const float*)d_in[23];
  const float* Wih1 = (const float*)d_in[24];
  const float* Whh1 = (const float*)d_in[25];
  const float* bih1 = (const float*)d_in[26];
  const float* bhh1 = (const float*)d_in[27];
  const float* Wa   = (const float*)d_in[28];
  const float* ba   = (const float*)d_in[29];
  const float* Ws1  = (const float*)d_in[30];
  const float* bs1  = (const float*)d_in[31];
  const float* Ws2  = (const float*)d_in[32];
  const float* bs2  = (const float*)d_in[33];
  const float* Wh1  = (const float*)d_in[34];
  const float* bh1  = (const float*)d_in[35];
  const float* Wh2  = (const float*)d_in[36];
  const float* bh2  = (const float*)d_in[37];

  float* ws = (float*)d_ws;
  int* srcD   = (int*)(ws + O_SRCD);
  int* dstD   = (int*)(ws + O_DSTD);
  int* counts = (int*)(ws + O_COUNTS);
  int* offs   = (int*)(ws + O_OFFS);
  int* curs   = (int*)(ws + O_CURS);
  int* esrc   = (int*)(ws + O_EIDX);
  float* PW1  = ws + O_PW1;
  float* PW2  = ws + O_PW2;
  float* PHH  = ws + O_LW;                                   // 131072 floats
  unsigned short* PWBu = (unsigned short*)(ws + O_LW + 131072u);  // 262144 bf16
  float* BC   = ws + O_BCOMB;
  float* ABF  = ws + O_ABF;
  float* HWT  = ws + O_HWT;
  float* XL1  = ws + O_BIG0;
  float* XR1  = ws + O_BIG1;
  float* H1   = ws + O_BIG2;
  float* XP   = ws + O_BIG3;
  float* Hres = ws + O_BIG4;
  float* XL2  = ws + O_BIG0;             // reuse (XL1 dead)
  float* XR2  = ws + O_BIG0 + 8192000u;
  float* PRE  = ws + O_BIG0;             // 32.768M floats: spans BIG0+BIG1 (XL/XR dead)
  float* H1SEQ = ws + O_BIG2;            // reuse (H1 dead)
  float* LOp  = ws + O_BIG3;             // reuse (XP dead)
  float* outp = (float*)d_out;

  prep_edges<<<67, 256, 0, stream>>>(ei, srcD, dstD, counts);
  hist_kernel<<<67, 256, 0, stream>>>(dstD, counts);
  scan_kernel<<<1, 1024, 0, stream>>>(counts, offs, curs);
  fill_kernel<<<67, 256, 0, stream>>>(srcD, dstD, curs, esrc);
  pack_kernel<<<1024, 256, 0, stream>>>(Wl1, Wr1, Wp, Wl2, Wr2,
      Wih0, Whh0, bih0, bhh0, Wih1, Whh1, bih1, bhh1,
      g1, be1, m1, v1, bg1, g2, be2, m2, v2, bg2,
      Ws1, Ws2, Wh1, PW1, PW2, PHH, PWBu, BC, ABF, HWT);
  proj1_kernel<<<4000, 320, 0, stream>>>(x, PW1, bp, XL1, XR1, XP);
  gat1_kernel<<<dim3(250, 64), 256, 0, stream>>>(XL1, XR1, esrc, offs, a1, ABF, H1);
  proj2_kernel<<<4000, 256, 0, stream>>>(H1, PW2, XL2, XR2);
  gat2_kernel<<<dim3(250, 64), 256, 0, stream>>>(XL2, XR2, esrc, offs, a2, ABF, XP, Hres);
  gemm_pre_kernel<<<2000, 512, 0, stream>>>(Hres, PWBu, BC, PRE);
  rec_kernel<<<500, 1024, 0, stream>>>(PRE, PHH, H1SEQ);
  gemm_pre_kernel<<<2000, 512, 0, stream>>>(H1SEQ, PWBu + 131072u, BC + 512, PRE);
  rec_kernel<<<500, 1024, 0, stream>>>(PRE, PHH + 65536u, LOp);
  attn_kernel<<<4000, 64, 0, stream>>>(LOp, x, Wa, ba, bs1, bs2, bh1, bh2, Wh2, HWT, outp);
}

// Round 10
// 925.802 us; speedup vs baseline: 2.3503x; 1.1240x over previous
//
#include <hip/hip_runtime.h>

#define EPS_BN 1e-5f

typedef __attribute__((ext_vector_type(8))) short bf16x8;
typedef __attribute__((ext_vector_type(4))) float f32x4;

// ---------------- workspace layout (float-unit offsets) ----------------
#define O_SRCD   0u
#define O_DSTD   17024u
#define O_COUNTS 34048u
#define O_OFFS   35072u
#define O_CURS   36096u
#define O_EIDX   37120u                    // esrc (src node id, CSR-ordered)
#define O_PW1    54144u                    // [32][640]  (Wl1T|Wr1T|WpT)
#define O_PW2    74624u                    // [256][256] (Wl2T|Wr2T)
#define O_LW     140160u                   // PHH (131072 f) + PWB (262144 bf16)
#define O_BCOMB  402304u                   // [2][128j][4]  (gp order)
#define O_ABF    403328u                   // A1(256)|B1(256)|A2(128)|B2(128)
#define O_HWT    404352u                   // Ws1T(832)|Ws2T(2048)|Wh1T(10240)
#define O_BIG0   417536u                   // XL1 | XL2,XR2 | pre (spans BIG0+BIG1)
#define O_BIG1   (O_BIG0 + 16384000u)      // XR1 | pre upper half
#define O_BIG2   (O_BIG1 + 16384000u)      // H1  | h1seq
#define O_BIG3   (O_BIG2 + 16384000u)      // XP  | LO
#define O_BIG4   (O_BIG3 + 8192000u)       // Hres

__device__ __forceinline__ float rsum32(float p) {
  p += __shfl_xor(p, 1);  p += __shfl_xor(p, 2);  p += __shfl_xor(p, 4);
  p += __shfl_xor(p, 8);  p += __shfl_xor(p, 16); return p;
}
__device__ __forceinline__ float rsum64(float p) {
  p = rsum32(p); p += __shfl_xor(p, 32); return p;
}
__device__ __forceinline__ float lrelu(float x) { return x > 0.f ? x : 0.2f * x; }
__device__ __forceinline__ float eluf(float x)  { return x > 0.f ? x : expm1f(x); }
__device__ __forceinline__ float geluf(float x) { return 0.5f * x * (1.f + erff(x * 0.70710678118654752f)); }
__device__ __forceinline__ unsigned short f2bf(float f) {
  unsigned int u = __float_as_uint(f);
  u += 0x7FFFu + ((u >> 16) & 1u);
  return (unsigned short)(u >> 16);
}
__device__ __forceinline__ float bf2f(unsigned short h) {
  return __uint_as_float(((unsigned int)h) << 16);
}

// ---------------- prep kernels ----------------
__global__ void prep_edges(const int* __restrict__ ei, int* __restrict__ srcD,
                           int* __restrict__ dstD, int* __restrict__ counts) {
  int i = blockIdx.x * 256 + threadIdx.x;
  if (i < 1024) counts[i] = 0;
  if (i < 17000) {
    int s = (i < 16000) ? ei[i] : (i - 16000);
    int d = (i < 16000) ? ei[16000 + i] : (i - 16000);
    srcD[i] = s; dstD[i] = d;
  }
}
__global__ void hist_kernel(const int* __restrict__ dstD, int* __restrict__ counts) {
  int i = blockIdx.x * 256 + threadIdx.x;
  if (i < 17000) atomicAdd(&counts[dstD[i]], 1);
}
__global__ void scan_kernel(const int* __restrict__ counts, int* __restrict__ offs,
                            int* __restrict__ curs) {
  __shared__ int sh[1024];
  int i = threadIdx.x;
  int v = (i < 1000) ? counts[i] : 0;
  sh[i] = v;
  __syncthreads();
  for (int d = 1; d < 1024; d <<= 1) {
    int t = (i >= d) ? sh[i - d] : 0;
    __syncthreads();
    sh[i] += t;
    __syncthreads();
  }
  if (i < 1000) { offs[i + 1] = sh[i]; curs[i] = sh[i] - v; }
  if (i == 0) offs[0] = 0;
}
__global__ void fill_kernel(const int* __restrict__ srcD, const int* __restrict__ dstD,
                            int* __restrict__ curs, int* __restrict__ esrc) {
  int i = blockIdx.x * 256 + threadIdx.x;
  if (i < 17000) { int p = atomicAdd(&curs[dstD[i]], 1); esrc[p] = srcD[i]; }
}

// PHH: hh weights [L][w16][q4][dk4][lane64][gate4], k = p*16 + q*4 + dk (p = lane>>3)
// PWB: ih weights split-bf16 MFMA B-frags [L][split][kc4][gt32][lane64][e8]
__global__ void pack_kernel(
    const float* __restrict__ Wl1, const float* __restrict__ Wr1, const float* __restrict__ Wp,
    const float* __restrict__ Wl2, const float* __restrict__ Wr2,
    const float* __restrict__ Wih0, const float* __restrict__ Whh0,
    const float* __restrict__ bih0, const float* __restrict__ bhh0,
    const float* __restrict__ Wih1, const float* __restrict__ Whh1,
    const float* __restrict__ bih1, const float* __restrict__ bhh1,
    const float* __restrict__ g1, const float* __restrict__ be1, const float* __restrict__ m1,
    const float* __restrict__ v1, const float* __restrict__ bg1,
    const float* __restrict__ g2, const float* __restrict__ be2, const float* __restrict__ m2,
    const float* __restrict__ v2, const float* __restrict__ bg2,
    const float* __restrict__ Ws1, const float* __restrict__ Ws2, const float* __restrict__ Wh1,
    float* __restrict__ PW1, float* __restrict__ PW2, float* __restrict__ PHH,
    unsigned short* __restrict__ PWBu,
    float* __restrict__ BC, float* __restrict__ ABF, float* __restrict__ HWT)
{
  int i = blockIdx.x * 256 + threadIdx.x;
  if (i < 131072) {  // PHH
    int gate = i & 3, lane = (i >> 2) & 63, dk = (i >> 8) & 3,
        q = (i >> 10) & 3, w = (i >> 12) & 15, L = (i >> 16) & 1;
    int jlo = lane & 7, p = lane >> 3;
    int jj = (w << 3) + jlo;
    int kk = (p << 4) + (q << 2) + dk;
    const float* Whh = L ? Whh1 : Whh0;
    PHH[i] = Whh[(gate * 128 + jj) * 128 + kk];
  }
  if (i < 262144) {  // PWB split-bf16
    int e = i & 7, lane = (i >> 3) & 63, gt = (i >> 9) & 31,
        kc = (i >> 14) & 3, sp = (i >> 16) & 1, L = (i >> 17) & 1;
    int gp = (gt << 4) + (lane & 15);
    int jj = gp >> 2, gate = gp & 3;
    int kk = (kc << 5) + ((lane >> 4) << 3) + e;
    const float* Wih = L ? Wih1 : Wih0;
    float wv = Wih[(gate * 128 + jj) * 128 + kk];
    unsigned short hi = f2bf(wv);
    PWBu[i] = (sp == 0) ? hi : f2bf(wv - bf2f(hi));
  }
  if (i < 65536) { int c = i & 255, k = i >> 8;
    PW2[i] = (c < 128) ? Wl2[c * 256 + k] : Wr2[(c - 128) * 256 + k]; }
  if (i < 20480) { int g = i % 640, k = i / 640;
    PW1[i] = (g < 256) ? Wl1[g * 32 + k] : (g < 512) ? Wr1[(g - 256) * 32 + k]
                                                     : Wp[(g - 512) * 32 + k]; }
  if (i < 1024) { int u = i & 3, jj = (i >> 2) & 127, L = i >> 9;
    BC[i] = (L ? bih1 : bih0)[u * 128 + jj] + (L ? bhh1 : bhh0)[u * 128 + jj]; }
  if (i < 768) {
    if (i < 256) ABF[i] = g1[i] * rsqrtf(v1[i] + EPS_BN);
    else if (i < 512) { int c = i - 256; float a = g1[c] * rsqrtf(v1[c] + EPS_BN);
      ABF[i] = (bg1[c] - m1[c]) * a + be1[c]; }
    else if (i < 640) { int c = i - 512; ABF[i] = g2[c] * rsqrtf(v2[c] + EPS_BN); }
    else { int c = i - 640; float a = g2[c] * rsqrtf(v2[c] + EPS_BN);
      ABF[i] = (bg2[c] - m2[c]) * a + be2[c]; }
  }
  if (i < 13120) {
    if (i < 832) { int l = i & 63, c = i >> 6; HWT[i] = Ws1[l * 13 + c]; }
    else if (i < 2880) { int k = i - 832; int l = k & 31, jj = k >> 5; HWT[i] = Ws2[l * 64 + jj]; }
    else { int k = i - 2880; int l = k & 63, r = k >> 6; HWT[i] = Wh1[l * 160 + r]; }
  }
}

// ---------------- projection 1: x -> xl1(256) | xr1(256) | xp(128) ----------------
__global__ __launch_bounds__(320)
void proj1_kernel(const float* __restrict__ X, const float* __restrict__ PW1,
                  const float* __restrict__ bp,
                  float* __restrict__ XL1, float* __restrict__ XR1, float* __restrict__ XP)
{
  __shared__ __align__(16) float xs[32][16];
  const int tid = threadIdx.x;
  const int r0 = blockIdx.x * 16;
  for (int el = tid; el < 512; el += 320) {
    int r = el >> 5, k = el & 31;
    xs[k][r] = X[(size_t)(r0 + r) * 32 + k];
  }
  __syncthreads();
  const int gA = tid, gB = tid + 320;
  float accA[16], accB[16];
  const float iB = (gB >= 512) ? bp[gB - 512] : 0.f;
  #pragma unroll
  for (int r = 0; r < 16; ++r) { accA[r] = 0.f; accB[r] = iB; }
  for (int k = 0; k < 32; ++k) {
    float wA = PW1[k * 640 + gA], wB = PW1[k * 640 + gB];
    float xv[16];
    #pragma unroll
    for (int q = 0; q < 4; ++q)
      *reinterpret_cast<float4*>(&xv[q * 4]) = *reinterpret_cast<const float4*>(&xs[k][q * 4]);
    #pragma unroll
    for (int r = 0; r < 16; ++r) {
      accA[r] = fmaf(wA, xv[r], accA[r]);
      accB[r] = fmaf(wB, xv[r], accB[r]);
    }
  }
  for (int r = 0; r < 16; ++r) {
    size_t row = r0 + r;
    if (gA < 256) XL1[row * 256 + gA] = accA[r];
    else          XR1[row * 256 + (gA - 256)] = accA[r];
    if (gB < 512) XR1[row * 256 + (gB - 256)] = accB[r];
    else          XP[row * 128 + (gB - 512)] = accB[r];
  }
}

// ---------------- GAT layer 1, one-pass online softmax (2 heads, d=128) ----------------
__global__ __launch_bounds__(256)
void gat1_kernel(const float* __restrict__ XL, const float* __restrict__ XR,
                 const int* __restrict__ esrc,
                 const int* __restrict__ offs, const float* __restrict__ a1,
                 const float* __restrict__ ABF, float* __restrict__ H1)
{
  const int lane = threadIdx.x & 63;
  const int wv = threadIdx.x >> 6;
  const int n = blockIdx.x * 4 + wv;
  const int b = blockIdx.y;
  const int beg = offs[n];
  const int deg = offs[n + 1] - beg;
  const float4 a4 = reinterpret_cast<const float4*>(a1)[lane];
  const float4* XLb = reinterpret_cast<const float4*>(XL) + (size_t)b * 64000;
  const float4 xr4 = reinterpret_cast<const float4*>(XR + (size_t)(b * 1000 + n) * 256)[lane];
  float m = -INFINITY, ssum = 0.f;
  float4 acc = make_float4(0.f, 0.f, 0.f, 0.f);
  int sC = esrc[beg];
  float4 xc = XLb[(size_t)sC * 64 + lane];
  for (int i = 0; i < deg; ++i) {
    int nx = (i + 1 < deg) ? (i + 1) : i;
    int sN = esrc[beg + nx];
    float4 xn = XLb[(size_t)sN * 64 + lane];
    float p = lrelu(xc.x + xr4.x) * a4.x + lrelu(xc.y + xr4.y) * a4.y
            + lrelu(xc.z + xr4.z) * a4.z + lrelu(xc.w + xr4.w) * a4.w;
    p = rsum32(p);
    float mn = fmaxf(m, p);
    float sc = __expf(m - mn);       // 0 on first iter (m=-inf), 1 if max unchanged
    float we = __expf(p - mn);
    ssum = ssum * sc + we;
    acc.x = fmaf(acc.x, sc, we * xc.x);
    acc.y = fmaf(acc.y, sc, we * xc.y);
    acc.z = fmaf(acc.z, sc, we * xc.z);
    acc.w = fmaf(acc.w, sc, we * xc.w);
    m = mn;
    xc = xn;
  }
  const float inv = 1.f / ssum;
  const float4 A4 = reinterpret_cast<const float4*>(ABF)[lane];
  const float4 B4 = reinterpret_cast<const float4*>(ABF + 256)[lane];
  float4 o;
  o.x = eluf(fmaf(acc.x * inv, A4.x, B4.x));
  o.y = eluf(fmaf(acc.y * inv, A4.y, B4.y));
  o.z = eluf(fmaf(acc.z * inv, A4.z, B4.z));
  o.w = eluf(fmaf(acc.w * inv, A4.w, B4.w));
  reinterpret_cast<float4*>(H1 + (size_t)(b * 1000 + n) * 256)[lane] = o;
}

// ---------------- projection 2: h1(256) -> xl2(128)|xr2(128) ----------------
__global__ __launch_bounds__(256)
void proj2_kernel(const float* __restrict__ H1, const float* __restrict__ PW2,
                  float* __restrict__ XL2, float* __restrict__ XR2)
{
  __shared__ __align__(16) float xs[256][20];
  const int tid = threadIdx.x;
  const int r0 = blockIdx.x * 16;
  for (int el = tid; el < 4096; el += 256) {
    int k = el & 255, r = el >> 8;
    xs[k][r] = H1[(size_t)(r0 + r) * 256 + k];
  }
  __syncthreads();
  float acc[16];
  #pragma unroll
  for (int r = 0; r < 16; ++r) acc[r] = 0.f;
  for (int k = 0; k < 256; ++k) {
    float wgt = PW2[k * 256 + tid];
    float xv[16];
    #pragma unroll
    for (int q = 0; q < 4; ++q)
      *reinterpret_cast<float4*>(&xv[q * 4]) = *reinterpret_cast<const float4*>(&xs[k][q * 4]);
    #pragma unroll
    for (int r = 0; r < 16; ++r) acc[r] = fmaf(wgt, xv[r], acc[r]);
  }
  float* dst = (tid < 128) ? XL2 : XR2;
  const int col = tid & 127;
  for (int r = 0; r < 16; ++r)
    dst[(size_t)(r0 + r) * 128 + col] = acc[r];
}

// ---------------- GAT layer 2, one-pass online softmax (1 head) + BN/ELU + residual ----
__global__ __launch_bounds__(256)
void gat2_kernel(const float* __restrict__ XL, const float* __restrict__ XR,
                 const int* __restrict__ esrc,
                 const int* __restrict__ offs, const float* __restrict__ a2,
                 const float* __restrict__ ABF, const float* __restrict__ XP,
                 float* __restrict__ Hout)
{
  const int lane = threadIdx.x & 63;
  const int wv = threadIdx.x >> 6;
  const int n = blockIdx.x * 4 + wv;
  const int b = blockIdx.y;
  const int beg = offs[n];
  const int deg = offs[n + 1] - beg;
  const float2 av = reinterpret_cast<const float2*>(a2)[lane];
  const float2* XLb = reinterpret_cast<const float2*>(XL) + (size_t)b * 64000;
  const float2 xr2 = reinterpret_cast<const float2*>(XR + (size_t)(b * 1000 + n) * 128)[lane];
  float m = -INFINITY, ssum = 0.f;
  float2 acc = make_float2(0.f, 0.f);
  int sC = esrc[beg];
  float2 xc = XLb[(size_t)sC * 64 + lane];
  for (int i = 0; i < deg; ++i) {
    int nx = (i + 1 < deg) ? (i + 1) : i;
    int sN = esrc[beg + nx];
    float2 xn = XLb[(size_t)sN * 64 + lane];
    float p = lrelu(xc.x + xr2.x) * av.x + lrelu(xc.y + xr2.y) * av.y;
    p = rsum64(p);
    float mn = fmaxf(m, p);
    float sc = __expf(m - mn);
    float we = __expf(p - mn);
    ssum = ssum * sc + we;
    acc.x = fmaf(acc.x, sc, we * xc.x);
    acc.y = fmaf(acc.y, sc, we * xc.y);
    m = mn;
    xc = xn;
  }
  const float inv = 1.f / ssum;
  const float2 A2 = reinterpret_cast<const float2*>(ABF + 512)[lane];
  const float2 B2 = reinterpret_cast<const float2*>(ABF + 640)[lane];
  const float2 xp = reinterpret_cast<const float2*>(XP + (size_t)(b * 1000 + n) * 128)[lane];
  float2 o;
  o.x = eluf(fmaf(acc.x * inv, A2.x, B2.x)) + xp.x;
  o.y = eluf(fmaf(acc.y * inv, A2.y, B2.y)) + xp.y;
  reinterpret_cast<float2*>(Hout + (size_t)(b * 1000 + n) * 128)[lane] = o;
}

// ---------------- MFMA pre-GEMM: PRE[r][gp] = X[r][:] @ WihT[:, gp] + BC[gp] ----------
__global__ __launch_bounds__(512)
void gemm_pre_kernel(const float* __restrict__ X, const unsigned short* __restrict__ PWB,
                     const float* __restrict__ BCL, float* __restrict__ PRE)
{
  const int tid = threadIdx.x;
  const int lane = tid & 63;
  const int wv = tid >> 6;            // 0..7, covers gp [wv*64, wv*64+64)
  const int l15 = lane & 15;
  const int kg = lane >> 4;           // 0..3
  const int r0 = blockIdx.x * 32;
  f32x4 acc[2][4];
  #pragma unroll
  for (int rt = 0; rt < 2; ++rt)
    #pragma unroll
    for (int gt = 0; gt < 4; ++gt)
      #pragma unroll
      for (int e = 0; e < 4; ++e) acc[rt][gt][e] = 0.f;
  for (int kc = 0; kc < 4; ++kc) {
    bf16x8 xh[2], xl[2];
    #pragma unroll
    for (int rt = 0; rt < 2; ++rt) {
      const float* xp = X + (size_t)(r0 + rt * 16 + l15) * 128 + (kc << 5) + (kg << 3);
      float4 va = *reinterpret_cast<const float4*>(xp);
      float4 vb = *reinterpret_cast<const float4*>(xp + 4);
      float xs[8] = {va.x, va.y, va.z, va.w, vb.x, vb.y, vb.z, vb.w};
      #pragma unroll
      for (int e = 0; e < 8; ++e) {
        unsigned short h = f2bf(xs[e]);
        xh[rt][e] = (short)h;
        xl[rt][e] = (short)f2bf(xs[e] - bf2f(h));
      }
    }
    #pragma unroll
    for (int gt = 0; gt < 4; ++gt) {
      const int gtg = (wv << 2) + gt;
      const unsigned short* wp = PWB + ((size_t)(kc * 32 + gtg)) * 512 + lane * 8;
      bf16x8 whi = *reinterpret_cast<const bf16x8*>(wp);
      bf16x8 wlo = *reinterpret_cast<const bf16x8*>(wp + 65536);
      #pragma unroll
      for (int rt = 0; rt < 2; ++rt) {
        acc[rt][gt] = __builtin_amdgcn_mfma_f32_16x16x32_bf16(xh[rt], whi, acc[rt][gt], 0, 0, 0);
        acc[rt][gt] = __builtin_amdgcn_mfma_f32_16x16x32_bf16(xh[rt], wlo, acc[rt][gt], 0, 0, 0);
        acc[rt][gt] = __builtin_amdgcn_mfma_f32_16x16x32_bf16(xl[rt], whi, acc[rt][gt], 0, 0, 0);
      }
    }
  }
  #pragma unroll
  for (int gt = 0; gt < 4; ++gt) {
    const int col = (wv << 6) + (gt << 4) + l15;
    const float bias = BCL[col];
    #pragma unroll
    for (int rt = 0; rt < 2; ++rt) {
      #pragma unroll
      for (int reg = 0; reg < 4; ++reg) {
        const int row = r0 + rt * 16 + (kg << 2) + reg;
        PRE[(size_t)row * 512 + col] = acc[rt][gt][reg] + bias;
      }
    }
  }
}

// ---------------- recurrent hh-only LSTM layer ----------------
#define FMA4(A, W, S) { (A).x = fmaf((W).x, (S), (A).x); (A).y = fmaf((W).y, (S), (A).y); \
                        (A).z = fmaf((W).z, (S), (A).z); (A).w = fmaf((W).w, (S), (A).w); }
#define AD4(a, b) { (a).x += (b).x; (a).y += (b).y; (a).z += (b).z; (a).w += (b).w; }
#define LROW 140

__device__ __forceinline__ float4 shflx4(float4 v, int msk) {
  float4 r;
  r.x = __shfl_xor(v.x, msk); r.y = __shfl_xor(v.y, msk);
  r.z = __shfl_xor(v.z, msk); r.w = __shfl_xor(v.w, msk);
  return r;
}
__device__ __forceinline__ void reduce8to1(float4 (&g)[8], int lane, float4& ga)
{
  const bool b4 = (lane & 32) != 0, b2 = (lane & 16) != 0, b1 = (lane & 8) != 0;
  float4 t[4];
  #pragma unroll
  for (int i = 0; i < 4; ++i) {
    float4 keep = b4 ? g[4 + i] : g[i];
    float4 send = b4 ? g[i] : g[4 + i];
    float4 r = shflx4(send, 32);
    AD4(keep, r); t[i] = keep;
  }
  float4 u[2];
  #pragma unroll
  for (int i = 0; i < 2; ++i) {
    float4 keep = b2 ? t[2 + i] : t[i];
    float4 send = b2 ? t[i] : t[2 + i];
    float4 r = shflx4(send, 16);
    AD4(keep, r); u[i] = keep;
  }
  {
    float4 keep = b1 ? u[1] : u[0];
    float4 send = b1 ? u[0] : u[1];
    float4 r = shflx4(send, 8);
    AD4(keep, r); ga = keep;
  }
}
__device__ __forceinline__ float cellf(float4 g, float& c) {
  const float ig = 1.f / (1.f + __expf(-g.x));
  const float fg = 1.f / (1.f + __expf(-g.y));
  const float gg = tanhf(g.z);
  const float og = 1.f / (1.f + __expf(-g.w));
  c = fmaf(fg, c, ig * gg);
  return og * tanhf(c);
}

__global__ __launch_bounds__(1024)
void rec_kernel(const float* __restrict__ PRE, const float* __restrict__ PHHL,
                float* __restrict__ HOUT)
{
  __shared__ __align__(16) float hs[8][LROW];
  const int tid = threadIdx.x;
  const int lane = tid & 63;
  const int w = tid >> 6;
  const int jlo = lane & 7;
  const int p = lane >> 3;
  const int j = (w << 3) + jlo;
  const int jo = j + ((j >> 5) << 2);
  const int q0 = blockIdx.x << 3;
  for (int i = tid; i < 8 * LROW; i += 1024) (&hs[0][0])[i] = 0.f;
  const float4* W4 = reinterpret_cast<const float4*>(PHHL);
  float cst = 0.f;
  __syncthreads();
  for (int t = 0; t < 16; ++t) {
    float4 g[8];
    #pragma unroll
    for (int s = 0; s < 8; ++s) g[s] = make_float4(0.f, 0.f, 0.f, 0.f);
    #pragma unroll
    for (int q = 0; q < 4; ++q) {
      const float4* wq = W4 + (((w << 2) + q) << 8) + lane;
      float4 w0 = wq[0], w1 = wq[64], w2 = wq[128], w3 = wq[192];
      const int col = (p << 4) + (q << 2);
      const int co = col + ((col >> 5) << 2);
      #pragma unroll
      for (int s = 0; s < 8; ++s) {
        float4 xv = *reinterpret_cast<const float4*>(&hs[s][co]);
        FMA4(g[s], w0, xv.x); FMA4(g[s], w1, xv.y);
        FMA4(g[s], w2, xv.z); FMA4(g[s], w3, xv.w);
      }
    }
    float4 ga;
    reduce8to1(g, lane, ga);
    const int row = ((q0 + p) << 4) + t;
    const float4 pf = *reinterpret_cast<const float4*>(PRE + (size_t)row * 512 + (j << 2));
    AD4(ga, pf);
    float h = cellf(ga, cst);
    __syncthreads();                       // all hs reads of t done
    hs[p][jo] = h;
    HOUT[(size_t)row * 128 + j] = h;
    __syncthreads();                       // h visible for t+1
  }
}

// ---------------- attention pool + skip MLP + head ----------------
__global__ __launch_bounds__(64)
void attn_kernel(const float* __restrict__ LO, const float* __restrict__ X,
                 const float* __restrict__ Wa, const float* __restrict__ ba,
                 const float* __restrict__ bs1, const float* __restrict__ bs2,
                 const float* __restrict__ bh1, const float* __restrict__ bh2,
                 const float* __restrict__ Wh2, const float* __restrict__ HWT,
                 float* __restrict__ out)
{
  const int q = blockIdx.x, l = threadIdx.x;
  const float* lob = LO + (size_t)q * 2048;
  float loa[16], lobv[16];
  #pragma unroll
  for (int t = 0; t < 16; ++t) {
    loa[t]  = lob[t * 128 + l];
    lobv[t] = lob[t * 128 + 64 + l];
  }
  const float wa = Wa[l], wb = Wa[64 + l];
  float sc[16];
  #pragma unroll
  for (int t = 0; t < 16; ++t) sc[t] = rsum64(loa[t] * wa + lobv[t] * wb) + ba[0];
  float mx = sc[0];
  #pragma unroll
  for (int t = 1; t < 16; ++t) mx = fmaxf(mx, sc[t]);
  float den = 0.f;
  #pragma unroll
  for (int t = 0; t < 16; ++t) { sc[t] = __expf(sc[t] - mx); den += sc[t]; }
  const float inv = 1.f / den;
  float ca = 0.f, cb = 0.f;
  #pragma unroll
  for (int t = 0; t < 16; ++t) {
    float wgt = sc[t] * inv;
    ca = fmaf(wgt, loa[t], ca);
    cb = fmaf(wgt, lobv[t], cb);
  }
  __shared__ float zsh[160];
  __shared__ float hsk[64];
  __shared__ float skin[16];
  zsh[l] = ca; zsh[64 + l] = cb;
  const int bb = q / 1000, nn = q - bb * 1000;
  if (l < 13) skin[l] = X[(size_t)((bb * 16 + 15) * 1000 + nn) * 32 + l];
  __syncthreads();
  float h1 = bs1[l];
  for (int c = 0; c < 13; ++c) h1 = fmaf(skin[c], HWT[c * 64 + l], h1);
  h1 = geluf(h1);
  hsk[l] = h1;
  __syncthreads();
  if (l < 32) {
    float a = bs2[l];
    for (int jj = 0; jj < 64; ++jj) a = fmaf(hsk[jj], HWT[832 + jj * 32 + l], a);
    zsh[128 + l] = a;
  }
  __syncthreads();
  float hh = bh1[l];
  for (int r = 0; r < 160; ++r) hh = fmaf(zsh[r], HWT[2880 + r * 64 + l], hh);
  hh = geluf(hh);
  float s = rsum64(hh * Wh2[l]);
  if (l == 0) out[q] = s + bh2[0];
}

// ---------------- launch ----------------
extern "C" void kernel_launch(void* const* d_in, const int* in_sizes, int n_in,
                              void* d_out, int out_size, void* d_ws, size_t ws_size,
                              hipStream_t stream)
{
  const float* x    = (const float*)d_in[0];
  const int*   ei   = (const int*)d_in[1];
  const float* Wp   = (const float*)d_in[2];
  const float* bp   = (const float*)d_in[3];
  const float* Wl1  = (const float*)d_in[4];
  const float* Wr1  = (const float*)d_in[5];
  const float* a1   = (const float*)d_in[6];
  const float* bg1  = (const float*)d_in[7];
  const float* g1   = (const float*)d_in[8];
  const float* be1  = (const float*)d_in[9];
  const float* m1   = (const float*)d_in[10];
  const float* v1   = (const float*)d_in[11];
  const float* Wl2  = (const float*)d_in[12];
  const float* Wr2  = (const float*)d_in[13];
  const float* a2   = (const float*)d_in[14];
  const float* bg2  = (const float*)d_in[15];
  const float* g2   = (const float*)d_in[16];
  const float* be2  = (const float*)d_in[17];
  const float* m2   = (const float*)d_in[18];
  const float* v2   = (const float*)d_in[19];
  const float* Wih0 = (const float*)d_in[20];
  const float* Whh0 = (const float*)d_in[21];
  const float* bih0 = (const float*)d_in[22];
  const float* bhh0 = (const float*)d_in[23];
  const float* Wih1 = (const float*)d_in[24];
  const float* Whh1 = (const float*)d_in[25];
  const float* bih1 = (const float*)d_in[26];
  const float* bhh1 = (const float*)d_in[27];
  const float* Wa   = (const float*)d_in[28];
  const float* ba   = (const float*)d_in[29];
  const float* Ws1  = (const float*)d_in[30];
  const float* bs1  = (const float*)d_in[31];
  const float* Ws2  = (const float*)d_in[32];
  const float* bs2  = (const float*)d_in[33];
  const float* Wh1  = (const float*)d_in[34];
  const float* bh1  = (const float*)d_in[35];
  const float* Wh2  = (const float*)d_in[36];
  const float* bh2  = (const float*)d_in[37];

  float* ws = (float*)d_ws;
  int* srcD   = (int*)(ws + O_SRCD);
  int* dstD   = (int*)(ws + O_DSTD);
  int* counts = (int*)(ws + O_COUNTS);
  int* offs   = (int*)(ws + O_OFFS);
  int* curs   = (int*)(ws + O_CURS);
  int* esrc   = (int*)(ws + O_EIDX);
  float* PW1  = ws + O_PW1;
  float* PW2  = ws + O_PW2;
  float* PHH  = ws + O_LW;                                   // 131072 floats
  unsigned short* PWBu = (unsigned short*)(ws + O_LW + 131072u);  // 262144 bf16
  float* BC   = ws + O_BCOMB;
  float* ABF  = ws + O_ABF;
  float* HWT  = ws + O_HWT;
  float* XL1  = ws + O_BIG0;
  float* XR1  = ws + O_BIG1;
  float* H1   = ws + O_BIG2;
  float* XP   = ws + O_BIG3;
  float* Hres = ws + O_BIG4;
  float* XL2  = ws + O_BIG0;             // reuse (XL1 dead)
  float* XR2  = ws + O_BIG0 + 8192000u;
  float* PRE  = ws + O_BIG0;             // spans BIG0+BIG1 (XL/XR dead)
  float* H1SEQ = ws + O_BIG2;            // reuse (H1 dead)
  float* LOp  = ws + O_BIG3;             // reuse (XP dead)
  float* outp = (float*)d_out;

  prep_edges<<<67, 256, 0, stream>>>(ei, srcD, dstD, counts);
  hist_kernel<<<67, 256, 0, stream>>>(dstD, counts);
  scan_kernel<<<1, 1024, 0, stream>>>(counts, offs, curs);
  fill_kernel<<<67, 256, 0, stream>>>(srcD, dstD, curs, esrc);
  pack_kernel<<<1024, 256, 0, stream>>>(Wl1, Wr1, Wp, Wl2, Wr2,
      Wih0, Whh0, bih0, bhh0, Wih1, Whh1, bih1, bhh1,
      g1, be1, m1, v1, bg1, g2, be2, m2, v2, bg2,
      Ws1, Ws2, Wh1, PW1, PW2, PHH, PWBu, BC, ABF, HWT);
  proj1_kernel<<<4000, 320, 0, stream>>>(x, PW1, bp, XL1, XR1, XP);
  gat1_kernel<<<dim3(250, 64), 256, 0, stream>>>(XL1, XR1, esrc, offs, a1, ABF, H1);
  proj2_kernel<<<4000, 256, 0, stream>>>(H1, PW2, XL2, XR2);
  gat2_kernel<<<dim3(250, 64), 256, 0, stream>>>(XL2, XR2, esrc, offs, a2, ABF, XP, Hres);
  gemm_pre_kernel<<<2000, 512, 0, stream>>>(Hres, PWBu, BC, PRE);
  rec_kernel<<<500, 1024, 0, stream>>>(PRE, PHH, H1SEQ);
  gemm_pre_kernel<<<2000, 512, 0, stream>>>(H1SEQ, PWBu + 131072u, BC + 512, PRE);
  rec_kernel<<<500, 1024, 0, stream>>>(PRE, PHH + 65536u, LOp);
  attn_kernel<<<4000, 64, 0, stream>>>(LOp, x, Wa, ba, bs1, bs2, bh1, bh2, Wh2, HWT, outp);
}

// Round 11
// 899.221 us; speedup vs baseline: 2.4197x; 1.0296x over previous
//
#include <hip/hip_runtime.h>

#define EPS_BN 1e-5f

typedef __attribute__((ext_vector_type(8))) short bf16x8;
typedef __attribute__((ext_vector_type(4))) float f32x4;

// ---------------- workspace layout (float-unit offsets) ----------------
#define O_SRCD   0u
#define O_DSTD   17024u
#define O_COUNTS 34048u
#define O_OFFS   35072u
#define O_CURS   36096u
#define O_EIDX   37120u                    // esrc (src node id, CSR-ordered)
#define O_PW1    54144u                    // [32][640]  (Wl1T|Wr1T|WpT)
#define O_PW2    74624u                    // [256][256] (Wl2T|Wr2T)
#define O_LW     140160u                   // PHH (131072 f) + PWB (262144 bf16)
#define O_BCOMB  402304u                   // [2][128j][4]  (gp order)
#define O_ABF    403328u                   // A1(256)|B1(256)|A2(128)|B2(128)
#define O_HWT    404352u                   // Ws1T(832)|Ws2T(2048)|Wh1T(10240)
#define O_BIG0   417536u                   // XL1(bf16) | XL2(bf16),XR2 | pre lower
#define O_BIG1   (O_BIG0 + 16384000u)      // XR1 | pre upper half
#define O_BIG2   (O_BIG1 + 16384000u)      // H1  | h1seq
#define O_BIG3   (O_BIG2 + 16384000u)      // XP  | LO
#define O_BIG4   (O_BIG3 + 8192000u)       // Hres

__device__ __forceinline__ float rsum32(float p) {
  p += __shfl_xor(p, 1);  p += __shfl_xor(p, 2);  p += __shfl_xor(p, 4);
  p += __shfl_xor(p, 8);  p += __shfl_xor(p, 16); return p;
}
__device__ __forceinline__ float rsum64(float p) {
  p = rsum32(p); p += __shfl_xor(p, 32); return p;
}
__device__ __forceinline__ float lrelu(float x) { return x > 0.f ? x : 0.2f * x; }
__device__ __forceinline__ float eluf(float x)  { return x > 0.f ? x : expm1f(x); }
__device__ __forceinline__ float geluf(float x) { return 0.5f * x * (1.f + erff(x * 0.70710678118654752f)); }
__device__ __forceinline__ unsigned short f2bf(float f) {
  unsigned int u = __float_as_uint(f);
  u += 0x7FFFu + ((u >> 16) & 1u);
  return (unsigned short)(u >> 16);
}
__device__ __forceinline__ float bf2f(unsigned short h) {
  return __uint_as_float(((unsigned int)h) << 16);
}
__device__ __forceinline__ float4 bf4f(ushort4 u) {
  return make_float4(bf2f(u.x), bf2f(u.y), bf2f(u.z), bf2f(u.w));
}
__device__ __forceinline__ float2 bf2f2(ushort2 u) {
  return make_float2(bf2f(u.x), bf2f(u.y));
}

// ---------------- prep kernels ----------------
__global__ void prep_edges(const int* __restrict__ ei, int* __restrict__ srcD,
                           int* __restrict__ dstD, int* __restrict__ counts) {
  int i = blockIdx.x * 256 + threadIdx.x;
  if (i < 1024) counts[i] = 0;
  if (i < 17000) {
    int s = (i < 16000) ? ei[i] : (i - 16000);
    int d = (i < 16000) ? ei[16000 + i] : (i - 16000);
    srcD[i] = s; dstD[i] = d;
  }
}
__global__ void hist_kernel(const int* __restrict__ dstD, int* __restrict__ counts) {
  int i = blockIdx.x * 256 + threadIdx.x;
  if (i < 17000) atomicAdd(&counts[dstD[i]], 1);
}
__global__ void scan_kernel(const int* __restrict__ counts, int* __restrict__ offs,
                            int* __restrict__ curs) {
  __shared__ int sh[1024];
  int i = threadIdx.x;
  int v = (i < 1000) ? counts[i] : 0;
  sh[i] = v;
  __syncthreads();
  for (int d = 1; d < 1024; d <<= 1) {
    int t = (i >= d) ? sh[i - d] : 0;
    __syncthreads();
    sh[i] += t;
    __syncthreads();
  }
  if (i < 1000) { offs[i + 1] = sh[i]; curs[i] = sh[i] - v; }
  if (i == 0) offs[0] = 0;
}
__global__ void fill_kernel(const int* __restrict__ srcD, const int* __restrict__ dstD,
                            int* __restrict__ curs, int* __restrict__ esrc) {
  int i = blockIdx.x * 256 + threadIdx.x;
  if (i < 17000) { int p = atomicAdd(&curs[dstD[i]], 1); esrc[p] = srcD[i]; }
}

// PHH: hh weights [L][w16][q4][dk4][lane64][gate4], k = p*16 + q*4 + dk (p = lane>>3)
// PWB: ih weights split-bf16 MFMA B-frags [L][split][kc4][gt32][lane64][e8]
__global__ void pack_kernel(
    const float* __restrict__ Wl1, const float* __restrict__ Wr1, const float* __restrict__ Wp,
    const float* __restrict__ Wl2, const float* __restrict__ Wr2,
    const float* __restrict__ Wih0, const float* __restrict__ Whh0,
    const float* __restrict__ bih0, const float* __restrict__ bhh0,
    const float* __restrict__ Wih1, const float* __restrict__ Whh1,
    const float* __restrict__ bih1, const float* __restrict__ bhh1,
    const float* __restrict__ g1, const float* __restrict__ be1, const float* __restrict__ m1,
    const float* __restrict__ v1, const float* __restrict__ bg1,
    const float* __restrict__ g2, const float* __restrict__ be2, const float* __restrict__ m2,
    const float* __restrict__ v2, const float* __restrict__ bg2,
    const float* __restrict__ Ws1, const float* __restrict__ Ws2, const float* __restrict__ Wh1,
    float* __restrict__ PW1, float* __restrict__ PW2, float* __restrict__ PHH,
    unsigned short* __restrict__ PWBu,
    float* __restrict__ BC, float* __restrict__ ABF, float* __restrict__ HWT)
{
  int i = blockIdx.x * 256 + threadIdx.x;
  if (i < 131072) {  // PHH
    int gate = i & 3, lane = (i >> 2) & 63, dk = (i >> 8) & 3,
        q = (i >> 10) & 3, w = (i >> 12) & 15, L = (i >> 16) & 1;
    int jlo = lane & 7, p = lane >> 3;
    int jj = (w << 3) + jlo;
    int kk = (p << 4) + (q << 2) + dk;
    const float* Whh = L ? Whh1 : Whh0;
    PHH[i] = Whh[(gate * 128 + jj) * 128 + kk];
  }
  if (i < 262144) {  // PWB split-bf16
    int e = i & 7, lane = (i >> 3) & 63, gt = (i >> 9) & 31,
        kc = (i >> 14) & 3, sp = (i >> 16) & 1, L = (i >> 17) & 1;
    int gp = (gt << 4) + (lane & 15);
    int jj = gp >> 2, gate = gp & 3;
    int kk = (kc << 5) + ((lane >> 4) << 3) + e;
    const float* Wih = L ? Wih1 : Wih0;
    float wv = Wih[(gate * 128 + jj) * 128 + kk];
    unsigned short hi = f2bf(wv);
    PWBu[i] = (sp == 0) ? hi : f2bf(wv - bf2f(hi));
  }
  if (i < 65536) { int c = i & 255, k = i >> 8;
    PW2[i] = (c < 128) ? Wl2[c * 256 + k] : Wr2[(c - 128) * 256 + k]; }
  if (i < 20480) { int g = i % 640, k = i / 640;
    PW1[i] = (g < 256) ? Wl1[g * 32 + k] : (g < 512) ? Wr1[(g - 256) * 32 + k]
                                                     : Wp[(g - 512) * 32 + k]; }
  if (i < 1024) { int u = i & 3, jj = (i >> 2) & 127, L = i >> 9;
    BC[i] = (L ? bih1 : bih0)[u * 128 + jj] + (L ? bhh1 : bhh0)[u * 128 + jj]; }
  if (i < 768) {
    if (i < 256) ABF[i] = g1[i] * rsqrtf(v1[i] + EPS_BN);
    else if (i < 512) { int c = i - 256; float a = g1[c] * rsqrtf(v1[c] + EPS_BN);
      ABF[i] = (bg1[c] - m1[c]) * a + be1[c]; }
    else if (i < 640) { int c = i - 512; ABF[i] = g2[c] * rsqrtf(v2[c] + EPS_BN); }
    else { int c = i - 640; float a = g2[c] * rsqrtf(v2[c] + EPS_BN);
      ABF[i] = (bg2[c] - m2[c]) * a + be2[c]; }
  }
  if (i < 13120) {
    if (i < 832) { int l = i & 63, c = i >> 6; HWT[i] = Ws1[l * 13 + c]; }
    else if (i < 2880) { int k = i - 832; int l = k & 31, jj = k >> 5; HWT[i] = Ws2[l * 64 + jj]; }
    else { int k = i - 2880; int l = k & 63, r = k >> 6; HWT[i] = Wh1[l * 160 + r]; }
  }
}

// ---------------- projection 1: x -> xl1(bf16,256) | xr1(256) | xp(128) ------------
__global__ __launch_bounds__(320)
void proj1_kernel(const float* __restrict__ X, const float* __restrict__ PW1,
                  const float* __restrict__ bp, unsigned short* __restrict__ XL1u,
                  float* __restrict__ XR1, float* __restrict__ XP)
{
  __shared__ __align__(16) float xs[32][16];
  const int tid = threadIdx.x;
  const int r0 = blockIdx.x * 16;
  for (int el = tid; el < 512; el += 320) {
    int r = el >> 5, k = el & 31;
    xs[k][r] = X[(size_t)(r0 + r) * 32 + k];
  }
  __syncthreads();
  const int gA = tid, gB = tid + 320;
  float accA[16], accB[16];
  const float iB = (gB >= 512) ? bp[gB - 512] : 0.f;
  #pragma unroll
  for (int r = 0; r < 16; ++r) { accA[r] = 0.f; accB[r] = iB; }
  for (int k = 0; k < 32; ++k) {
    float wA = PW1[k * 640 + gA], wB = PW1[k * 640 + gB];
    float xv[16];
    #pragma unroll
    for (int q = 0; q < 4; ++q)
      *reinterpret_cast<float4*>(&xv[q * 4]) = *reinterpret_cast<const float4*>(&xs[k][q * 4]);
    #pragma unroll
    for (int r = 0; r < 16; ++r) {
      accA[r] = fmaf(wA, xv[r], accA[r]);
      accB[r] = fmaf(wB, xv[r], accB[r]);
    }
  }
  for (int r = 0; r < 16; ++r) {
    size_t row = r0 + r;
    if (gA < 256) XL1u[row * 256 + gA] = f2bf(accA[r]);
    else          XR1[row * 256 + (gA - 256)] = accA[r];
    if (gB < 512) XR1[row * 256 + (gB - 256)] = accB[r];
    else          XP[row * 128 + (gB - 512)] = accB[r];
  }
}

// ---------------- GAT layer 1, one-pass online softmax, bf16 gather ----------------
__global__ __launch_bounds__(256)
void gat1_kernel(const unsigned short* __restrict__ XLu, const float* __restrict__ XR,
                 const int* __restrict__ esrc,
                 const int* __restrict__ offs, const float* __restrict__ a1,
                 const float* __restrict__ ABF, float* __restrict__ H1)
{
  const int lane = threadIdx.x & 63;
  const int wv = threadIdx.x >> 6;
  const int n = blockIdx.x * 4 + wv;
  const int b = blockIdx.y;
  const int beg = offs[n];
  const int deg = offs[n + 1] - beg;
  const float4 a4 = reinterpret_cast<const float4*>(a1)[lane];
  const ushort4* XLb = reinterpret_cast<const ushort4*>(XLu) + (size_t)b * 64000 + lane;
  const float4 xr4 = reinterpret_cast<const float4*>(XR + (size_t)(b * 1000 + n) * 256)[lane];
  float m = -INFINITY, ssum = 0.f;
  float4 acc = make_float4(0.f, 0.f, 0.f, 0.f);
  int sC = esrc[beg];
  ushort4 uc = XLb[(size_t)sC * 64];
  for (int i = 0; i < deg; ++i) {
    int nx = (i + 1 < deg) ? (i + 1) : i;
    int sN = esrc[beg + nx];
    ushort4 un = XLb[(size_t)sN * 64];
    float4 xc = bf4f(uc);
    float p = lrelu(xc.x + xr4.x) * a4.x + lrelu(xc.y + xr4.y) * a4.y
            + lrelu(xc.z + xr4.z) * a4.z + lrelu(xc.w + xr4.w) * a4.w;
    p = rsum32(p);
    float mn = fmaxf(m, p);
    float sc = __expf(m - mn);       // 0 on first iter (m=-inf), 1 if max unchanged
    float we = __expf(p - mn);
    ssum = ssum * sc + we;
    acc.x = fmaf(acc.x, sc, we * xc.x);
    acc.y = fmaf(acc.y, sc, we * xc.y);
    acc.z = fmaf(acc.z, sc, we * xc.z);
    acc.w = fmaf(acc.w, sc, we * xc.w);
    m = mn;
    uc = un;
  }
  const float inv = 1.f / ssum;
  const float4 A4 = reinterpret_cast<const float4*>(ABF)[lane];
  const float4 B4 = reinterpret_cast<const float4*>(ABF + 256)[lane];
  float4 o;
  o.x = eluf(fmaf(acc.x * inv, A4.x, B4.x));
  o.y = eluf(fmaf(acc.y * inv, A4.y, B4.y));
  o.z = eluf(fmaf(acc.z * inv, A4.z, B4.z));
  o.w = eluf(fmaf(acc.w * inv, A4.w, B4.w));
  reinterpret_cast<float4*>(H1 + (size_t)(b * 1000 + n) * 256)[lane] = o;
}

// ---------------- projection 2: h1(256) -> xl2(bf16,128)|xr2(128) ----------------
__global__ __launch_bounds__(256)
void proj2_kernel(const float* __restrict__ H1, const float* __restrict__ PW2,
                  unsigned short* __restrict__ XL2u, float* __restrict__ XR2)
{
  __shared__ __align__(16) float xs[256][20];
  const int tid = threadIdx.x;
  const int r0 = blockIdx.x * 16;
  for (int el = tid; el < 4096; el += 256) {
    int k = el & 255, r = el >> 8;
    xs[k][r] = H1[(size_t)(r0 + r) * 256 + k];
  }
  __syncthreads();
  float acc[16];
  #pragma unroll
  for (int r = 0; r < 16; ++r) acc[r] = 0.f;
  for (int k = 0; k < 256; ++k) {
    float wgt = PW2[k * 256 + tid];
    float xv[16];
    #pragma unroll
    for (int q = 0; q < 4; ++q)
      *reinterpret_cast<float4*>(&xv[q * 4]) = *reinterpret_cast<const float4*>(&xs[k][q * 4]);
    #pragma unroll
    for (int r = 0; r < 16; ++r) acc[r] = fmaf(wgt, xv[r], acc[r]);
  }
  if (tid < 128) {
    for (int r = 0; r < 16; ++r)
      XL2u[(size_t)(r0 + r) * 128 + tid] = f2bf(acc[r]);
  } else {
    const int col = tid - 128;
    for (int r = 0; r < 16; ++r)
      XR2[(size_t)(r0 + r) * 128 + col] = acc[r];
  }
}

// ---------------- GAT layer 2, one-pass online softmax, bf16 gather + residual ------
__global__ __launch_bounds__(256)
void gat2_kernel(const unsigned short* __restrict__ XLu, const float* __restrict__ XR,
                 const int* __restrict__ esrc,
                 const int* __restrict__ offs, const float* __restrict__ a2,
                 const float* __restrict__ ABF, const float* __restrict__ XP,
                 float* __restrict__ Hout)
{
  const int lane = threadIdx.x & 63;
  const int wv = threadIdx.x >> 6;
  const int n = blockIdx.x * 4 + wv;
  const int b = blockIdx.y;
  const int beg = offs[n];
  const int deg = offs[n + 1] - beg;
  const float2 av = reinterpret_cast<const float2*>(a2)[lane];
  const ushort2* XLb = reinterpret_cast<const ushort2*>(XLu) + (size_t)b * 64000 + lane;
  const float2 xr2 = reinterpret_cast<const float2*>(XR + (size_t)(b * 1000 + n) * 128)[lane];
  float m = -INFINITY, ssum = 0.f;
  float2 acc = make_float2(0.f, 0.f);
  int sC = esrc[beg];
  ushort2 uc = XLb[(size_t)sC * 64];
  for (int i = 0; i < deg; ++i) {
    int nx = (i + 1 < deg) ? (i + 1) : i;
    int sN = esrc[beg + nx];
    ushort2 un = XLb[(size_t)sN * 64];
    float2 xc = bf2f2(uc);
    float p = lrelu(xc.x + xr2.x) * av.x + lrelu(xc.y + xr2.y) * av.y;
    p = rsum64(p);
    float mn = fmaxf(m, p);
    float sc = __expf(m - mn);
    float we = __expf(p - mn);
    ssum = ssum * sc + we;
    acc.x = fmaf(acc.x, sc, we * xc.x);
    acc.y = fmaf(acc.y, sc, we * xc.y);
    m = mn;
    uc = un;
  }
  const float inv = 1.f / ssum;
  const float2 A2 = reinterpret_cast<const float2*>(ABF + 512)[lane];
  const float2 B2 = reinterpret_cast<const float2*>(ABF + 640)[lane];
  const float2 xp = reinterpret_cast<const float2*>(XP + (size_t)(b * 1000 + n) * 128)[lane];
  float2 o;
  o.x = eluf(fmaf(acc.x * inv, A2.x, B2.x)) + xp.x;
  o.y = eluf(fmaf(acc.y * inv, A2.y, B2.y)) + xp.y;
  reinterpret_cast<float2*>(Hout + (size_t)(b * 1000 + n) * 128)[lane] = o;
}

// ---------------- MFMA pre-GEMM: PRE[r][gp] = X[r][:] @ WihT[:, gp] + BC[gp] ----------
__global__ __launch_bounds__(512)
void gemm_pre_kernel(const float* __restrict__ X, const unsigned short* __restrict__ PWB,
                     const float* __restrict__ BCL, float* __restrict__ PRE)
{
  const int tid = threadIdx.x;
  const int lane = tid & 63;
  const int wv = tid >> 6;            // 0..7, covers gp [wv*64, wv*64+64)
  const int l15 = lane & 15;
  const int kg = lane >> 4;           // 0..3
  const int r0 = blockIdx.x * 32;
  f32x4 acc[2][4];
  #pragma unroll
  for (int rt = 0; rt < 2; ++rt)
    #pragma unroll
    for (int gt = 0; gt < 4; ++gt)
      #pragma unroll
      for (int e = 0; e < 4; ++e) acc[rt][gt][e] = 0.f;
  for (int kc = 0; kc < 4; ++kc) {
    bf16x8 xh[2], xl[2];
    #pragma unroll
    for (int rt = 0; rt < 2; ++rt) {
      const float* xp = X + (size_t)(r0 + rt * 16 + l15) * 128 + (kc << 5) + (kg << 3);
      float4 va = *reinterpret_cast<const float4*>(xp);
      float4 vb = *reinterpret_cast<const float4*>(xp + 4);
      float xs[8] = {va.x, va.y, va.z, va.w, vb.x, vb.y, vb.z, vb.w};
      #pragma unroll
      for (int e = 0; e < 8; ++e) {
        unsigned short h = f2bf(xs[e]);
        xh[rt][e] = (short)h;
        xl[rt][e] = (short)f2bf(xs[e] - bf2f(h));
      }
    }
    #pragma unroll
    for (int gt = 0; gt < 4; ++gt) {
      const int gtg = (wv << 2) + gt;
      const unsigned short* wp = PWB + ((size_t)(kc * 32 + gtg)) * 512 + lane * 8;
      bf16x8 whi = *reinterpret_cast<const bf16x8*>(wp);
      bf16x8 wlo = *reinterpret_cast<const bf16x8*>(wp + 65536);
      #pragma unroll
      for (int rt = 0; rt < 2; ++rt) {
        acc[rt][gt] = __builtin_amdgcn_mfma_f32_16x16x32_bf16(xh[rt], whi, acc[rt][gt], 0, 0, 0);
        acc[rt][gt] = __builtin_amdgcn_mfma_f32_16x16x32_bf16(xh[rt], wlo, acc[rt][gt], 0, 0, 0);
        acc[rt][gt] = __builtin_amdgcn_mfma_f32_16x16x32_bf16(xl[rt], whi, acc[rt][gt], 0, 0, 0);
      }
    }
  }
  #pragma unroll
  for (int gt = 0; gt < 4; ++gt) {
    const int col = (wv << 6) + (gt << 4) + l15;
    const float bias = BCL[col];
    #pragma unroll
    for (int rt = 0; rt < 2; ++rt) {
      #pragma unroll
      for (int reg = 0; reg < 4; ++reg) {
        const int row = r0 + rt * 16 + (kg << 2) + reg;
        PRE[(size_t)row * 512 + col] = acc[rt][gt][reg] + bias;
      }
    }
  }
}

// ---------------- recurrent hh-only LSTM layer ----------------
#define FMA4(A, W, S) { (A).x = fmaf((W).x, (S), (A).x); (A).y = fmaf((W).y, (S), (A).y); \
                        (A).z = fmaf((W).z, (S), (A).z); (A).w = fmaf((W).w, (S), (A).w); }
#define AD4(a, b) { (a).x += (b).x; (a).y += (b).y; (a).z += (b).z; (a).w += (b).w; }
#define LROW 140

__device__ __forceinline__ float4 shflx4(float4 v, int msk) {
  float4 r;
  r.x = __shfl_xor(v.x, msk); r.y = __shfl_xor(v.y, msk);
  r.z = __shfl_xor(v.z, msk); r.w = __shfl_xor(v.w, msk);
  return r;
}
__device__ __forceinline__ void reduce8to1(float4 (&g)[8], int lane, float4& ga)
{
  const bool b4 = (lane & 32) != 0, b2 = (lane & 16) != 0, b1 = (lane & 8) != 0;
  float4 t[4];
  #pragma unroll
  for (int i = 0; i < 4; ++i) {
    float4 keep = b4 ? g[4 + i] : g[i];
    float4 send = b4 ? g[i] : g[4 + i];
    float4 r = shflx4(send, 32);
    AD4(keep, r); t[i] = keep;
  }
  float4 u[2];
  #pragma unroll
  for (int i = 0; i < 2; ++i) {
    float4 keep = b2 ? t[2 + i] : t[i];
    float4 send = b2 ? t[i] : t[2 + i];
    float4 r = shflx4(send, 16);
    AD4(keep, r); u[i] = keep;
  }
  {
    float4 keep = b1 ? u[1] : u[0];
    float4 send = b1 ? u[0] : u[1];
    float4 r = shflx4(send, 8);
    AD4(keep, r); ga = keep;
  }
}
__device__ __forceinline__ float cellf(float4 g, float& c) {
  const float ig = 1.f / (1.f + __expf(-g.x));
  const float fg = 1.f / (1.f + __expf(-g.y));
  const float gg = tanhf(g.z);
  const float og = 1.f / (1.f + __expf(-g.w));
  c = fmaf(fg, c, ig * gg);
  return og * tanhf(c);
}

__global__ __launch_bounds__(1024)
void rec_kernel(const float* __restrict__ PRE, const float* __restrict__ PHHL,
                float* __restrict__ HOUT)
{
  __shared__ __align__(16) float hs[8][LROW];
  const int tid = threadIdx.x;
  const int lane = tid & 63;
  const int w = tid >> 6;
  const int jlo = lane & 7;
  const int p = lane >> 3;
  const int j = (w << 3) + jlo;
  const int jo = j + ((j >> 5) << 2);
  const int q0 = blockIdx.x << 3;
  for (int i = tid; i < 8 * LROW; i += 1024) (&hs[0][0])[i] = 0.f;
  const float4* W4 = reinterpret_cast<const float4*>(PHHL);
  float cst = 0.f;
  __syncthreads();
  for (int t = 0; t < 16; ++t) {
    float4 g[8];
    #pragma unroll
    for (int s = 0; s < 8; ++s) g[s] = make_float4(0.f, 0.f, 0.f, 0.f);
    #pragma unroll
    for (int q = 0; q < 4; ++q) {
      const float4* wq = W4 + (((w << 2) + q) << 8) + lane;
      float4 w0 = wq[0], w1 = wq[64], w2 = wq[128], w3 = wq[192];
      const int col = (p << 4) + (q << 2);
      const int co = col + ((col >> 5) << 2);
      #pragma unroll
      for (int s = 0; s < 8; ++s) {
        float4 xv = *reinterpret_cast<const float4*>(&hs[s][co]);
        FMA4(g[s], w0, xv.x); FMA4(g[s], w1, xv.y);
        FMA4(g[s], w2, xv.z); FMA4(g[s], w3, xv.w);
      }
    }
    float4 ga;
    reduce8to1(g, lane, ga);
    const int row = ((q0 + p) << 4) + t;
    const float4 pf = *reinterpret_cast<const float4*>(PRE + (size_t)row * 512 + (j << 2));
    AD4(ga, pf);
    float h = cellf(ga, cst);
    __syncthreads();                       // all hs reads of t done
    hs[p][jo] = h;
    HOUT[(size_t)row * 128 + j] = h;
    __syncthreads();                       // h visible for t+1
  }
}

// ---------------- attention pool + skip MLP + head ----------------
__global__ __launch_bounds__(64)
void attn_kernel(const float* __restrict__ LO, const float* __restrict__ X,
                 const float* __restrict__ Wa, const float* __restrict__ ba,
                 const float* __restrict__ bs1, const float* __restrict__ bs2,
                 const float* __restrict__ bh1, const float* __restrict__ bh2,
                 const float* __restrict__ Wh2, const float* __restrict__ HWT,
                 float* __restrict__ out)
{
  const int q = blockIdx.x, l = threadIdx.x;
  const float* lob = LO + (size_t)q * 2048;
  float loa[16], lobv[16];
  #pragma unroll
  for (int t = 0; t < 16; ++t) {
    loa[t]  = lob[t * 128 + l];
    lobv[t] = lob[t * 128 + 64 + l];
  }
  const float wa = Wa[l], wb = Wa[64 + l];
  float sc[16];
  #pragma unroll
  for (int t = 0; t < 16; ++t) sc[t] = rsum64(loa[t] * wa + lobv[t] * wb) + ba[0];
  float mx = sc[0];
  #pragma unroll
  for (int t = 1; t < 16; ++t) mx = fmaxf(mx, sc[t]);
  float den = 0.f;
  #pragma unroll
  for (int t = 0; t < 16; ++t) { sc[t] = __expf(sc[t] - mx); den += sc[t]; }
  const float inv = 1.f / den;
  float ca = 0.f, cb = 0.f;
  #pragma unroll
  for (int t = 0; t < 16; ++t) {
    float wgt = sc[t] * inv;
    ca = fmaf(wgt, loa[t], ca);
    cb = fmaf(wgt, lobv[t], cb);
  }
  __shared__ float zsh[160];
  __shared__ float hsk[64];
  __shared__ float skin[16];
  zsh[l] = ca; zsh[64 + l] = cb;
  const int bb = q / 1000, nn = q - bb * 1000;
  if (l < 13) skin[l] = X[(size_t)((bb * 16 + 15) * 1000 + nn) * 32 + l];
  __syncthreads();
  float h1 = bs1[l];
  for (int c = 0; c < 13; ++c) h1 = fmaf(skin[c], HWT[c * 64 + l], h1);
  h1 = geluf(h1);
  hsk[l] = h1;
  __syncthreads();
  if (l < 32) {
    float a = bs2[l];
    for (int jj = 0; jj < 64; ++jj) a = fmaf(hsk[jj], HWT[832 + jj * 32 + l], a);
    zsh[128 + l] = a;
  }
  __syncthreads();
  float hh = bh1[l];
  for (int r = 0; r < 160; ++r) hh = fmaf(zsh[r], HWT[2880 + r * 64 + l], hh);
  hh = geluf(hh);
  float s = rsum64(hh * Wh2[l]);
  if (l == 0) out[q] = s + bh2[0];
}

// ---------------- launch ----------------
extern "C" void kernel_launch(void* const* d_in, const int* in_sizes, int n_in,
                              void* d_out, int out_size, void* d_ws, size_t ws_size,
                              hipStream_t stream)
{
  const float* x    = (const float*)d_in[0];
  const int*   ei   = (const int*)d_in[1];
  const float* Wp   = (const float*)d_in[2];
  const float* bp   = (const float*)d_in[3];
  const float* Wl1  = (const float*)d_in[4];
  const float* Wr1  = (const float*)d_in[5];
  const float* a1   = (const float*)d_in[6];
  const float* bg1  = (const float*)d_in[7];
  const float* g1   = (const float*)d_in[8];
  const float* be1  = (const float*)d_in[9];
  const float* m1   = (const float*)d_in[10];
  const float* v1   = (const float*)d_in[11];
  const float* Wl2  = (const float*)d_in[12];
  const float* Wr2  = (const float*)d_in[13];
  const float* a2   = (const float*)d_in[14];
  const float* bg2  = (const float*)d_in[15];
  const float* g2   = (const float*)d_in[16];
  const float* be2  = (const float*)d_in[17];
  const float* m2   = (const float*)d_in[18];
  const float* v2   = (const float*)d_in[19];
  const float* Wih0 = (const float*)d_in[20];
  const float* Whh0 = (const float*)d_in[21];
  const float* bih0 = (const float*)d_in[22];
  const float* bhh0 = (const float*)d_in[23];
  const float* Wih1 = (const float*)d_in[24];
  const float* Whh1 = (const float*)d_in[25];
  const float* bih1 = (const float*)d_in[26];
  const float* bhh1 = (const float*)d_in[27];
  const float* Wa   = (const float*)d_in[28];
  const float* ba   = (const float*)d_in[29];
  const float* Ws1  = (const float*)d_in[30];
  const float* bs1  = (const float*)d_in[31];
  const float* Ws2  = (const float*)d_in[32];
  const float* bs2  = (const float*)d_in[33];
  const float* Wh1  = (const float*)d_in[34];
  const float* bh1  = (const float*)d_in[35];
  const float* Wh2  = (const float*)d_in[36];
  const float* bh2  = (const float*)d_in[37];

  float* ws = (float*)d_ws;
  int* srcD   = (int*)(ws + O_SRCD);
  int* dstD   = (int*)(ws + O_DSTD);
  int* counts = (int*)(ws + O_COUNTS);
  int* offs   = (int*)(ws + O_OFFS);
  int* curs   = (int*)(ws + O_CURS);
  int* esrc   = (int*)(ws + O_EIDX);
  float* PW1  = ws + O_PW1;
  float* PW2  = ws + O_PW2;
  float* PHH  = ws + O_LW;                                   // 131072 floats
  unsigned short* PWBu = (unsigned short*)(ws + O_LW + 131072u);  // 262144 bf16
  float* BC   = ws + O_BCOMB;
  float* ABF  = ws + O_ABF;
  float* HWT  = ws + O_HWT;
  unsigned short* XL1u = (unsigned short*)(ws + O_BIG0);   // 16.4M bf16 = 8.2M f-slots
  float* XR1  = ws + O_BIG1;
  float* H1   = ws + O_BIG2;
  float* XP   = ws + O_BIG3;
  float* Hres = ws + O_BIG4;
  unsigned short* XL2u = (unsigned short*)(ws + O_BIG0);   // reuse (XL1 dead)
  float* XR2  = ws + O_BIG0 + 8192000u;
  float* PRE  = ws + O_BIG0;             // spans BIG0+BIG1 (XL/XR dead)
  float* H1SEQ = ws + O_BIG2;            // reuse (H1 dead)
  float* LOp  = ws + O_BIG3;             // reuse (XP dead)
  float* outp = (float*)d_out;

  prep_edges<<<67, 256, 0, stream>>>(ei, srcD, dstD, counts);
  hist_kernel<<<67, 256, 0, stream>>>(dstD, counts);
  scan_kernel<<<1, 1024, 0, stream>>>(counts, offs, curs);
  fill_kernel<<<67, 256, 0, stream>>>(srcD, dstD, curs, esrc);
  pack_kernel<<<1024, 256, 0, stream>>>(Wl1, Wr1, Wp, Wl2, Wr2,
      Wih0, Whh0, bih0, bhh0, Wih1, Whh1, bih1, bhh1,
      g1, be1, m1, v1, bg1, g2, be2, m2, v2, bg2,
      Ws1, Ws2, Wh1, PW1, PW2, PHH, PWBu, BC, ABF, HWT);
  proj1_kernel<<<4000, 320, 0, stream>>>(x, PW1, bp, XL1u, XR1, XP);
  gat1_kernel<<<dim3(250, 64), 256, 0, stream>>>(XL1u, XR1, esrc, offs, a1, ABF, H1);
  proj2_kernel<<<4000, 256, 0, stream>>>(H1, PW2, XL2u, XR2);
  gat2_kernel<<<dim3(250, 64), 256, 0, stream>>>(XL2u, XR2, esrc, offs, a2, ABF, XP, Hres);
  gemm_pre_kernel<<<2000, 512, 0, stream>>>(Hres, PWBu, BC, PRE);
  rec_kernel<<<500, 1024, 0, stream>>>(PRE, PHH, H1SEQ);
  gemm_pre_kernel<<<2000, 512, 0, stream>>>(H1SEQ, PWBu + 131072u, BC + 512, PRE);
  rec_kernel<<<500, 1024, 0, stream>>>(PRE, PHH + 65536u, LOp);
  attn_kernel<<<4000, 64, 0, stream>>>(LOp, x, Wa, ba, bs1, bs2, bh1, bh2, Wh2, HWT, outp);
}

// Round 12
// 721.023 us; speedup vs baseline: 3.0178x; 1.2471x over previous
//
#include <hip/hip_runtime.h>
#include <hip/hip_fp16.h>

#define EPS_BN 1e-5f

typedef __attribute__((ext_vector_type(8))) short bf16x8;
typedef __attribute__((ext_vector_type(4))) float f32x4;

// ---------------- workspace layout (float-unit offsets) ----------------
#define O_SRCD   0u
#define O_DSTD   17024u
#define O_COUNTS 34048u
#define O_OFFS   35072u
#define O_CURS   36096u
#define O_EIDX   37120u                    // esrc (src node id, CSR-ordered)
#define O_PW1    54144u                    // [32][640]  (Wl1T|Wr1T|WpT)
#define O_PW2    74624u                    // [256][256] (Wl2T|Wr2T)
#define O_LW     140160u                   // PHHB (262144 bf16) + PWB (262144 bf16)
#define O_BCOMB  402304u                   // [2][128j][4]  (gp order)
#define O_ABF    403328u                   // A1(256)|B1(256)|A2(128)|B2(128)
#define O_HWT    404352u                   // Ws1T(832)|Ws2T(2048)|Wh1T(10240)
#define O_BIG0   417536u                   // XL1(bf16) | XL2(bf16),XR2 | PRE(fp16)
#define O_BIG1   (O_BIG0 + 16384000u)      // XR1
#define O_BIG2   (O_BIG1 + 16384000u)      // H1  | h1seq
#define O_BIG3   (O_BIG2 + 16384000u)      // XP  | LO
#define O_BIG4   (O_BIG3 + 8192000u)       // Hres

__device__ __forceinline__ float rsum32(float p) {
  p += __shfl_xor(p, 1);  p += __shfl_xor(p, 2);  p += __shfl_xor(p, 4);
  p += __shfl_xor(p, 8);  p += __shfl_xor(p, 16); return p;
}
__device__ __forceinline__ float rsum64(float p) {
  p = rsum32(p); p += __shfl_xor(p, 32); return p;
}
__device__ __forceinline__ float lrelu(float x) { return x > 0.f ? x : 0.2f * x; }
__device__ __forceinline__ float eluf(float x)  { return x > 0.f ? x : expm1f(x); }
__device__ __forceinline__ float geluf(float x) { return 0.5f * x * (1.f + erff(x * 0.70710678118654752f)); }
__device__ __forceinline__ unsigned short f2bf(float f) {
  unsigned int u = __float_as_uint(f);
  u += 0x7FFFu + ((u >> 16) & 1u);
  return (unsigned short)(u >> 16);
}
__device__ __forceinline__ float bf2f(unsigned short h) {
  return __uint_as_float(((unsigned int)h) << 16);
}
__device__ __forceinline__ float4 bf4f(ushort4 u) {
  return make_float4(bf2f(u.x), bf2f(u.y), bf2f(u.z), bf2f(u.w));
}
__device__ __forceinline__ float2 bf2f2(ushort2 u) {
  return make_float2(bf2f(u.x), bf2f(u.y));
}
__device__ __forceinline__ unsigned short f2h(float x) {
  __half h = __float2half(x);
  return *reinterpret_cast<unsigned short*>(&h);
}
__device__ __forceinline__ float h2f(unsigned short u) {
  __half h = *reinterpret_cast<__half*>(&u);
  return __half2float(h);
}

// ---------------- prep kernels ----------------
__global__ void prep_edges(const int* __restrict__ ei, int* __restrict__ srcD,
                           int* __restrict__ dstD, int* __restrict__ counts) {
  int i = blockIdx.x * 256 + threadIdx.x;
  if (i < 1024) counts[i] = 0;
  if (i < 17000) {
    int s = (i < 16000) ? ei[i] : (i - 16000);
    int d = (i < 16000) ? ei[16000 + i] : (i - 16000);
    srcD[i] = s; dstD[i] = d;
  }
}
__global__ void hist_kernel(const int* __restrict__ dstD, int* __restrict__ counts) {
  int i = blockIdx.x * 256 + threadIdx.x;
  if (i < 17000) atomicAdd(&counts[dstD[i]], 1);
}
__global__ void scan_kernel(const int* __restrict__ counts, int* __restrict__ offs,
                            int* __restrict__ curs) {
  __shared__ int sh[1024];
  int i = threadIdx.x;
  int v = (i < 1000) ? counts[i] : 0;
  sh[i] = v;
  __syncthreads();
  for (int d = 1; d < 1024; d <<= 1) {
    int t = (i >= d) ? sh[i - d] : 0;
    __syncthreads();
    sh[i] += t;
    __syncthreads();
  }
  if (i < 1000) { offs[i + 1] = sh[i]; curs[i] = sh[i] - v; }
  if (i == 0) offs[0] = 0;
}
__global__ void fill_kernel(const int* __restrict__ srcD, const int* __restrict__ dstD,
                            int* __restrict__ curs, int* __restrict__ esrc) {
  int i = blockIdx.x * 256 + threadIdx.x;
  if (i < 17000) { int p = atomicAdd(&curs[dstD[i]], 1); esrc[p] = srcD[i]; }
}

// PHHB: hh weights split-bf16 MFMA B-frags [L][split][kc4][gt32][lane64][e8]
// PWB : ih weights, same layout. gp = gt*16 + (lane&15) = j*4+gate; k = kc*32+(lane>>4)*8+e
__global__ void pack_kernel(
    const float* __restrict__ Wl1, const float* __restrict__ Wr1, const float* __restrict__ Wp,
    const float* __restrict__ Wl2, const float* __restrict__ Wr2,
    const float* __restrict__ Wih0, const float* __restrict__ Whh0,
    const float* __restrict__ bih0, const float* __restrict__ bhh0,
    const float* __restrict__ Wih1, const float* __restrict__ Whh1,
    const float* __restrict__ bih1, const float* __restrict__ bhh1,
    const float* __restrict__ g1, const float* __restrict__ be1, const float* __restrict__ m1,
    const float* __restrict__ v1, const float* __restrict__ bg1,
    const float* __restrict__ g2, const float* __restrict__ be2, const float* __restrict__ m2,
    const float* __restrict__ v2, const float* __restrict__ bg2,
    const float* __restrict__ Ws1, const float* __restrict__ Ws2, const float* __restrict__ Wh1,
    float* __restrict__ PW1, float* __restrict__ PW2,
    unsigned short* __restrict__ PHHBu, unsigned short* __restrict__ PWBu,
    float* __restrict__ BC, float* __restrict__ ABF, float* __restrict__ HWT)
{
  int i = blockIdx.x * 256 + threadIdx.x;
  if (i < 262144) {  // PHHB + PWB split-bf16 (identical index decomposition)
    int e = i & 7, lane = (i >> 3) & 63, gt = (i >> 9) & 31,
        kc = (i >> 14) & 3, sp = (i >> 16) & 1, L = (i >> 17) & 1;
    int gp = (gt << 4) + (lane & 15);
    int jj = gp >> 2, gate = gp & 3;
    int kk = (kc << 5) + ((lane >> 4) << 3) + e;
    const float* Wih = L ? Wih1 : Wih0;
    const float* Whh = L ? Whh1 : Whh0;
    float wv = Wih[(gate * 128 + jj) * 128 + kk];
    unsigned short hi = f2bf(wv);
    PWBu[i] = (sp == 0) ? hi : f2bf(wv - bf2f(hi));
    float hv = Whh[(gate * 128 + jj) * 128 + kk];
    unsigned short hhi = f2bf(hv);
    PHHBu[i] = (sp == 0) ? hhi : f2bf(hv - bf2f(hhi));
  }
  if (i < 65536) { int c = i & 255, k = i >> 8;
    PW2[i] = (c < 128) ? Wl2[c * 256 + k] : Wr2[(c - 128) * 256 + k]; }
  if (i < 20480) { int g = i % 640, k = i / 640;
    PW1[i] = (g < 256) ? Wl1[g * 32 + k] : (g < 512) ? Wr1[(g - 256) * 32 + k]
                                                     : Wp[(g - 512) * 32 + k]; }
  if (i < 1024) { int u = i & 3, jj = (i >> 2) & 127, L = i >> 9;
    BC[i] = (L ? bih1 : bih0)[u * 128 + jj] + (L ? bhh1 : bhh0)[u * 128 + jj]; }
  if (i < 768) {
    if (i < 256) ABF[i] = g1[i] * rsqrtf(v1[i] + EPS_BN);
    else if (i < 512) { int c = i - 256; float a = g1[c] * rsqrtf(v1[c] + EPS_BN);
      ABF[i] = (bg1[c] - m1[c]) * a + be1[c]; }
    else if (i < 640) { int c = i - 512; ABF[i] = g2[c] * rsqrtf(v2[c] + EPS_BN); }
    else { int c = i - 640; float a = g2[c] * rsqrtf(v2[c] + EPS_BN);
      ABF[i] = (bg2[c] - m2[c]) * a + be2[c]; }
  }
  if (i < 13120) {
    if (i < 832) { int l = i & 63, c = i >> 6; HWT[i] = Ws1[l * 13 + c]; }
    else if (i < 2880) { int k = i - 832; int l = k & 31, jj = k >> 5; HWT[i] = Ws2[l * 64 + jj]; }
    else { int k = i - 2880; int l = k & 63, r = k >> 6; HWT[i] = Wh1[l * 160 + r]; }
  }
}

// ---------------- projection 1: x -> xl1(bf16,256) | xr1(256) | xp(128) ------------
__global__ __launch_bounds__(320)
void proj1_kernel(const float* __restrict__ X, const float* __restrict__ PW1,
                  const float* __restrict__ bp, unsigned short* __restrict__ XL1u,
                  float* __restrict__ XR1, float* __restrict__ XP)
{
  __shared__ __align__(16) float xs[32][16];
  const int tid = threadIdx.x;
  const int r0 = blockIdx.x * 16;
  for (int el = tid; el < 512; el += 320) {
    int r = el >> 5, k = el & 31;
    xs[k][r] = X[(size_t)(r0 + r) * 32 + k];
  }
  __syncthreads();
  const int gA = tid, gB = tid + 320;
  float accA[16], accB[16];
  const float iB = (gB >= 512) ? bp[gB - 512] : 0.f;
  #pragma unroll
  for (int r = 0; r < 16; ++r) { accA[r] = 0.f; accB[r] = iB; }
  for (int k = 0; k < 32; ++k) {
    float wA = PW1[k * 640 + gA], wB = PW1[k * 640 + gB];
    float xv[16];
    #pragma unroll
    for (int q = 0; q < 4; ++q)
      *reinterpret_cast<float4*>(&xv[q * 4]) = *reinterpret_cast<const float4*>(&xs[k][q * 4]);
    #pragma unroll
    for (int r = 0; r < 16; ++r) {
      accA[r] = fmaf(wA, xv[r], accA[r]);
      accB[r] = fmaf(wB, xv[r], accB[r]);
    }
  }
  for (int r = 0; r < 16; ++r) {
    size_t row = r0 + r;
    if (gA < 256) XL1u[row * 256 + gA] = f2bf(accA[r]);
    else          XR1[row * 256 + (gA - 256)] = accA[r];
    if (gB < 512) XR1[row * 256 + (gB - 256)] = accB[r];
    else          XP[row * 128 + (gB - 512)] = accB[r];
  }
}

// ---------------- GAT layer 1, one-pass online softmax, bf16 gather ----------------
__global__ __launch_bounds__(256)
void gat1_kernel(const unsigned short* __restrict__ XLu, const float* __restrict__ XR,
                 const int* __restrict__ esrc,
                 const int* __restrict__ offs, const float* __restrict__ a1,
                 const float* __restrict__ ABF, float* __restrict__ H1)
{
  const int lane = threadIdx.x & 63;
  const int wv = threadIdx.x >> 6;
  const int n = blockIdx.x * 4 + wv;
  const int b = blockIdx.y;
  const int beg = offs[n];
  const int deg = offs[n + 1] - beg;
  const float4 a4 = reinterpret_cast<const float4*>(a1)[lane];
  const ushort4* XLb = reinterpret_cast<const ushort4*>(XLu) + (size_t)b * 64000 + lane;
  const float4 xr4 = reinterpret_cast<const float4*>(XR + (size_t)(b * 1000 + n) * 256)[lane];
  float m = -INFINITY, ssum = 0.f;
  float4 acc = make_float4(0.f, 0.f, 0.f, 0.f);
  int sC = esrc[beg];
  ushort4 uc = XLb[(size_t)sC * 64];
  for (int i = 0; i < deg; ++i) {
    int nx = (i + 1 < deg) ? (i + 1) : i;
    int sN = esrc[beg + nx];
    ushort4 un = XLb[(size_t)sN * 64];
    float4 xc = bf4f(uc);
    float p = lrelu(xc.x + xr4.x) * a4.x + lrelu(xc.y + xr4.y) * a4.y
            + lrelu(xc.z + xr4.z) * a4.z + lrelu(xc.w + xr4.w) * a4.w;
    p = rsum32(p);
    float mn = fmaxf(m, p);
    float sc = __expf(m - mn);
    float we = __expf(p - mn);
    ssum = ssum * sc + we;
    acc.x = fmaf(acc.x, sc, we * xc.x);
    acc.y = fmaf(acc.y, sc, we * xc.y);
    acc.z = fmaf(acc.z, sc, we * xc.z);
    acc.w = fmaf(acc.w, sc, we * xc.w);
    m = mn;
    uc = un;
  }
  const float inv = 1.f / ssum;
  const float4 A4 = reinterpret_cast<const float4*>(ABF)[lane];
  const float4 B4 = reinterpret_cast<const float4*>(ABF + 256)[lane];
  float4 o;
  o.x = eluf(fmaf(acc.x * inv, A4.x, B4.x));
  o.y = eluf(fmaf(acc.y * inv, A4.y, B4.y));
  o.z = eluf(fmaf(acc.z * inv, A4.z, B4.z));
  o.w = eluf(fmaf(acc.w * inv, A4.w, B4.w));
  reinterpret_cast<float4*>(H1 + (size_t)(b * 1000 + n) * 256)[lane] = o;
}

// ---------------- projection 2: h1(256) -> xl2(bf16,128)|xr2(128) ----------------
__global__ __launch_bounds__(256)
void proj2_kernel(const float* __restrict__ H1, const float* __restrict__ PW2,
                  unsigned short* __restrict__ XL2u, float* __restrict__ XR2)
{
  __shared__ __align__(16) float xs[256][20];
  const int tid = threadIdx.x;
  const int r0 = blockIdx.x * 16;
  for (int el = tid; el < 4096; el += 256) {
    int k = el & 255, r = el >> 8;
    xs[k][r] = H1[(size_t)(r0 + r) * 256 + k];
  }
  __syncthreads();
  float acc[16];
  #pragma unroll
  for (int r = 0; r < 16; ++r) acc[r] = 0.f;
  for (int k = 0; k < 256; ++k) {
    float wgt = PW2[k * 256 + tid];
    float xv[16];
    #pragma unroll
    for (int q = 0; q < 4; ++q)
      *reinterpret_cast<float4*>(&xv[q * 4]) = *reinterpret_cast<const float4*>(&xs[k][q * 4]);
    #pragma unroll
    for (int r = 0; r < 16; ++r) acc[r] = fmaf(wgt, xv[r], acc[r]);
  }
  if (tid < 128) {
    for (int r = 0; r < 16; ++r)
      XL2u[(size_t)(r0 + r) * 128 + tid] = f2bf(acc[r]);
  } else {
    const int col = tid - 128;
    for (int r = 0; r < 16; ++r)
      XR2[(size_t)(r0 + r) * 128 + col] = acc[r];
  }
}

// ---------------- GAT layer 2, one-pass online softmax, bf16 gather + residual ------
__global__ __launch_bounds__(256)
void gat2_kernel(const unsigned short* __restrict__ XLu, const float* __restrict__ XR,
                 const int* __restrict__ esrc,
                 const int* __restrict__ offs, const float* __restrict__ a2,
                 const float* __restrict__ ABF, const float* __restrict__ XP,
                 float* __restrict__ Hout)
{
  const int lane = threadIdx.x & 63;
  const int wv = threadIdx.x >> 6;
  const int n = blockIdx.x * 4 + wv;
  const int b = blockIdx.y;
  const int beg = offs[n];
  const int deg = offs[n + 1] - beg;
  const float2 av = reinterpret_cast<const float2*>(a2)[lane];
  const ushort2* XLb = reinterpret_cast<const ushort2*>(XLu) + (size_t)b * 64000 + lane;
  const float2 xr2 = reinterpret_cast<const float2*>(XR + (size_t)(b * 1000 + n) * 128)[lane];
  float m = -INFINITY, ssum = 0.f;
  float2 acc = make_float2(0.f, 0.f);
  int sC = esrc[beg];
  ushort2 uc = XLb[(size_t)sC * 64];
  for (int i = 0; i < deg; ++i) {
    int nx = (i + 1 < deg) ? (i + 1) : i;
    int sN = esrc[beg + nx];
    ushort2 un = XLb[(size_t)sN * 64];
    float2 xc = bf2f2(uc);
    float p = lrelu(xc.x + xr2.x) * av.x + lrelu(xc.y + xr2.y) * av.y;
    p = rsum64(p);
    float mn = fmaxf(m, p);
    float sc = __expf(m - mn);
    float we = __expf(p - mn);
    ssum = ssum * sc + we;
    acc.x = fmaf(acc.x, sc, we * xc.x);
    acc.y = fmaf(acc.y, sc, we * xc.y);
    m = mn;
    uc = un;
  }
  const float inv = 1.f / ssum;
  const float2 A2 = reinterpret_cast<const float2*>(ABF + 512)[lane];
  const float2 B2 = reinterpret_cast<const float2*>(ABF + 640)[lane];
  const float2 xp = reinterpret_cast<const float2*>(XP + (size_t)(b * 1000 + n) * 128)[lane];
  float2 o;
  o.x = eluf(fmaf(acc.x * inv, A2.x, B2.x)) + xp.x;
  o.y = eluf(fmaf(acc.y * inv, A2.y, B2.y)) + xp.y;
  reinterpret_cast<float2*>(Hout + (size_t)(b * 1000 + n) * 128)[lane] = o;
}

// ---------------- MFMA pre-GEMM: PRE[r][gp] = fp16( X[r][:] @ WihT[:,gp] + BC[gp] ) ----
__global__ __launch_bounds__(512)
void gemm_pre_kernel(const float* __restrict__ X, const unsigned short* __restrict__ PWB,
                     const float* __restrict__ BCL, unsigned short* __restrict__ PREh)
{
  const int tid = threadIdx.x;
  const int lane = tid & 63;
  const int wv = tid >> 6;
  const int l15 = lane & 15;
  const int kg = lane >> 4;
  const int r0 = blockIdx.x * 32;
  f32x4 acc[2][4];
  #pragma unroll
  for (int rt = 0; rt < 2; ++rt)
    #pragma unroll
    for (int gt = 0; gt < 4; ++gt)
      #pragma unroll
      for (int e = 0; e < 4; ++e) acc[rt][gt][e] = 0.f;
  for (int kc = 0; kc < 4; ++kc) {
    bf16x8 xh[2], xl[2];
    #pragma unroll
    for (int rt = 0; rt < 2; ++rt) {
      const float* xp = X + (size_t)(r0 + rt * 16 + l15) * 128 + (kc << 5) + (kg << 3);
      float4 va = *reinterpret_cast<const float4*>(xp);
      float4 vb = *reinterpret_cast<const float4*>(xp + 4);
      float xs[8] = {va.x, va.y, va.z, va.w, vb.x, vb.y, vb.z, vb.w};
      #pragma unroll
      for (int e = 0; e < 8; ++e) {
        unsigned short h = f2bf(xs[e]);
        xh[rt][e] = (short)h;
        xl[rt][e] = (short)f2bf(xs[e] - bf2f(h));
      }
    }
    #pragma unroll
    for (int gt = 0; gt < 4; ++gt) {
      const int gtg = (wv << 2) + gt;
      const unsigned short* wp = PWB + ((size_t)(kc * 32 + gtg)) * 512 + lane * 8;
      bf16x8 whi = *reinterpret_cast<const bf16x8*>(wp);
      bf16x8 wlo = *reinterpret_cast<const bf16x8*>(wp + 65536);
      #pragma unroll
      for (int rt = 0; rt < 2; ++rt) {
        acc[rt][gt] = __builtin_amdgcn_mfma_f32_16x16x32_bf16(xh[rt], whi, acc[rt][gt], 0, 0, 0);
        acc[rt][gt] = __builtin_amdgcn_mfma_f32_16x16x32_bf16(xh[rt], wlo, acc[rt][gt], 0, 0, 0);
        acc[rt][gt] = __builtin_amdgcn_mfma_f32_16x16x32_bf16(xl[rt], whi, acc[rt][gt], 0, 0, 0);
      }
    }
  }
  #pragma unroll
  for (int gt = 0; gt < 4; ++gt) {
    const int col = (wv << 6) + (gt << 4) + l15;
    const float bias = BCL[col];
    #pragma unroll
    for (int rt = 0; rt < 2; ++rt) {
      #pragma unroll
      for (int reg = 0; reg < 4; ++reg) {
        const int row = r0 + rt * 16 + (kg << 2) + reg;
        PREh[(size_t)row * 512 + col] = f2h(acc[rt][gt][reg] + bias);
      }
    }
  }
}

// ---------------- MFMA recurrent hh LSTM layer ----------------
__device__ __forceinline__ float cellf(float4 g, float& c) {
  const float ig = 1.f / (1.f + __expf(-g.x));
  const float fg = 1.f / (1.f + __expf(-g.y));
  const float gg = tanhf(g.z);
  const float og = 1.f / (1.f + __expf(-g.w));
  c = fmaf(fg, c, ig * gg);
  return og * tanhf(c);
}

// 250 blocks x 512 thr (8 waves), 16 seqs/block. Whh-hi resident in LDS (128 KB),
// Whh-lo streamed from L2 each t. h kept as split-bf16 A-fragments in LDS, written
// in place by the epilogue. Per t: 48 MFMA/wave + quad-transpose + cellf.
__global__ __launch_bounds__(512)
void rec2_kernel(const unsigned short* __restrict__ PREh,
                 const unsigned short* __restrict__ PHHB,
                 float* __restrict__ HOUT)
{
  __shared__ unsigned short whi[65536];        // [kc4][gt32][lane64][e8] = 128 KB
  __shared__ unsigned short afr[2][4][64][8];  // [split][kc][lane][e]   = 8 KB
  const int tid = threadIdx.x;
  const int lane = tid & 63;
  const int w = tid >> 6;                      // 0..7: gates [w*64, w*64+64)
  const int l15 = lane & 15;
  const int kg = lane >> 4;
  const int q0 = blockIdx.x << 4;
  for (int i = tid; i < 8192; i += 512)
    reinterpret_cast<uint4*>(whi)[i] = reinterpret_cast<const uint4*>(PHHB)[i];
  reinterpret_cast<uint4*>(&afr[0][0][0][0])[tid] = make_uint4(0u, 0u, 0u, 0u);
  const unsigned short* wloG = PHHB + 65536;
  float cs[4] = {0.f, 0.f, 0.f, 0.f};
  const int qq = l15 & 3;                      // quad pos (gate before transpose)
  const int uu = l15 >> 2;                     // unit-in-tile
  const int seq = (kg << 2) + qq;              // seq after transpose
  for (int t = 0; t < 16; ++t) {
    __syncthreads();                           // afr (t's A-frags) visible
    bf16x8 ah[4], al[4];
    #pragma unroll
    for (int kc = 0; kc < 4; ++kc) {
      ah[kc] = *reinterpret_cast<const bf16x8*>(&afr[0][kc][lane][0]);
      al[kc] = *reinterpret_cast<const bf16x8*>(&afr[1][kc][lane][0]);
    }
    f32x4 acc[4];
    #pragma unroll
    for (int gl = 0; gl < 4; ++gl)
      #pragma unroll
      for (int e = 0; e < 4; ++e) acc[gl][e] = 0.f;
    #pragma unroll
    for (int gl = 0; gl < 4; ++gl) {
      const int gt = (w << 2) + gl;
      #pragma unroll
      for (int kc = 0; kc < 4; ++kc) {
        const int off = ((kc * 32 + gt) * 64 + lane) * 8;
        bf16x8 wh = *reinterpret_cast<const bf16x8*>(&whi[off]);
        bf16x8 wl = *reinterpret_cast<const bf16x8*>(&wloG[off]);
        acc[gl] = __builtin_amdgcn_mfma_f32_16x16x32_bf16(ah[kc], wh, acc[gl], 0, 0, 0);
        acc[gl] = __builtin_amdgcn_mfma_f32_16x16x32_bf16(ah[kc], wl, acc[gl], 0, 0, 0);
        acc[gl] = __builtin_amdgcn_mfma_f32_16x16x32_bf16(al[kc], wh, acc[gl], 0, 0, 0);
      }
    }
    __syncthreads();                           // all A reads done before overwrite
    const int row = ((q0 + seq) << 4) + t;
    #pragma unroll
    for (int gl = 0; gl < 4; ++gl) {
      const int gt = (w << 2) + gl;
      // 4x4 quad transpose: lane ends with the 4 gates of (seq, unit)
      float in0 = acc[gl][0], in1 = acc[gl][1], in2 = acc[gl][2], in3 = acc[gl][3];
      float s0 = __shfl_xor(in1, 1), s1 = __shfl_xor(in0, 1),
            s2 = __shfl_xor(in3, 1), s3 = __shfl_xor(in2, 1);
      const bool b0 = (qq & 1);
      float t0 = b0 ? s0 : in0;
      float t1 = b0 ? in1 : s1;
      float t2 = b0 ? s2 : in2;
      float t3 = b0 ? in3 : s3;
      float u0 = __shfl_xor(t2, 2), u1 = __shfl_xor(t3, 2),
            u2 = __shfl_xor(t0, 2), u3 = __shfl_xor(t1, 2);
      const bool b1 = (qq & 2);
      float g0 = b1 ? u0 : t0;
      float g1 = b1 ? u1 : t1;
      float g2 = b1 ? t2 : u2;
      float g3 = b1 ? t3 : u3;
      const unsigned short* pp = PREh + (size_t)row * 512 + (gt << 4) + (uu << 2);
      ushort4 pu = *reinterpret_cast<const ushort4*>(pp);
      float4 gv = make_float4(g0 + h2f(pu.x), g1 + h2f(pu.y),
                              g2 + h2f(pu.z), g3 + h2f(pu.w));
      float h = cellf(gv, cs[gl]);
      const int unit = (gt << 2) + uu;
      HOUT[(size_t)row * 128 + unit] = h;
      if (t < 15) {
        unsigned short hh = f2bf(h);
        unsigned short hl = f2bf(h - bf2f(hh));
        const int kc2 = unit >> 5;
        const int lane2 = seq | (((unit & 31) >> 3) << 4);
        const int e2 = unit & 7;
        afr[0][kc2][lane2][e2] = hh;
        afr[1][kc2][lane2][e2] = hl;
      }
    }
  }
}

// ---------------- attention pool + skip MLP + head ----------------
__global__ __launch_bounds__(64)
void attn_kernel(const float* __restrict__ LO, const float* __restrict__ X,
                 const float* __restrict__ Wa, const float* __restrict__ ba,
                 const float* __restrict__ bs1, const float* __restrict__ bs2,
                 const float* __restrict__ bh1, const float* __restrict__ bh2,
                 const float* __restrict__ Wh2, const float* __restrict__ HWT,
                 float* __restrict__ out)
{
  const int q = blockIdx.x, l = threadIdx.x;
  const float* lob = LO + (size_t)q * 2048;
  float loa[16], lobv[16];
  #pragma unroll
  for (int t = 0; t < 16; ++t) {
    loa[t]  = lob[t * 128 + l];
    lobv[t] = lob[t * 128 + 64 + l];
  }
  const float wa = Wa[l], wb = Wa[64 + l];
  float sc[16];
  #pragma unroll
  for (int t = 0; t < 16; ++t) sc[t] = rsum64(loa[t] * wa + lobv[t] * wb) + ba[0];
  float mx = sc[0];
  #pragma unroll
  for (int t = 1; t < 16; ++t) mx = fmaxf(mx, sc[t]);
  float den = 0.f;
  #pragma unroll
  for (int t = 0; t < 16; ++t) { sc[t] = __expf(sc[t] - mx); den += sc[t]; }
  const float inv = 1.f / den;
  float ca = 0.f, cb = 0.f;
  #pragma unroll
  for (int t = 0; t < 16; ++t) {
    float wgt = sc[t] * inv;
    ca = fmaf(wgt, loa[t], ca);
    cb = fmaf(wgt, lobv[t], cb);
  }
  __shared__ float zsh[160];
  __shared__ float hsk[64];
  __shared__ float skin[16];
  zsh[l] = ca; zsh[64 + l] = cb;
  const int bb = q / 1000, nn = q - bb * 1000;
  if (l < 13) skin[l] = X[(size_t)((bb * 16 + 15) * 1000 + nn) * 32 + l];
  __syncthreads();
  float h1 = bs1[l];
  for (int c = 0; c < 13; ++c) h1 = fmaf(skin[c], HWT[c * 64 + l], h1);
  h1 = geluf(h1);
  hsk[l] = h1;
  __syncthreads();
  if (l < 32) {
    float a = bs2[l];
    for (int jj = 0; jj < 64; ++jj) a = fmaf(hsk[jj], HWT[832 + jj * 32 + l], a);
    zsh[128 + l] = a;
  }
  __syncthreads();
  float hh = bh1[l];
  for (int r = 0; r < 160; ++r) hh = fmaf(zsh[r], HWT[2880 + r * 64 + l], hh);
  hh = geluf(hh);
  float s = rsum64(hh * Wh2[l]);
  if (l == 0) out[q] = s + bh2[0];
}

// ---------------- launch ----------------
extern "C" void kernel_launch(void* const* d_in, const int* in_sizes, int n_in,
                              void* d_out, int out_size, void* d_ws, size_t ws_size,
                              hipStream_t stream)
{
  const float* x    = (const float*)d_in[0];
  const int*   ei   = (const int*)d_in[1];
  const float* Wp   = (const float*)d_in[2];
  const float* bp   = (const float*)d_in[3];
  const float* Wl1  = (const float*)d_in[4];
  const float* Wr1  = (const float*)d_in[5];
  const float* a1   = (const float*)d_in[6];
  const float* bg1  = (const float*)d_in[7];
  const float* g1   = (const float*)d_in[8];
  const float* be1  = (const float*)d_in[9];
  const float* m1   = (const float*)d_in[10];
  const float* v1   = (const float*)d_in[11];
  const float* Wl2  = (const float*)d_in[12];
  const float* Wr2  = (const float*)d_in[13];
  const float* a2   = (const float*)d_in[14];
  const float* bg2  = (const float*)d_in[15];
  const float* g2   = (const float*)d_in[16];
  const float* be2  = (const float*)d_in[17];
  const float* m2   = (const float*)d_in[18];
  const float* v2   = (const float*)d_in[19];
  const float* Wih0 = (const float*)d_in[20];
  const float* Whh0 = (const float*)d_in[21];
  const float* bih0 = (const float*)d_in[22];
  const float* bhh0 = (const float*)d_in[23];
  const float* Wih1 = (const float*)d_in[24];
  const float* Whh1 = (const float*)d_in[25];
  const float* bih1 = (const float*)d_in[26];
  const float* bhh1 = (const float*)d_in[27];
  const float* Wa   = (const float*)d_in[28];
  const float* ba   = (const float*)d_in[29];
  const float* Ws1  = (const float*)d_in[30];
  const float* bs1  = (const float*)d_in[31];
  const float* Ws2  = (const float*)d_in[32];
  const float* bs2  = (const float*)d_in[33];
  const float* Wh1  = (const float*)d_in[34];
  const float* bh1  = (const float*)d_in[35];
  const float* Wh2  = (const float*)d_in[36];
  const float* bh2  = (const float*)d_in[37];

  float* ws = (float*)d_ws;
  int* srcD   = (int*)(ws + O_SRCD);
  int* dstD   = (int*)(ws + O_DSTD);
  int* counts = (int*)(ws + O_COUNTS);
  int* offs   = (int*)(ws + O_OFFS);
  int* curs   = (int*)(ws + O_CURS);
  int* esrc   = (int*)(ws + O_EIDX);
  float* PW1  = ws + O_PW1;
  float* PW2  = ws + O_PW2;
  unsigned short* PHHBu = (unsigned short*)(ws + O_LW);           // 262144 bf16
  unsigned short* PWBu  = (unsigned short*)(ws + O_LW + 131072u); // 262144 bf16
  float* BC   = ws + O_BCOMB;
  float* ABF  = ws + O_ABF;
  float* HWT  = ws + O_HWT;
  unsigned short* XL1u = (unsigned short*)(ws + O_BIG0);
  float* XR1  = ws + O_BIG1;
  float* H1   = ws + O_BIG2;
  float* XP   = ws + O_BIG3;
  float* Hres = ws + O_BIG4;
  unsigned short* XL2u = (unsigned short*)(ws + O_BIG0);
  float* XR2  = ws + O_BIG0 + 8192000u;
  unsigned short* PREh = (unsigned short*)(ws + O_BIG0);  // 64000*512 fp16 = BIG0 exactly
  float* H1SEQ = ws + O_BIG2;
  float* LOp  = ws + O_BIG3;
  float* outp = (float*)d_out;

  prep_edges<<<67, 256, 0, stream>>>(ei, srcD, dstD, counts);
  hist_kernel<<<67, 256, 0, stream>>>(dstD, counts);
  scan_kernel<<<1, 1024, 0, stream>>>(counts, offs, curs);
  fill_kernel<<<67, 256, 0, stream>>>(srcD, dstD, curs, esrc);
  pack_kernel<<<1024, 256, 0, stream>>>(Wl1, Wr1, Wp, Wl2, Wr2,
      Wih0, Whh0, bih0, bhh0, Wih1, Whh1, bih1, bhh1,
      g1, be1, m1, v1, bg1, g2, be2, m2, v2, bg2,
      Ws1, Ws2, Wh1, PW1, PW2, PHHBu, PWBu, BC, ABF, HWT);
  proj1_kernel<<<4000, 320, 0, stream>>>(x, PW1, bp, XL1u, XR1, XP);
  gat1_kernel<<<dim3(250, 64), 256, 0, stream>>>(XL1u, XR1, esrc, offs, a1, ABF, H1);
  proj2_kernel<<<4000, 256, 0, stream>>>(H1, PW2, XL2u, XR2);
  gat2_kernel<<<dim3(250, 64), 256, 0, stream>>>(XL2u, XR2, esrc, offs, a2, ABF, XP, Hres);
  gemm_pre_kernel<<<2000, 512, 0, stream>>>(Hres, PWBu, BC, PREh);
  rec2_kernel<<<250, 512, 0, stream>>>(PREh, PHHBu, H1SEQ);
  gemm_pre_kernel<<<2000, 512, 0, stream>>>(H1SEQ, PWBu + 131072u, BC + 512, PREh);
  rec2_kernel<<<250, 512, 0, stream>>>(PREh, PHHBu + 131072u, LOp);
  attn_kernel<<<4000, 64, 0, stream>>>(LOp, x, Wa, ba, bs1, bs2, bh1, bh2, Wh2, HWT, outp);
}

// Round 13
// 549.757 us; speedup vs baseline: 3.9579x; 1.3115x over previous
//
#include <hip/hip_runtime.h>
#include <hip/hip_fp16.h>

#define EPS_BN 1e-5f

typedef __attribute__((ext_vector_type(8))) short bf16x8;
typedef __attribute__((ext_vector_type(4))) float f32x4;

// ---------------- workspace layout (float-unit offsets) ----------------
#define O_SRCD   0u
#define O_DSTD   17024u
#define O_COUNTS 34048u
#define O_OFFS   35072u
#define O_CURS   36096u
#define O_EIDX   37120u                    // esrc (src node id, CSR-ordered)
#define O_PW1    54144u                    // [32][640]  (Wl1T|Wr1T|WpT)
#define O_PW2    74624u                    // PW2B: 131072 bf16 B-frags (Wl2|Wr2)
#define O_LW     140160u                   // PHHB (262144 bf16) + PWB (262144 bf16)
#define O_BCOMB  402304u                   // [2][128j][4]  (gp order)
#define O_ABF    403328u                   // A1(256)|B1(256)|A2(128)|B2(128)
#define O_HWT    404352u                   // Ws1T(832)|Ws2T(2048)|Wh1T(10240)
#define O_BIG0   417536u                   // XL1(bf16) | XL2(bf16),XR2 | PRE(fp16)
#define O_BIG1   (O_BIG0 + 16384000u)      // XR1
#define O_BIG2   (O_BIG1 + 16384000u)      // H1  | h1seq
#define O_BIG3   (O_BIG2 + 16384000u)      // XP  | LO
#define O_BIG4   (O_BIG3 + 8192000u)       // Hres

__device__ __forceinline__ float rsum32(float p) {
  p += __shfl_xor(p, 1);  p += __shfl_xor(p, 2);  p += __shfl_xor(p, 4);
  p += __shfl_xor(p, 8);  p += __shfl_xor(p, 16); return p;
}
__device__ __forceinline__ float rsum64(float p) {
  p = rsum32(p); p += __shfl_xor(p, 32); return p;
}
__device__ __forceinline__ float lrelu(float x) { return x > 0.f ? x : 0.2f * x; }
__device__ __forceinline__ float eluf(float x)  { return x > 0.f ? x : expm1f(x); }
__device__ __forceinline__ float geluf(float x) { return 0.5f * x * (1.f + erff(x * 0.70710678118654752f)); }
__device__ __forceinline__ unsigned short f2bf(float f) {
  unsigned int u = __float_as_uint(f);
  u += 0x7FFFu + ((u >> 16) & 1u);
  return (unsigned short)(u >> 16);
}
__device__ __forceinline__ float bf2f(unsigned short h) {
  return __uint_as_float(((unsigned int)h) << 16);
}
__device__ __forceinline__ unsigned short f2h(float x) {
  __half h = __float2half(x);
  return *reinterpret_cast<unsigned short*>(&h);
}
__device__ __forceinline__ float h2f(unsigned short u) {
  __half h = *reinterpret_cast<__half*>(&u);
  return __half2float(h);
}
__device__ __forceinline__ void unpk(unsigned int w, float& lo, float& hi) {
  lo = __uint_as_float(w << 16);
  hi = __uint_as_float(w & 0xFFFF0000u);
}

// ---------------- prep kernels ----------------
__global__ void prep_edges(const int* __restrict__ ei, int* __restrict__ srcD,
                           int* __restrict__ dstD, int* __restrict__ counts) {
  int i = blockIdx.x * 256 + threadIdx.x;
  if (i < 1024) counts[i] = 0;
  if (i < 17000) {
    int s = (i < 16000) ? ei[i] : (i - 16000);
    int d = (i < 16000) ? ei[16000 + i] : (i - 16000);
    srcD[i] = s; dstD[i] = d;
  }
}
__global__ void hist_kernel(const int* __restrict__ dstD, int* __restrict__ counts) {
  int i = blockIdx.x * 256 + threadIdx.x;
  if (i < 17000) atomicAdd(&counts[dstD[i]], 1);
}
__global__ void scan_kernel(const int* __restrict__ counts, int* __restrict__ offs,
                            int* __restrict__ curs) {
  __shared__ int sh[1024];
  int i = threadIdx.x;
  int v = (i < 1000) ? counts[i] : 0;
  sh[i] = v;
  __syncthreads();
  for (int d = 1; d < 1024; d <<= 1) {
    int t = (i >= d) ? sh[i - d] : 0;
    __syncthreads();
    sh[i] += t;
    __syncthreads();
  }
  if (i < 1000) { offs[i + 1] = sh[i]; curs[i] = sh[i] - v; }
  if (i == 0) offs[0] = 0;
}
__global__ void fill_kernel(const int* __restrict__ srcD, const int* __restrict__ dstD,
                            int* __restrict__ curs, int* __restrict__ esrc) {
  int i = blockIdx.x * 256 + threadIdx.x;
  if (i < 17000) { int p = atomicAdd(&curs[dstD[i]], 1); esrc[p] = srcD[i]; }
}

// PHHB/PWB: hh/ih weights split-bf16 MFMA B-frags [L][split][kc4][gt32][lane64][e8]
// PW2B: GAT2 proj weights split-bf16 B-frags [sp][kc8][ct16][lane64][e8]
__global__ void pack_kernel(
    const float* __restrict__ Wl1, const float* __restrict__ Wr1, const float* __restrict__ Wp,
    const float* __restrict__ Wl2, const float* __restrict__ Wr2,
    const float* __restrict__ Wih0, const float* __restrict__ Whh0,
    const float* __restrict__ bih0, const float* __restrict__ bhh0,
    const float* __restrict__ Wih1, const float* __restrict__ Whh1,
    const float* __restrict__ bih1, const float* __restrict__ bhh1,
    const float* __restrict__ g1, const float* __restrict__ be1, const float* __restrict__ m1,
    const float* __restrict__ v1, const float* __restrict__ bg1,
    const float* __restrict__ g2, const float* __restrict__ be2, const float* __restrict__ m2,
    const float* __restrict__ v2, const float* __restrict__ bg2,
    const float* __restrict__ Ws1, const float* __restrict__ Ws2, const float* __restrict__ Wh1,
    float* __restrict__ PW1, unsigned short* __restrict__ PW2Bu,
    unsigned short* __restrict__ PHHBu, unsigned short* __restrict__ PWBu,
    float* __restrict__ BC, float* __restrict__ ABF, float* __restrict__ HWT)
{
  int i = blockIdx.x * 256 + threadIdx.x;
  if (i < 262144) {  // PHHB + PWB split-bf16
    int e = i & 7, lane = (i >> 3) & 63, gt = (i >> 9) & 31,
        kc = (i >> 14) & 3, sp = (i >> 16) & 1, L = (i >> 17) & 1;
    int gp = (gt << 4) + (lane & 15);
    int jj = gp >> 2, gate = gp & 3;
    int kk = (kc << 5) + ((lane >> 4) << 3) + e;
    const float* Wih = L ? Wih1 : Wih0;
    const float* Whh = L ? Whh1 : Whh0;
    float wv = Wih[(gate * 128 + jj) * 128 + kk];
    unsigned short hi = f2bf(wv);
    PWBu[i] = (sp == 0) ? hi : f2bf(wv - bf2f(hi));
    float hv = Whh[(gate * 128 + jj) * 128 + kk];
    unsigned short hhi = f2bf(hv);
    PHHBu[i] = (sp == 0) ? hhi : f2bf(hv - bf2f(hhi));
  }
  if (i < 131072) {  // PW2B split-bf16 B-frags
    int e = i & 7, lane = (i >> 3) & 63, ct = (i >> 9) & 15,
        kc = (i >> 13) & 7, sp = (i >> 16) & 1;
    int c = (ct << 4) + (lane & 15);
    int k = (kc << 5) + ((lane >> 4) << 3) + e;
    float wv2 = (c < 128) ? Wl2[c * 256 + k] : Wr2[(c - 128) * 256 + k];
    unsigned short hi = f2bf(wv2);
    PW2Bu[i] = (sp == 0) ? hi : f2bf(wv2 - bf2f(hi));
  }
  if (i < 20480) { int g = i % 640, k = i / 640;
    PW1[i] = (g < 256) ? Wl1[g * 32 + k] : (g < 512) ? Wr1[(g - 256) * 32 + k]
                                                     : Wp[(g - 512) * 32 + k]; }
  if (i < 1024) { int u = i & 3, jj = (i >> 2) & 127, L = i >> 9;
    BC[i] = (L ? bih1 : bih0)[u * 128 + jj] + (L ? bhh1 : bhh0)[u * 128 + jj]; }
  if (i < 768) {
    if (i < 256) ABF[i] = g1[i] * rsqrtf(v1[i] + EPS_BN);
    else if (i < 512) { int c = i - 256; float a = g1[c] * rsqrtf(v1[c] + EPS_BN);
      ABF[i] = (bg1[c] - m1[c]) * a + be1[c]; }
    else if (i < 640) { int c = i - 512; ABF[i] = g2[c] * rsqrtf(v2[c] + EPS_BN); }
    else { int c = i - 640; float a = g2[c] * rsqrtf(v2[c] + EPS_BN);
      ABF[i] = (bg2[c] - m2[c]) * a + be2[c]; }
  }
  if (i < 13120) {
    if (i < 832) { int l = i & 63, c = i >> 6; HWT[i] = Ws1[l * 13 + c]; }
    else if (i < 2880) { int k = i - 832; int l = k & 31, jj = k >> 5; HWT[i] = Ws2[l * 64 + jj]; }
    else { int k = i - 2880; int l = k & 63, r = k >> 6; HWT[i] = Wh1[l * 160 + r]; }
  }
}

// ---------------- projection 1: x -> xl1(bf16,256) | xr1(256) | xp(128) ------------
__global__ __launch_bounds__(320)
void proj1_kernel(const float* __restrict__ X, const float* __restrict__ PW1,
                  const float* __restrict__ bp, unsigned short* __restrict__ XL1u,
                  float* __restrict__ XR1, float* __restrict__ XP)
{
  __shared__ __align__(16) float xs[32][16];
  const int tid = threadIdx.x;
  const int r0 = blockIdx.x * 16;
  for (int el = tid; el < 512; el += 320) {
    int r = el >> 5, k = el & 31;
    xs[k][r] = X[(size_t)(r0 + r) * 32 + k];
  }
  __syncthreads();
  const int gA = tid, gB = tid + 320;
  float accA[16], accB[16];
  const float iB = (gB >= 512) ? bp[gB - 512] : 0.f;
  #pragma unroll
  for (int r = 0; r < 16; ++r) { accA[r] = 0.f; accB[r] = iB; }
  for (int k = 0; k < 32; ++k) {
    float wA = PW1[k * 640 + gA], wB = PW1[k * 640 + gB];
    float xv[16];
    #pragma unroll
    for (int q = 0; q < 4; ++q)
      *reinterpret_cast<float4*>(&xv[q * 4]) = *reinterpret_cast<const float4*>(&xs[k][q * 4]);
    #pragma unroll
    for (int r = 0; r < 16; ++r) {
      accA[r] = fmaf(wA, xv[r], accA[r]);
      accB[r] = fmaf(wB, xv[r], accB[r]);
    }
  }
  for (int r = 0; r < 16; ++r) {
    size_t row = r0 + r;
    if (gA < 256) XL1u[row * 256 + gA] = f2bf(accA[r]);
    else          XR1[row * 256 + (gA - 256)] = accA[r];
    if (gB < 512) XR1[row * 256 + (gB - 256)] = accB[r];
    else          XP[row * 128 + (gB - 512)] = accB[r];
  }
}

// ---------------- GAT layer 1: 2 edges/wave-iter, 16-lane (edge-parity x head) groups ----
__global__ __launch_bounds__(256)
void gat1_kernel(const unsigned short* __restrict__ XLu, const float* __restrict__ XR,
                 const int* __restrict__ esrc, const int* __restrict__ offs,
                 const float* __restrict__ a1, const float* __restrict__ ABF,
                 float* __restrict__ H1)
{
  const int lane = threadIdx.x & 63;
  const int wv = threadIdx.x >> 6;
  const int n = blockIdx.x * 4 + wv;
  const int b = blockIdx.y;
  const int epar = lane >> 5;              // edge parity
  const int head = (lane >> 4) & 1;
  const int li = lane & 15;
  const int f0 = head * 128 + li * 8;
  const int beg = offs[n];
  const int deg = offs[n + 1] - beg;
  const uint4* XLb = reinterpret_cast<const uint4*>(XLu) + (size_t)b * 32000 + (f0 >> 3);
  float xr[8], av[8];
  {
    const float* xrp = XR + (size_t)(b * 1000 + n) * 256 + f0;
    float4 t0 = *reinterpret_cast<const float4*>(xrp);
    float4 t1 = *reinterpret_cast<const float4*>(xrp + 4);
    xr[0]=t0.x; xr[1]=t0.y; xr[2]=t0.z; xr[3]=t0.w;
    xr[4]=t1.x; xr[5]=t1.y; xr[6]=t1.z; xr[7]=t1.w;
    const float* ap = a1 + f0;
    float4 a0 = *reinterpret_cast<const float4*>(ap);
    float4 a1v = *reinterpret_cast<const float4*>(ap + 4);
    av[0]=a0.x; av[1]=a0.y; av[2]=a0.z; av[3]=a0.w;
    av[4]=a1v.x; av[5]=a1v.y; av[6]=a1v.z; av[7]=a1v.w;
  }
  float m = -1e30f, ssum = 0.f, acc[8];
  #pragma unroll
  for (int k = 0; k < 8; ++k) acc[k] = 0.f;
  bool v = epar < deg;
  int s0 = esrc[beg + (v ? epar : 0)];
  uint4 u = XLb[(size_t)s0 * 32];
  for (int i0 = 0; i0 < deg; i0 += 2) {
    int nmy = i0 + 2 + epar;
    bool nv = nmy < deg;
    int sN = esrc[beg + (nv ? nmy : 0)];
    uint4 un = XLb[(size_t)sN * 32];
    float x[8];
    unpk(u.x, x[0], x[1]); unpk(u.y, x[2], x[3]);
    unpk(u.z, x[4], x[5]); unpk(u.w, x[6], x[7]);
    float p = 0.f;
    #pragma unroll
    for (int k = 0; k < 8; ++k) {
      float t = x[k] + xr[k];
      float lr = fmaxf(t, 0.2f * t);
      p = fmaf(lr, av[k], p);
    }
    p += __shfl_xor(p, 1); p += __shfl_xor(p, 2);
    p += __shfl_xor(p, 4); p += __shfl_xor(p, 8);
    p = v ? p : -1e30f;
    float mn = fmaxf(m, p);
    float scl = __expf(m - mn);
    float we = v ? __expf(p - mn) : 0.f;
    ssum = fmaf(ssum, scl, we);
    #pragma unroll
    for (int k = 0; k < 8; ++k) acc[k] = fmaf(acc[k], scl, we * x[k]);
    m = mn;
    v = nv; u = un;
  }
  // merge edge-parity halves (same head): lane ^ 32
  float mo = __shfl_xor(m, 32), so = __shfl_xor(ssum, 32);
  float M = fmaxf(m, mo);
  float es = __expf(m - M), eo = __expf(mo - M);
  float S = fmaf(ssum, es, so * eo);
  float inv = 1.f / S;
  float A4[8], B4[8];
  {
    const float* aap = ABF + f0;
    float4 t0 = *reinterpret_cast<const float4*>(aap);
    float4 t1 = *reinterpret_cast<const float4*>(aap + 4);
    A4[0]=t0.x; A4[1]=t0.y; A4[2]=t0.z; A4[3]=t0.w;
    A4[4]=t1.x; A4[5]=t1.y; A4[6]=t1.z; A4[7]=t1.w;
    const float* bbp = ABF + 256 + f0;
    float4 s0v = *reinterpret_cast<const float4*>(bbp);
    float4 s1v = *reinterpret_cast<const float4*>(bbp + 4);
    B4[0]=s0v.x; B4[1]=s0v.y; B4[2]=s0v.z; B4[3]=s0v.w;
    B4[4]=s1v.x; B4[5]=s1v.y; B4[6]=s1v.z; B4[7]=s1v.w;
  }
  float o[8];
  #pragma unroll
  for (int k = 0; k < 8; ++k) {
    float ao = __shfl_xor(acc[k], 32);
    float A = fmaf(acc[k], es, ao * eo);
    o[k] = eluf(fmaf(A * inv, A4[k], B4[k]));
  }
  if (lane < 32) {
    float* hp = H1 + (size_t)(b * 1000 + n) * 256 + f0;
    *reinterpret_cast<float4*>(hp) = make_float4(o[0], o[1], o[2], o[3]);
    *reinterpret_cast<float4*>(hp + 4) = make_float4(o[4], o[5], o[6], o[7]);
  }
}

// ---------------- projection 2 (MFMA): h1(256) -> xl2(bf16,128)|xr2(128) ----------------
__global__ __launch_bounds__(512)
void proj2_kernel(const float* __restrict__ H1, const unsigned short* __restrict__ PW2B,
                  unsigned short* __restrict__ XL2u, float* __restrict__ XR2)
{
  const int tid = threadIdx.x;
  const int lane = tid & 63;
  const int wv = tid >> 6;
  const int l15 = lane & 15;
  const int kg = lane >> 4;
  const int r0 = blockIdx.x * 32;
  f32x4 acc[2][2];
  #pragma unroll
  for (int rt = 0; rt < 2; ++rt)
    #pragma unroll
    for (int ct = 0; ct < 2; ++ct)
      #pragma unroll
      for (int e = 0; e < 4; ++e) acc[rt][ct][e] = 0.f;
  for (int kc = 0; kc < 8; ++kc) {
    bf16x8 xh[2], xl[2];
    #pragma unroll
    for (int rt = 0; rt < 2; ++rt) {
      const float* xp = H1 + (size_t)(r0 + rt * 16 + l15) * 256 + (kc << 5) + (kg << 3);
      float4 va = *reinterpret_cast<const float4*>(xp);
      float4 vb = *reinterpret_cast<const float4*>(xp + 4);
      float xs[8] = {va.x, va.y, va.z, va.w, vb.x, vb.y, vb.z, vb.w};
      #pragma unroll
      for (int e = 0; e < 8; ++e) {
        unsigned short h = f2bf(xs[e]);
        xh[rt][e] = (short)h;
        xl[rt][e] = (short)f2bf(xs[e] - bf2f(h));
      }
    }
    #pragma unroll
    for (int ct = 0; ct < 2; ++ct) {
      const int ctg = (wv << 1) + ct;
      const unsigned short* wp = PW2B + ((size_t)(kc * 16 + ctg)) * 512 + lane * 8;
      bf16x8 whi = *reinterpret_cast<const bf16x8*>(wp);
      bf16x8 wlo = *reinterpret_cast<const bf16x8*>(wp + 65536);
      #pragma unroll
      for (int rt = 0; rt < 2; ++rt) {
        acc[rt][ct] = __builtin_amdgcn_mfma_f32_16x16x32_bf16(xh[rt], whi, acc[rt][ct], 0, 0, 0);
        acc[rt][ct] = __builtin_amdgcn_mfma_f32_16x16x32_bf16(xh[rt], wlo, acc[rt][ct], 0, 0, 0);
        acc[rt][ct] = __builtin_amdgcn_mfma_f32_16x16x32_bf16(xl[rt], whi, acc[rt][ct], 0, 0, 0);
      }
    }
  }
  #pragma unroll
  for (int ct = 0; ct < 2; ++ct) {
    const int col = (wv << 5) + (ct << 4) + l15;
    #pragma unroll
    for (int rt = 0; rt < 2; ++rt) {
      #pragma unroll
      for (int reg = 0; reg < 4; ++reg) {
        const int row = r0 + rt * 16 + (kg << 2) + reg;
        float val = acc[rt][ct][reg];
        if (col < 128) XL2u[(size_t)row * 128 + col] = f2bf(val);
        else           XR2[(size_t)row * 128 + (col - 128)] = val;
      }
    }
  }
}

// ---------------- GAT layer 2: 4 edges/wave-iter, 16-lane edge groups + residual ------
__global__ __launch_bounds__(256)
void gat2_kernel(const unsigned short* __restrict__ XLu, const float* __restrict__ XR,
                 const int* __restrict__ esrc, const int* __restrict__ offs,
                 const float* __restrict__ a2, const float* __restrict__ ABF,
                 const float* __restrict__ XP, float* __restrict__ Hout)
{
  const int lane = threadIdx.x & 63;
  const int wv = threadIdx.x >> 6;
  const int n = blockIdx.x * 4 + wv;
  const int b = blockIdx.y;
  const int grp = lane >> 4;               // edge slot 0..3
  const int li = lane & 15;
  const int f0 = li * 8;
  const int beg = offs[n];
  const int deg = offs[n + 1] - beg;
  const uint4* XLb = reinterpret_cast<const uint4*>(XLu) + (size_t)b * 16000 + li;
  float xr[8], av[8];
  {
    const float* xrp = XR + (size_t)(b * 1000 + n) * 128 + f0;
    float4 t0 = *reinterpret_cast<const float4*>(xrp);
    float4 t1 = *reinterpret_cast<const float4*>(xrp + 4);
    xr[0]=t0.x; xr[1]=t0.y; xr[2]=t0.z; xr[3]=t0.w;
    xr[4]=t1.x; xr[5]=t1.y; xr[6]=t1.z; xr[7]=t1.w;
    const float* ap = a2 + f0;
    float4 a0 = *reinterpret_cast<const float4*>(ap);
    float4 a1v = *reinterpret_cast<const float4*>(ap + 4);
    av[0]=a0.x; av[1]=a0.y; av[2]=a0.z; av[3]=a0.w;
    av[4]=a1v.x; av[5]=a1v.y; av[6]=a1v.z; av[7]=a1v.w;
  }
  float m = -1e30f, ssum = 0.f, acc[8];
  #pragma unroll
  for (int k = 0; k < 8; ++k) acc[k] = 0.f;
  bool v = grp < deg;
  int s0 = esrc[beg + (v ? grp : 0)];
  uint4 u = XLb[(size_t)s0 * 16];
  for (int i0 = 0; i0 < deg; i0 += 4) {
    int nmy = i0 + 4 + grp;
    bool nv = nmy < deg;
    int sN = esrc[beg + (nv ? nmy : 0)];
    uint4 un = XLb[(size_t)sN * 16];
    float x[8];
    unpk(u.x, x[0], x[1]); unpk(u.y, x[2], x[3]);
    unpk(u.z, x[4], x[5]); unpk(u.w, x[6], x[7]);
    float p = 0.f;
    #pragma unroll
    for (int k = 0; k < 8; ++k) {
      float t = x[k] + xr[k];
      float lr = fmaxf(t, 0.2f * t);
      p = fmaf(lr, av[k], p);
    }
    p += __shfl_xor(p, 1); p += __shfl_xor(p, 2);
    p += __shfl_xor(p, 4); p += __shfl_xor(p, 8);
    p = v ? p : -1e30f;
    float mn = fmaxf(m, p);
    float scl = __expf(m - mn);
    float we = v ? __expf(p - mn) : 0.f;
    ssum = fmaf(ssum, scl, we);
    #pragma unroll
    for (int k = 0; k < 8; ++k) acc[k] = fmaf(acc[k], scl, we * x[k]);
    m = mn;
    v = nv; u = un;
  }
  // merge 4 edge groups: xor16 then xor32
  #pragma unroll
  for (int msk = 16; msk <= 32; msk <<= 1) {
    float mo = __shfl_xor(m, msk), so = __shfl_xor(ssum, msk);
    float M = fmaxf(m, mo);
    float es = __expf(m - M), eo = __expf(mo - M);
    ssum = fmaf(ssum, es, so * eo);
    #pragma unroll
    for (int k = 0; k < 8; ++k) {
      float ao = __shfl_xor(acc[k], msk);
      acc[k] = fmaf(acc[k], es, ao * eo);
    }
    m = M;
  }
  float inv = 1.f / ssum;
  if (lane < 16) {
    const float* aap = ABF + 512 + f0;
    float4 t0 = *reinterpret_cast<const float4*>(aap);
    float4 t1 = *reinterpret_cast<const float4*>(aap + 4);
    const float* bbp = ABF + 640 + f0;
    float4 s0v = *reinterpret_cast<const float4*>(bbp);
    float4 s1v = *reinterpret_cast<const float4*>(bbp + 4);
    const float* xpp = XP + (size_t)(b * 1000 + n) * 128 + f0;
    float4 p0 = *reinterpret_cast<const float4*>(xpp);
    float4 p1 = *reinterpret_cast<const float4*>(xpp + 4);
    float A4[8] = {t0.x, t0.y, t0.z, t0.w, t1.x, t1.y, t1.z, t1.w};
    float B4[8] = {s0v.x, s0v.y, s0v.z, s0v.w, s1v.x, s1v.y, s1v.z, s1v.w};
    float P4[8] = {p0.x, p0.y, p0.z, p0.w, p1.x, p1.y, p1.z, p1.w};
    float o[8];
    #pragma unroll
    for (int k = 0; k < 8; ++k)
      o[k] = eluf(fmaf(acc[k] * inv, A4[k], B4[k])) + P4[k];
    float* hp = Hout + (size_t)(b * 1000 + n) * 128 + f0;
    *reinterpret_cast<float4*>(hp) = make_float4(o[0], o[1], o[2], o[3]);
    *reinterpret_cast<float4*>(hp + 4) = make_float4(o[4], o[5], o[6], o[7]);
  }
}

// ---------------- MFMA pre-GEMM: PRE[r][gp] = fp16( X[r][:] @ WihT[:,gp] + BC[gp] ) ----
__global__ __launch_bounds__(512)
void gemm_pre_kernel(const float* __restrict__ X, const unsigned short* __restrict__ PWB,
                     const float* __restrict__ BCL, unsigned short* __restrict__ PREh)
{
  const int tid = threadIdx.x;
  const int lane = tid & 63;
  const int wv = tid >> 6;
  const int l15 = lane & 15;
  const int kg = lane >> 4;
  const int r0 = blockIdx.x * 32;
  f32x4 acc[2][4];
  #pragma unroll
  for (int rt = 0; rt < 2; ++rt)
    #pragma unroll
    for (int gt = 0; gt < 4; ++gt)
      #pragma unroll
      for (int e = 0; e < 4; ++e) acc[rt][gt][e] = 0.f;
  for (int kc = 0; kc < 4; ++kc) {
    bf16x8 xh[2], xl[2];
    #pragma unroll
    for (int rt = 0; rt < 2; ++rt) {
      const float* xp = X + (size_t)(r0 + rt * 16 + l15) * 128 + (kc << 5) + (kg << 3);
      float4 va = *reinterpret_cast<const float4*>(xp);
      float4 vb = *reinterpret_cast<const float4*>(xp + 4);
      float xs[8] = {va.x, va.y, va.z, va.w, vb.x, vb.y, vb.z, vb.w};
      #pragma unroll
      for (int e = 0; e < 8; ++e) {
        unsigned short h = f2bf(xs[e]);
        xh[rt][e] = (short)h;
        xl[rt][e] = (short)f2bf(xs[e] - bf2f(h));
      }
    }
    #pragma unroll
    for (int gt = 0; gt < 4; ++gt) {
      const int gtg = (wv << 2) + gt;
      const unsigned short* wp = PWB + ((size_t)(kc * 32 + gtg)) * 512 + lane * 8;
      bf16x8 whi = *reinterpret_cast<const bf16x8*>(wp);
      bf16x8 wlo = *reinterpret_cast<const bf16x8*>(wp + 65536);
      #pragma unroll
      for (int rt = 0; rt < 2; ++rt) {
        acc[rt][gt] = __builtin_amdgcn_mfma_f32_16x16x32_bf16(xh[rt], whi, acc[rt][gt], 0, 0, 0);
        acc[rt][gt] = __builtin_amdgcn_mfma_f32_16x16x32_bf16(xh[rt], wlo, acc[rt][gt], 0, 0, 0);
        acc[rt][gt] = __builtin_amdgcn_mfma_f32_16x16x32_bf16(xl[rt], whi, acc[rt][gt], 0, 0, 0);
      }
    }
  }
  #pragma unroll
  for (int gt = 0; gt < 4; ++gt) {
    const int col = (wv << 6) + (gt << 4) + l15;
    const float bias = BCL[col];
    #pragma unroll
    for (int rt = 0; rt < 2; ++rt) {
      #pragma unroll
      for (int reg = 0; reg < 4; ++reg) {
        const int row = r0 + rt * 16 + (kg << 2) + reg;
        PREh[(size_t)row * 512 + col] = f2h(acc[rt][gt][reg] + bias);
      }
    }
  }
}

// ---------------- MFMA recurrent hh LSTM layer ----------------
__device__ __forceinline__ float cellf(float4 g, float& c) {
  const float ig = 1.f / (1.f + __expf(-g.x));
  const float fg = 1.f / (1.f + __expf(-g.y));
  const float gg = tanhf(g.z);
  const float og = 1.f / (1.f + __expf(-g.w));
  c = fmaf(fg, c, ig * gg);
  return og * tanhf(c);
}

__global__ __launch_bounds__(512)
void rec2_kernel(const unsigned short* __restrict__ PREh,
                 const unsigned short* __restrict__ PHHB,
                 float* __restrict__ HOUT)
{
  __shared__ unsigned short whi[65536];        // [kc4][gt32][lane64][e8] = 128 KB
  __shared__ unsigned short afr[2][4][64][8];  // [split][kc][lane][e]   = 8 KB
  const int tid = threadIdx.x;
  const int lane = tid & 63;
  const int w = tid >> 6;                      // 0..7: gates [w*64, w*64+64)
  const int l15 = lane & 15;
  const int kg = lane >> 4;
  const int q0 = blockIdx.x << 4;
  for (int i = tid; i < 8192; i += 512)
    reinterpret_cast<uint4*>(whi)[i] = reinterpret_cast<const uint4*>(PHHB)[i];
  reinterpret_cast<uint4*>(&afr[0][0][0][0])[tid] = make_uint4(0u, 0u, 0u, 0u);
  const unsigned short* wloG = PHHB + 65536;
  float cs[4] = {0.f, 0.f, 0.f, 0.f};
  const int qq = l15 & 3;
  const int uu = l15 >> 2;
  const int seq = (kg << 2) + qq;
  for (int t = 0; t < 16; ++t) {
    __syncthreads();
    bf16x8 ah[4], al[4];
    #pragma unroll
    for (int kc = 0; kc < 4; ++kc) {
      ah[kc] = *reinterpret_cast<const bf16x8*>(&afr[0][kc][lane][0]);
      al[kc] = *reinterpret_cast<const bf16x8*>(&afr[1][kc][lane][0]);
    }
    f32x4 acc[4];
    #pragma unroll
    for (int gl = 0; gl < 4; ++gl)
      #pragma unroll
      for (int e = 0; e < 4; ++e) acc[gl][e] = 0.f;
    #pragma unroll
    for (int gl = 0; gl < 4; ++gl) {
      const int gt = (w << 2) + gl;
      #pragma unroll
      for (int kc = 0; kc < 4; ++kc) {
        const int off = ((kc * 32 + gt) * 64 + lane) * 8;
        bf16x8 wh = *reinterpret_cast<const bf16x8*>(&whi[off]);
        bf16x8 wl = *reinterpret_cast<const bf16x8*>(&wloG[off]);
        acc[gl] = __builtin_amdgcn_mfma_f32_16x16x32_bf16(ah[kc], wh, acc[gl], 0, 0, 0);
        acc[gl] = __builtin_amdgcn_mfma_f32_16x16x32_bf16(ah[kc], wl, acc[gl], 0, 0, 0);
        acc[gl] = __builtin_amdgcn_mfma_f32_16x16x32_bf16(al[kc], wh, acc[gl], 0, 0, 0);
      }
    }
    __syncthreads();
    const int row = ((q0 + seq) << 4) + t;
    #pragma unroll
    for (int gl = 0; gl < 4; ++gl) {
      const int gt = (w << 2) + gl;
      float in0 = acc[gl][0], in1 = acc[gl][1], in2 = acc[gl][2], in3 = acc[gl][3];
      float s0 = __shfl_xor(in1, 1), s1 = __shfl_xor(in0, 1),
            s2 = __shfl_xor(in3, 1), s3 = __shfl_xor(in2, 1);
      const bool b0 = (qq & 1);
      float t0 = b0 ? s0 : in0;
      float t1 = b0 ? in1 : s1;
      float t2 = b0 ? s2 : in2;
      float t3 = b0 ? in3 : s3;
      float u0 = __shfl_xor(t2, 2), u1 = __shfl_xor(t3, 2),
            u2 = __shfl_xor(t0, 2), u3 = __shfl_xor(t1, 2);
      const bool b1 = (qq & 2);
      float g0 = b1 ? u0 : t0;
      float g1 = b1 ? u1 : t1;
      float g2 = b1 ? t2 : u2;
      float g3 = b1 ? t3 : u3;
      const unsigned short* pp = PREh + (size_t)row * 512 + (gt << 4) + (uu << 2);
      ushort4 pu = *reinterpret_cast<const ushort4*>(pp);
      float4 gv = make_float4(g0 + h2f(pu.x), g1 + h2f(pu.y),
                              g2 + h2f(pu.z), g3 + h2f(pu.w));
      float h = cellf(gv, cs[gl]);
      const int unit = (gt << 2) + uu;
      HOUT[(size_t)row * 128 + unit] = h;
      if (t < 15) {
        unsigned short hh = f2bf(h);
        unsigned short hl = f2bf(h - bf2f(hh));
        const int kc2 = unit >> 5;
        const int lane2 = seq | (((unit & 31) >> 3) << 4);
        const int e2 = unit & 7;
        afr[0][kc2][lane2][e2] = hh;
        afr[1][kc2][lane2][e2] = hl;
      }
    }
  }
}

// ---------------- attention pool + skip MLP + head ----------------
__global__ __launch_bounds__(64)
void attn_kernel(const float* __restrict__ LO, const float* __restrict__ X,
                 const float* __restrict__ Wa, const float* __restrict__ ba,
                 const float* __restrict__ bs1, const float* __restrict__ bs2,
                 const float* __restrict__ bh1, const float* __restrict__ bh2,
                 const float* __restrict__ Wh2, const float* __restrict__ HWT,
                 float* __restrict__ out)
{
  const int q = blockIdx.x, l = threadIdx.x;
  const float* lob = LO + (size_t)q * 2048;
  float loa[16], lobv[16];
  #pragma unroll
  for (int t = 0; t < 16; ++t) {
    loa[t]  = lob[t * 128 + l];
    lobv[t] = lob[t * 128 + 64 + l];
  }
  const float wa = Wa[l], wb = Wa[64 + l];
  float sc[16];
  #pragma unroll
  for (int t = 0; t < 16; ++t) sc[t] = rsum64(loa[t] * wa + lobv[t] * wb) + ba[0];
  float mx = sc[0];
  #pragma unroll
  for (int t = 1; t < 16; ++t) mx = fmaxf(mx, sc[t]);
  float den = 0.f;
  #pragma unroll
  for (int t = 0; t < 16; ++t) { sc[t] = __expf(sc[t] - mx); den += sc[t]; }
  const float inv = 1.f / den;
  float ca = 0.f, cb = 0.f;
  #pragma unroll
  for (int t = 0; t < 16; ++t) {
    float wgt = sc[t] * inv;
    ca = fmaf(wgt, loa[t], ca);
    cb = fmaf(wgt, lobv[t], cb);
  }
  __shared__ float zsh[160];
  __shared__ float hsk[64];
  __shared__ float skin[16];
  zsh[l] = ca; zsh[64 + l] = cb;
  const int bb = q / 1000, nn = q - bb * 1000;
  if (l < 13) skin[l] = X[(size_t)((bb * 16 + 15) * 1000 + nn) * 32 + l];
  __syncthreads();
  float h1 = bs1[l];
  for (int c = 0; c < 13; ++c) h1 = fmaf(skin[c], HWT[c * 64 + l], h1);
  h1 = geluf(h1);
  hsk[l] = h1;
  __syncthreads();
  if (l < 32) {
    float a = bs2[l];
    for (int jj = 0; jj < 64; ++jj) a = fmaf(hsk[jj], HWT[832 + jj * 32 + l], a);
    zsh[128 + l] = a;
  }
  __syncthreads();
  float hh = bh1[l];
  for (int r = 0; r < 160; ++r) hh = fmaf(zsh[r], HWT[2880 + r * 64 + l], hh);
  hh = geluf(hh);
  float s = rsum64(hh * Wh2[l]);
  if (l == 0) out[q] = s + bh2[0];
}

// ---------------- launch ----------------
extern "C" void kernel_launch(void* const* d_in, const int* in_sizes, int n_in,
                              void* d_out, int out_size, void* d_ws, size_t ws_size,
                              hipStream_t stream)
{
  const float* x    = (const float*)d_in[0];
  const int*   ei   = (const int*)d_in[1];
  const float* Wp   = (const float*)d_in[2];
  const float* bp   = (const float*)d_in[3];
  const float* Wl1  = (const float*)d_in[4];
  const float* Wr1  = (const float*)d_in[5];
  const float* a1   = (const float*)d_in[6];
  const float* bg1  = (const float*)d_in[7];
  const float* g1   = (const float*)d_in[8];
  const float* be1  = (const float*)d_in[9];
  const float* m1   = (const float*)d_in[10];
  const float* v1   = (const float*)d_in[11];
  const float* Wl2  = (const float*)d_in[12];
  const float* Wr2  = (const float*)d_in[13];
  const float* a2   = (const float*)d_in[14];
  const float* bg2  = (const float*)d_in[15];
  const float* g2   = (const float*)d_in[16];
  const float* be2  = (const float*)d_in[17];
  const float* m2   = (const float*)d_in[18];
  const float* v2   = (const float*)d_in[19];
  const float* Wih0 = (const float*)d_in[20];
  const float* Whh0 = (const float*)d_in[21];
  const float* bih0 = (const float*)d_in[22];
  const float* bhh0 = (const float*)d_in[23];
  const float* Wih1 = (const float*)d_in[24];
  const float* Whh1 = (const float*)d_in[25];
  const float* bih1 = (const float*)d_in[26];
  const float* bhh1 = (const float*)d_in[27];
  const float* Wa   = (const float*)d_in[28];
  const float* ba   = (const float*)d_in[29];
  const float* Ws1  = (const float*)d_in[30];
  const float* bs1  = (const float*)d_in[31];
  const float* Ws2  = (const float*)d_in[32];
  const float* bs2  = (const float*)d_in[33];
  const float* Wh1  = (const float*)d_in[34];
  const float* bh1  = (const float*)d_in[35];
  const float* Wh2  = (const float*)d_in[36];
  const float* bh2  = (const float*)d_in[37];

  float* ws = (float*)d_ws;
  int* srcD   = (int*)(ws + O_SRCD);
  int* dstD   = (int*)(ws + O_DSTD);
  int* counts = (int*)(ws + O_COUNTS);
  int* offs   = (int*)(ws + O_OFFS);
  int* curs   = (int*)(ws + O_CURS);
  int* esrc   = (int*)(ws + O_EIDX);
  float* PW1  = ws + O_PW1;
  unsigned short* PW2Bu = (unsigned short*)(ws + O_PW2);          // 131072 bf16
  unsigned short* PHHBu = (unsigned short*)(ws + O_LW);           // 262144 bf16
  unsigned short* PWBu  = (unsigned short*)(ws + O_LW + 131072u); // 262144 bf16
  float* BC   = ws + O_BCOMB;
  float* ABF  = ws + O_ABF;
  float* HWT  = ws + O_HWT;
  unsigned short* XL1u = (unsigned short*)(ws + O_BIG0);
  float* XR1  = ws + O_BIG1;
  float* H1   = ws + O_BIG2;
  float* XP   = ws + O_BIG3;
  float* Hres = ws + O_BIG4;
  unsigned short* XL2u = (unsigned short*)(ws + O_BIG0);
  float* XR2  = ws + O_BIG0 + 8192000u;
  unsigned short* PREh = (unsigned short*)(ws + O_BIG0);
  float* H1SEQ = ws + O_BIG2;
  float* LOp  = ws + O_BIG3;
  float* outp = (float*)d_out;

  prep_edges<<<67, 256, 0, stream>>>(ei, srcD, dstD, counts);
  hist_kernel<<<67, 256, 0, stream>>>(dstD, counts);
  scan_kernel<<<1, 1024, 0, stream>>>(counts, offs, curs);
  fill_kernel<<<67, 256, 0, stream>>>(srcD, dstD, curs, esrc);
  pack_kernel<<<1024, 256, 0, stream>>>(Wl1, Wr1, Wp, Wl2, Wr2,
      Wih0, Whh0, bih0, bhh0, Wih1, Whh1, bih1, bhh1,
      g1, be1, m1, v1, bg1, g2, be2, m2, v2, bg2,
      Ws1, Ws2, Wh1, PW1, PW2Bu, PHHBu, PWBu, BC, ABF, HWT);
  proj1_kernel<<<4000, 320, 0, stream>>>(x, PW1, bp, XL1u, XR1, XP);
  gat1_kernel<<<dim3(250, 64), 256, 0, stream>>>(XL1u, XR1, esrc, offs, a1, ABF, H1);
  proj2_kernel<<<2000, 512, 0, stream>>>(H1, PW2Bu, XL2u, XR2);
  gat2_kernel<<<dim3(250, 64), 256, 0, stream>>>(XL2u, XR2, esrc, offs, a2, ABF, XP, Hres);
  gemm_pre_kernel<<<2000, 512, 0, stream>>>(Hres, PWBu, BC, PREh);
  rec2_kernel<<<250, 512, 0, stream>>>(PREh, PHHBu, H1SEQ);
  gemm_pre_kernel<<<2000, 512, 0, stream>>>(H1SEQ, PWBu + 131072u, BC + 512, PREh);
  rec2_kernel<<<250, 512, 0, stream>>>(PREh, PHHBu + 131072u, LOp);
  attn_kernel<<<4000, 64, 0, stream>>>(LOp, x, Wa, ba, bs1, bs2, bh1, bh2, Wh2, HWT, outp);
}